// Round 3
// baseline (827.068 us; speedup 1.0000x reference)
//
#include <hip/hip_runtime.h>

typedef unsigned short u16;
typedef unsigned int u32;
typedef __attribute__((ext_vector_type(8))) short short8;
typedef __attribute__((ext_vector_type(4))) float f32x4;

// ---------- bf16 helpers ----------
__device__ inline u16 f2b(float f) {  // RNE
  u32 u = __builtin_bit_cast(u32, f);
  u += 0x7fff + ((u >> 16) & 1);
  return (u16)(u >> 16);
}
__device__ inline float b2f(u16 u) {
  return __builtin_bit_cast(float, (u32)u << 16);
}
// round-to-nearest (ties away) pack — cheaper than RNE, used for P only
__device__ inline u32 pack_bf16_rn(float a, float b) {
  const u32 ua = __builtin_bit_cast(u32, a) + 0x8000u;
  const u32 ub = __builtin_bit_cast(u32, b) + 0x8000u;
  return (ua >> 16) | (ub & 0xffff0000u);
}
__device__ inline void c_store(float* p, float v) { *p = v; }
__device__ inline void c_store(u16* p, float v) { *p = f2b(v); }

__device__ inline float fexp2(float x) {
#if __has_builtin(__builtin_amdgcn_exp2f)
  return __builtin_amdgcn_exp2f(x);
#else
  return exp2f(x);
#endif
}

// ---------- async global->LDS, 16B per lane ----------
typedef const __attribute__((address_space(1))) u32 gu32;
typedef __attribute__((address_space(3))) u32 lu32;
__device__ inline void async16(const u16* g, u16* l) {
  __builtin_amdgcn_global_load_lds((gu32*)g, (lu32*)l, 16, 0, 0);
}

// Q scale folded into rmsnorm producer: 1/sqrt(128) * log2(e)
#define QS (0.08838834764831843f * 1.4426950408889634f)

// =====================================================================
// (32*MI)x128x(K,BK=32) bf16 GEMM, m97 structure (verified r3-r6).
// MI=4: 128-row tile. MI=2: 64-row tile for occupancy-starved shapes.
// =====================================================================
template <int MI, typename TC>
__global__ __launch_bounds__(256) void gemm128_kernel(
    const u16* __restrict__ A, long lda,
    const u16* __restrict__ Bt, long ldb,
    TC* __restrict__ C0, TC* __restrict__ C1, TC* __restrict__ C2, long ldc,
    const float* b0, const float* b1, const float* b2,
    int K) {
  __shared__ u16 As[32 * MI * 32];
  __shared__ u16 Bs[128 * 32];

  const int tid = threadIdx.x;
  const int lane = tid & 63;
  const int w = tid >> 6;
  const int r = lane & 15;
  const int quad = lane >> 4;
  const int m0 = blockIdx.y * (32 * MI);
  const int nb = blockIdx.x * 128;
  const int seg = nb / 1536;
  const int nc = nb - seg * 1536;
  TC* C = seg == 0 ? C0 : (seg == 1 ? C1 : C2);
  const float* bias = seg == 0 ? b0 : (seg == 1 ? b1 : b2);

  const int srow = lane >> 2;
  const int sx = ((lane & 3) ^ (srow & 3)) * 8;
  const u16* Ag = A + (size_t)(m0 + w * 8 * MI + srow) * lda + sx;
  const u16* Bg = Bt + (size_t)(nb + w * 32 + srow) * ldb + sx;
  u16* Al[MI / 2];
#pragma unroll
  for (int j = 0; j < MI / 2; ++j) Al[j] = &As[(w * 8 * MI + 16 * j) * 32];
  u16* const Bl0 = &Bs[(w * 32) * 32];
  u16* const Bl1 = &Bs[(w * 32 + 16) * 32];

  const int wm = (w >> 1) * (16 * MI);
  const int wn = (w & 1) * 64;

  f32x4 acc[MI][4];
#pragma unroll
  for (int i = 0; i < MI; ++i)
#pragma unroll
    for (int j = 0; j < 4; ++j) acc[i][j] = (f32x4){0.f, 0.f, 0.f, 0.f};

  const int fco = (quad ^ (r & 3)) * 8;

  for (int kk = 0; kk < K; kk += 32) {
    __syncthreads();
#pragma unroll
    for (int j = 0; j < MI / 2; ++j) async16(Ag + kk + (size_t)(16 * j) * lda, Al[j]);
    async16(Bg + kk, Bl0);
    async16(Bg + kk + 16 * ldb, Bl1);
    __syncthreads();

    short8 af[MI], bf[4];
#pragma unroll
    for (int mi = 0; mi < MI; ++mi)
      af[mi] = *reinterpret_cast<const short8*>(&As[(wm + 16 * mi + r) * 32 + fco]);
#pragma unroll
    for (int ni = 0; ni < 4; ++ni)
      bf[ni] = *reinterpret_cast<const short8*>(&Bs[(wn + 16 * ni + r) * 32 + fco]);
#pragma unroll
    for (int mi = 0; mi < MI; ++mi)
#pragma unroll
      for (int ni = 0; ni < 4; ++ni)
        acc[mi][ni] = __builtin_amdgcn_mfma_f32_16x16x32_bf16(af[mi], bf[ni], acc[mi][ni], 0, 0, 0);
  }

#pragma unroll
  for (int mi = 0; mi < MI; ++mi)
#pragma unroll
    for (int ni = 0; ni < 4; ++ni)
#pragma unroll
      for (int rr = 0; rr < 4; ++rr) {
        const int row = m0 + wm + 16 * mi + 4 * quad + rr;
        const int col = nc + wn + 16 * ni + r;
        c_store(&C[(size_t)row * ldc + col], acc[mi][ni][rr] + bias[col]);
      }
}

// =====================================================================
// Merged f32->bf16 convert for hs and rhs
// =====================================================================
__global__ __launch_bounds__(256) void conv2_kernel(
    const float* __restrict__ xa, u16* __restrict__ ya, int n8a,
    const float* __restrict__ xb, u16* __restrict__ yb, int n8b) {
  int i = blockIdx.x * 256 + threadIdx.x;
  const float* x;
  u16* y;
  if (i < n8a) {
    x = xa; y = ya;
  } else {
    i -= n8a;
    if (i >= n8b) return;
    x = xb; y = yb;
  }
  const float4 v0 = reinterpret_cast<const float4*>(x)[2 * i];
  const float4 v1 = reinterpret_cast<const float4*>(x)[2 * i + 1];
  uint4 rv;
  rv.x = (u32)f2b(v0.x) | ((u32)f2b(v0.y) << 16);
  rv.y = (u32)f2b(v0.z) | ((u32)f2b(v0.w) << 16);
  rv.z = (u32)f2b(v1.x) | ((u32)f2b(v1.y) << 16);
  rv.w = (u32)f2b(v1.z) | ((u32)f2b(v1.w) << 16);
  reinterpret_cast<uint4*>(y)[i] = rv;
}

// =====================================================================
// Transpose-convert, all 6 weights merged (W f32 [1536][1536] -> Wt^T bf16)
// =====================================================================
__device__ inline void transconv_body(const float* __restrict__ W, u16* __restrict__ Wt) {
  __shared__ u16 Ls[64 * 72];
  const int tid = threadIdx.x;
  const int k0 = blockIdx.y * 64;
  const int n0 = blockIdx.x * 64;
#pragma unroll
  for (int i = 0; i < 4; ++i) {
    const int c = tid + 256 * i;
    const int row = c >> 4;
    const int c4 = (c & 15) * 4;
    const float4 v = *reinterpret_cast<const float4*>(&W[(size_t)(k0 + row) * 1536 + n0 + c4]);
    Ls[(c4 + 0) * 72 + row] = f2b(v.x);
    Ls[(c4 + 1) * 72 + row] = f2b(v.y);
    Ls[(c4 + 2) * 72 + row] = f2b(v.z);
    Ls[(c4 + 3) * 72 + row] = f2b(v.w);
  }
  __syncthreads();
#pragma unroll
  for (int i = 0; i < 2; ++i) {
    const int c = tid + 256 * i;
    const int n = c >> 3;
    const int kc = (c & 7) * 8;
    u16 tmp[8];
#pragma unroll
    for (int j = 0; j < 8; ++j) tmp[j] = Ls[n * 72 + kc + j];
    *reinterpret_cast<uint4*>(&Wt[(size_t)(n0 + n) * 1536 + k0 + kc]) =
        *reinterpret_cast<const uint4*>(tmp);
  }
}

__global__ __launch_bounds__(256) void transconv6_kernel(
    const float* W0, const float* W1, const float* W2,
    const float* W3, const float* W4, const float* W5,
    u16* T0, u16* T1, u16* T2, u16* T3, u16* T4, u16* T5) {
  const int z = blockIdx.z;
  const float* W = z == 0 ? W0 : z == 1 ? W1 : z == 2 ? W2 : z == 3 ? W3 : z == 4 ? W4 : W5;
  u16* Wt = z == 0 ? T0 : z == 1 ? T1 : z == 2 ? T2 : z == 3 ? T3 : z == 4 ? T4 : T5;
  transconv_body(W, Wt);
}

// =====================================================================
// Merged RMSNorm: z=0 q-path (scaled by QS, plain+rope), z=1 k-path
// (rope), z=2 ref-k (1024 rows, plain). Verified r4-r6.
// =====================================================================
__global__ __launch_bounds__(256) void rmsnorm3_kernel(
    const u16* xq, const u16* xk, const u16* xkr,
    const float* gq, const float* gk,
    const float* rc, const float* rs,
    u16* oq_plain, u16* oq_rope, u16* ok_rope, u16* okr_plain) {
  __shared__ float red[4];
  const int z = blockIdx.y;
  const int row = blockIdx.x;
  if (z == 2 && row >= 1024) return;
  const u16* x; const float* g; u16* po; u16* pr; float sc;
  if (z == 0)      { x = xq;  g = gq; po = oq_plain; pr = oq_rope; sc = QS;  }
  else if (z == 1) { x = xk;  g = gk; po = nullptr;  pr = ok_rope; sc = 1.f; }
  else             { x = xkr; g = gk; po = okr_plain; pr = nullptr; sc = 1.f; }

  const int tid = threadIdx.x;
  const u32* xr = reinterpret_cast<const u32*>(x + (size_t)row * 1536);
  float xe[3], xo[3];
  float ss = 0.f;
#pragma unroll
  for (int j = 0; j < 3; ++j) {
    const u32 u = xr[tid + 256 * j];
    const float e = b2f((u16)(u & 0xffff));
    const float o = b2f((u16)(u >> 16));
    xe[j] = e; xo[j] = o;
    ss += e * e + o * o;
  }
#pragma unroll
  for (int off = 32; off; off >>= 1) ss += __shfl_xor(ss, off, 64);
  if ((tid & 63) == 0) red[tid >> 6] = ss;
  __syncthreads();
  const float total = red[0] + red[1] + red[2] + red[3];
  const float rinv = rsqrtf(total * (1.0f / 1536.0f) + 1e-6f) * sc;
  u32* po32 = po ? reinterpret_cast<u32*>(po + (size_t)row * 1536) : nullptr;
  u32* pr32 = pr ? reinterpret_cast<u32*>(pr + (size_t)row * 1536) : nullptr;
#pragma unroll
  for (int j = 0; j < 3; ++j) {
    const int p = tid + 256 * j;
    const float2 gg = reinterpret_cast<const float2*>(g)[p];
    const float e = xe[j] * rinv * gg.x;
    const float o = xo[j] * rinv * gg.y;
    if (po32) po32[p] = (u32)f2b(e) | ((u32)f2b(o) << 16);
    if (pr32) {
      const int i = p & 63;
      const float c = rc[row * 64 + i];
      const float s = rs[row * 64 + i];
      const float re = e * c - o * s;
      const float im = e * s + o * c;
      pr32[p] = (u32)f2b(re) | ((u32)f2b(im) << 16);
    }
  }
}

// =====================================================================
// Merged per-head V transpose (verified r4-r6)
// =====================================================================
__global__ __launch_bounds__(256) void vtrans2_kernel(
    const u16* __restrict__ V0, u16* __restrict__ Vt0,
    const u16* __restrict__ V1, u16* __restrict__ Vt1) {
  __shared__ u16 Ls[64 * 136];
  const int z = blockIdx.z;
  const int kvLen = z == 0 ? 4096 : 1024;
  const int kv0 = blockIdx.x * 64;
  if (kv0 >= kvLen) return;
  const u16* V = z == 0 ? V0 : V1;
  u16* Vt = z == 0 ? Vt0 : Vt1;
  const int tid = threadIdx.x;
  const int h = blockIdx.y;
#pragma unroll
  for (int i = 0; i < 4; ++i) {
    const int c = tid + 256 * i;
    const int row = c >> 4, c8 = c & 15;
    *reinterpret_cast<uint4*>(&Ls[row * 136 + 8 * c8]) =
        *reinterpret_cast<const uint4*>(V + (size_t)(kv0 + row) * 1536 + h * 128 + 8 * c8);
  }
  __syncthreads();
#pragma unroll
  for (int i = 0; i < 4; ++i) {
    const int c = tid + 256 * i;
    const int d = c >> 3, kc = c & 7;
    u16 tmp[8];
#pragma unroll
    for (int j = 0; j < 8; ++j) tmp[j] = Ls[(8 * kc + j) * 136 + d];
    *reinterpret_cast<uint4*>(Vt + ((size_t)h * 128 + d) * kvLen + kv0 + 8 * kc) =
        *reinterpret_cast<const uint4*>(tmp);
  }
}

// =====================================================================
// Flash attention, round-9: LDS-bandwidth fix.
//  r8 post-mortem: structure was LDS-BW-bound, not latency-bound.
//  Per tile-unit (1177 cyc budget): 68 ds_read_b128 x 12 cyc = 816 cyc
//  -> LDS pipe ~70% busy vs MFMA 24 / VALU 37 / HBM 8. Each of the 4
//  waves re-reads the ENTIRE K and V tiles from LDS (fragments carry no
//  'w' index).
//  FIX: V fragments move to registers, loaded directly from global in
//  fragment layout: lane (r,quad), dt -> Vt[16dt+r][kv0+8quad..+7].
//  Per instruction: 16 rows x 64B = sector-perfect; identical addrs
//  across the 4 waves -> L1 absorbs the duplication. Issued at top of
//  tile t BEFORE the K async16 for t+1 (compiler's pre-PV wait is then
//  a counted vmcnt that leaves the K prefetch in flight). Removes 8 of
//  17 ds_reads/wave/tile + all V staging; LDS 38.4 -> 21.8 KB.
//  launch_bounds (256,3): grid binds occupancy (3 blk/CU = 12 waves/CU
//  = 3/SIMD), so VGPR cap 170 is free headroom for vreg[8] (+32).
//  Kept: KVBLK=32 K double-buffer, 1 barrier/tile, setprio, defer-max,
//  merged cross+main passes.
// =====================================================================
__global__ __launch_bounds__(256, 3) void flash_kernel(
    const u16* __restrict__ Qc, const u16* __restrict__ Kc,
    const u16* __restrict__ Vc, int kvLenC,
    const u16* __restrict__ Qm, const u16* __restrict__ Km,
    const u16* __restrict__ Vm, int kvLenM,
    u16* __restrict__ Ob) {
  __shared__ u16 Ks[2][32 * 128];
  __shared__ u16 Pb[4][16 * 40];
  __shared__ float ab[4][16];

  const int tid = threadIdx.x;
  const int lane = tid & 63;
  const int w = tid >> 6;
  const int r = lane & 15;
  const int quad = lane >> 4;
  const int h = blockIdx.y;
  const int q0 = blockIdx.x * 64;
  const int qrow = q0 + 16 * w + r;

  auto run_pass = [&](const u16* __restrict__ Q, const u16* __restrict__ K,
                      const u16* __restrict__ Vt, int kvLen, f32x4* Oc) {
    // Q fragments (B-operand of S^T): lane holds Q[qrow][32ks+8quad+j]
    short8 qf[4];
    {
      const u16* qbase = Q + (size_t)qrow * 1536 + h * 128 + 8 * quad;
#pragma unroll
      for (int ks = 0; ks < 4; ++ks)
        qf[ks] = *reinterpret_cast<const short8*>(qbase + 32 * ks);
    }

    // K staging: uniform base + 32-bit per-lane element offsets
    const u16* Kb = K + h * 128;
    u32 koff[2];
    int klo[2];
    {
      const int p16 = lane & 15, rin = lane >> 4;
#pragma unroll
      for (int j = 0; j < 2; ++j) {
        const int row = 8 * w + 4 * j + rin;
        koff[j] = (u32)row * 1536u + 8u * (u32)(p16 ^ (row & 15));
        klo[j] = (8 * w + 4 * j) * 128;
      }
    }

    // V: per-lane global base for fragment loads
    const u16* Vb = Vt + (size_t)h * 128 * kvLen + (size_t)r * kvLen + 8 * quad;

#pragma unroll
    for (int dt = 0; dt < 8; ++dt) Oc[dt] = (f32x4){0.f, 0.f, 0.f, 0.f};
    float m_i = -1e30f, l_i = 0.f;

    const int nt = kvLen >> 5;

    // prologue: stage K tile 0 into buffer 0
#pragma unroll
    for (int j = 0; j < 2; ++j) async16(Kb + koff[j], &Ks[0][klo[j]]);

    for (int t = 0; t < nt; ++t) {
      const int buf = t & 1;
      __syncthreads();  // drains vmcnt(0): K stage(t) complete AND all
                        // waves' Ks[buf^1] reads are done.

      // V fragments for THIS tile (consumed in PV, ~400 cyc away).
      short8 vreg[8];
      {
        const u16* vp = Vb + t * 32;
#pragma unroll
        for (int dt = 0; dt < 8; ++dt)
          vreg[dt] = *reinterpret_cast<const short8*>(vp + (size_t)(16 * dt) * kvLen);
      }
      if (t + 1 < nt) {
        const size_t ko = (size_t)(t + 1) * (32 * 1536);
#pragma unroll
        for (int j = 0; j < 2; ++j) async16(Kb + ko + koff[j], &Ks[buf ^ 1][klo[j]]);
      }

      // S^T = K * Q^T (log2-domain; Q pre-scaled)
      f32x4 St[2];
#pragma unroll
      for (int mt = 0; mt < 2; ++mt) St[mt] = (f32x4){0.f, 0.f, 0.f, 0.f};
      __builtin_amdgcn_s_setprio(1);
#pragma unroll
      for (int mt = 0; mt < 2; ++mt) {
        const u16* kp = &Ks[buf][(16 * mt + r) * 128];
#pragma unroll
        for (int ks = 0; ks < 4; ++ks) {
          const short8 af = *reinterpret_cast<const short8*>(kp + 8 * ((quad + 4 * ks) ^ r));
          St[mt] = __builtin_amdgcn_mfma_f32_16x16x32_bf16(af, qf[ks], St[mt], 0, 0, 0);
        }
      }
      __builtin_amdgcn_s_setprio(0);

      // online softmax (base 2); lane owns q-row r
      float mloc = -1e30f;
#pragma unroll
      for (int mt = 0; mt < 2; ++mt)
#pragma unroll
        for (int rr = 0; rr < 4; ++rr) mloc = fmaxf(mloc, St[mt][rr]);
      mloc = fmaxf(mloc, __shfl_xor(mloc, 16, 64));
      mloc = fmaxf(mloc, __shfl_xor(mloc, 32, 64));

      float alpha = 1.0f;
      if (__any(mloc > m_i + 11.5f)) {  // defer-max: only rescale on big growth
        const float mn = fmaxf(m_i, mloc);
        alpha = fexp2(m_i - mn);
        m_i = mn;
        if (quad == 0) ab[w][r] = alpha;
        const float4 a4 = *reinterpret_cast<const float4*>(&ab[w][4 * quad]);
#pragma unroll
        for (int dt = 0; dt < 8; ++dt) {
          Oc[dt][0] *= a4.x; Oc[dt][1] *= a4.y; Oc[dt][2] *= a4.z; Oc[dt][3] *= a4.w;
        }
      }

      float psum = 0.f;
      uint2 pk[2];
#pragma unroll
      for (int mt = 0; mt < 2; ++mt) {
        const float p0 = fexp2(St[mt][0] - m_i);
        const float p1 = fexp2(St[mt][1] - m_i);
        const float p2 = fexp2(St[mt][2] - m_i);
        const float p3 = fexp2(St[mt][3] - m_i);
        psum += (p0 + p1) + (p2 + p3);
        pk[mt].x = pack_bf16_rn(p0, p1);
        pk[mt].y = pack_bf16_rn(p2, p3);
      }
      psum += __shfl_xor(psum, 16, 64);
      psum += __shfl_xor(psum, 32, 64);
      l_i = l_i * alpha + psum;

      // PV: P is 16q x 32k this tile; B-operand from vreg.
#pragma unroll
      for (int mt = 0; mt < 2; ++mt)
        *reinterpret_cast<uint2*>(&Pb[w][r * 40 + 16 * mt + 4 * quad]) = pk[mt];
      {
        const short8 pa = *reinterpret_cast<const short8*>(&Pb[w][r * 40 + 8 * quad]);
        __builtin_amdgcn_s_setprio(1);
#pragma unroll
        for (int dt = 0; dt < 8; ++dt)
          Oc[dt] = __builtin_amdgcn_mfma_f32_16x16x32_bf16(pa, vreg[dt], Oc[dt], 0, 0, 0);
        __builtin_amdgcn_s_setprio(0);
      }
    }

    // normalize by 1/l (LDS broadcast, wave-private)
    if (quad == 0) ab[w][r] = 1.0f / l_i;
    const float4 li4 = *reinterpret_cast<const float4*>(&ab[w][4 * quad]);
#pragma unroll
    for (int dt = 0; dt < 8; ++dt) {
      Oc[dt][0] *= li4.x; Oc[dt][1] *= li4.y; Oc[dt][2] *= li4.z; Oc[dt][3] *= li4.w;
    }
  };

  f32x4 Ocr[8];  // cross-attn result, normalized, held in regs
  run_pass(Qc, Kc, Vc, kvLenC, Ocr);
  __syncthreads();  // all cross LDS reads done before main re-stages buf 0
  f32x4 Oc[8];
  run_pass(Qm, Km, Vm, kvLenM, Oc);

  // store bf16: main + cross
  u16* obb = Ob + (size_t)(q0 + 16 * w) * 1536 + h * 128;
#pragma unroll
  for (int rr = 0; rr < 4; ++rr) {
    u16* brow = obb + (size_t)(4 * quad + rr) * 1536 + r;
#pragma unroll
    for (int dt = 0; dt < 8; ++dt)
      brow[16 * dt] = f2b(Oc[dt][rr] + Ocr[dt][rr]);
  }
}

// =====================================================================
// Host orchestration (8 dispatches)
// =====================================================================
extern "C" void kernel_launch(void* const* d_in, const int* in_sizes, int n_in,
                              void* d_out, int out_size, void* d_ws, size_t ws_size,
                              hipStream_t stream) {
  (void)in_sizes; (void)n_in; (void)out_size; (void)ws_size;
  constexpr int T = 4096, TR = 1024, DIM = 1536, NH = 12;

  const float* hs  = (const float*)d_in[0];
  const float* rhs = (const float*)d_in[1];
  const float* rc  = (const float*)d_in[2];
  const float* rs  = (const float*)d_in[3];
  const float* Wq  = (const float*)d_in[4];
  const float* bq  = (const float*)d_in[5];
  const float* Wk  = (const float*)d_in[6];
  const float* bk  = (const float*)d_in[7];
  const float* Wv  = (const float*)d_in[8];
  const float* bv  = (const float*)d_in[9];
  const float* Wkr = (const float*)d_in[10];
  const float* bkr = (const float*)d_in[11];
  const float* Wvr = (const float*)d_in[12];
  const float* bvr = (const float*)d_in[13];
  const float* Wo  = (const float*)d_in[14];
  const float* bo  = (const float*)d_in[15];
  const float* gq  = (const float*)d_in[16];
  const float* gk  = (const float*)d_in[17];
  float* out = (float*)d_out;

  char* ws = (char*)d_ws;
  size_t off = 0;
  auto alloc = [&](size_t bytes) -> void* {
    void* p = ws + off;
    off += (bytes + 255) & ~(size_t)255;
    return p;
  };
  u16* bQ    = (u16*)alloc((size_t)T * DIM * 2);
  u16* bQr   = (u16*)alloc((size_t)T * DIM * 2);
  u16* bK    = (u16*)alloc((size_t)T * DIM * 2);
  u16* bV    = (u16*)alloc((size_t)T * DIM * 2);
  u16* bKr   = (u16*)alloc((size_t)TR * DIM * 2);
  u16* bVr   = (u16*)alloc((size_t)TR * DIM * 2);
  u16* bHs   = (u16*)alloc((size_t)T * DIM * 2);       // bf16 hs; ALIAS-> VtG
  u16* bRhs  = (u16*)alloc((size_t)TR * DIM * 2);      // bf16 rhs; ALIAS-> VtR
  u16* bWqkv = (u16*)alloc((size_t)3 * DIM * DIM * 2); // WqT|WkT|WvT; ALIAS-> bOb
  u16* bWr   = (u16*)alloc((size_t)2 * DIM * DIM * 2); // WkrT|WvrT
  u16* bWoT  = (u16*)alloc((size_t)DIM * DIM * 2);     // WoT (own slab)
  u16* VtG = bHs;
  u16* VtR = bRhs;
  u16* bOb = bWqkv;

  const dim3 blk(256);

  // 1. f32->bf16 converts (merged)
  conv2_kernel<<<dim3((T * DIM / 8 + TR * DIM / 8 + 255) / 256), blk, 0, stream>>>(
      hs, bHs, T * DIM / 8, rhs, bRhs, TR * DIM / 8);

  // 2. weight transpose-converts (all six merged)
  transconv6_kernel<<<dim3(24, 24, 6), blk, 0, stream>>>(
      Wq, Wk, Wv, Wkr, Wvr, Wo,
      bWqkv + 0 * (size_t)DIM * DIM, bWqkv + 1 * (size_t)DIM * DIM,
      bWqkv + 2 * (size_t)DIM * DIM, bWr + 0 * (size_t)DIM * DIM,
      bWr + 1 * (size_t)DIM * DIM, bWoT);

  // 3-4. projections (QKV fused 128-tile; KrVr 64-tile for occupancy)
  gemm128_kernel<4, u16><<<dim3(36, 32), blk, 0, stream>>>(
      bHs, DIM, bWqkv, DIM, bQ, bK, bV, DIM, bq, bk, bv, DIM);
  gemm128_kernel<2, u16><<<dim3(24, 16), blk, 0, stream>>>(
      bRhs, DIM, bWr, DIM, bKr, bVr, (u16*)nullptr, DIM, bkr, bvr, nullptr, DIM);

  // 5. rmsnorm/rope (merged; q-path pre-scaled by QS)
  rmsnorm3_kernel<<<dim3(T, 3), blk, 0, stream>>>(
      bQ, bK, bKr, gq, gk, rc, rs, bQ, bQr, bK, bKr);

  // 6. per-head V transposes (merged; alias buffers are dead)
  vtrans2_kernel<<<dim3(T / 64, NH, 2), blk, 0, stream>>>(bV, VtG, bVr, VtR);

  // 7. merged flash attention: cross (kv=1024) + main (kv=4096), adds in regs
  flash_kernel<<<dim3(T / 64, NH), blk, 0, stream>>>(
      bQ, bKr, VtR, TR, bQr, bK, VtG, T, bOb);

  // 8. output projection (64-row tiles for occupancy)
  gemm128_kernel<2, float><<<dim3(12, 64), blk, 0, stream>>>(
      bOb, DIM, bWoT, DIM, out, (float*)nullptr, (float*)nullptr, DIM, bo, nullptr, nullptr, DIM);
}

// Round 4
// 581.665 us; speedup vs baseline: 1.4219x; 1.4219x over previous
//
#include <hip/hip_runtime.h>

typedef unsigned short u16;
typedef unsigned int u32;
typedef __attribute__((ext_vector_type(8))) short short8;
typedef __attribute__((ext_vector_type(4))) float f32x4;

// ---------- bf16 helpers ----------
__device__ inline u16 f2b(float f) {  // RNE
  u32 u = __builtin_bit_cast(u32, f);
  u += 0x7fff + ((u >> 16) & 1);
  return (u16)(u >> 16);
}
__device__ inline float b2f(u16 u) {
  return __builtin_bit_cast(float, (u32)u << 16);
}
// round-to-nearest (ties away) pack — cheaper than RNE, used for P only
__device__ inline u32 pack_bf16_rn(float a, float b) {
  const u32 ua = __builtin_bit_cast(u32, a) + 0x8000u;
  const u32 ub = __builtin_bit_cast(u32, b) + 0x8000u;
  return (ua >> 16) | (ub & 0xffff0000u);
}
__device__ inline void c_store(float* p, float v) { *p = v; }
__device__ inline void c_store(u16* p, float v) { *p = f2b(v); }

__device__ inline float fexp2(float x) {
#if __has_builtin(__builtin_amdgcn_exp2f)
  return __builtin_amdgcn_exp2f(x);
#else
  return exp2f(x);
#endif
}

// ---------- async global->LDS, 16B per lane ----------
typedef const __attribute__((address_space(1))) u32 gu32;
typedef __attribute__((address_space(3))) u32 lu32;
__device__ inline void async16(const u16* g, u16* l) {
  __builtin_amdgcn_global_load_lds((gu32*)g, (lu32*)l, 16, 0, 0);
}

// Q scale folded into rmsnorm producer: 1/sqrt(128) * log2(e)
#define QS (0.08838834764831843f * 1.4426950408889634f)

// =====================================================================
// (32*MI)x128x(K,BK=32) bf16 GEMM, m97 structure (verified r3-r6).
// MI=4: 128-row tile. MI=2: 64-row tile for occupancy-starved shapes.
// =====================================================================
template <int MI, typename TC>
__global__ __launch_bounds__(256) void gemm128_kernel(
    const u16* __restrict__ A, long lda,
    const u16* __restrict__ Bt, long ldb,
    TC* __restrict__ C0, TC* __restrict__ C1, TC* __restrict__ C2, long ldc,
    const float* b0, const float* b1, const float* b2,
    int K) {
  __shared__ u16 As[32 * MI * 32];
  __shared__ u16 Bs[128 * 32];

  const int tid = threadIdx.x;
  const int lane = tid & 63;
  const int w = tid >> 6;
  const int r = lane & 15;
  const int quad = lane >> 4;
  const int m0 = blockIdx.y * (32 * MI);
  const int nb = blockIdx.x * 128;
  const int seg = nb / 1536;
  const int nc = nb - seg * 1536;
  TC* C = seg == 0 ? C0 : (seg == 1 ? C1 : C2);
  const float* bias = seg == 0 ? b0 : (seg == 1 ? b1 : b2);

  const int srow = lane >> 2;
  const int sx = ((lane & 3) ^ (srow & 3)) * 8;
  const u16* Ag = A + (size_t)(m0 + w * 8 * MI + srow) * lda + sx;
  const u16* Bg = Bt + (size_t)(nb + w * 32 + srow) * ldb + sx;
  u16* Al[MI / 2];
#pragma unroll
  for (int j = 0; j < MI / 2; ++j) Al[j] = &As[(w * 8 * MI + 16 * j) * 32];
  u16* const Bl0 = &Bs[(w * 32) * 32];
  u16* const Bl1 = &Bs[(w * 32 + 16) * 32];

  const int wm = (w >> 1) * (16 * MI);
  const int wn = (w & 1) * 64;

  f32x4 acc[MI][4];
#pragma unroll
  for (int i = 0; i < MI; ++i)
#pragma unroll
    for (int j = 0; j < 4; ++j) acc[i][j] = (f32x4){0.f, 0.f, 0.f, 0.f};

  const int fco = (quad ^ (r & 3)) * 8;

  for (int kk = 0; kk < K; kk += 32) {
    __syncthreads();
#pragma unroll
    for (int j = 0; j < MI / 2; ++j) async16(Ag + kk + (size_t)(16 * j) * lda, Al[j]);
    async16(Bg + kk, Bl0);
    async16(Bg + kk + 16 * ldb, Bl1);
    __syncthreads();

    short8 af[MI], bf[4];
#pragma unroll
    for (int mi = 0; mi < MI; ++mi)
      af[mi] = *reinterpret_cast<const short8*>(&As[(wm + 16 * mi + r) * 32 + fco]);
#pragma unroll
    for (int ni = 0; ni < 4; ++ni)
      bf[ni] = *reinterpret_cast<const short8*>(&Bs[(wn + 16 * ni + r) * 32 + fco]);
#pragma unroll
    for (int mi = 0; mi < MI; ++mi)
#pragma unroll
      for (int ni = 0; ni < 4; ++ni)
        acc[mi][ni] = __builtin_amdgcn_mfma_f32_16x16x32_bf16(af[mi], bf[ni], acc[mi][ni], 0, 0, 0);
  }

#pragma unroll
  for (int mi = 0; mi < MI; ++mi)
#pragma unroll
    for (int ni = 0; ni < 4; ++ni)
#pragma unroll
      for (int rr = 0; rr < 4; ++rr) {
        const int row = m0 + wm + 16 * mi + 4 * quad + rr;
        const int col = nc + wn + 16 * ni + r;
        c_store(&C[(size_t)row * ldc + col], acc[mi][ni][rr] + bias[col]);
      }
}

// =====================================================================
// Merged f32->bf16 convert for hs and rhs
// =====================================================================
__global__ __launch_bounds__(256) void conv2_kernel(
    const float* __restrict__ xa, u16* __restrict__ ya, int n8a,
    const float* __restrict__ xb, u16* __restrict__ yb, int n8b) {
  int i = blockIdx.x * 256 + threadIdx.x;
  const float* x;
  u16* y;
  if (i < n8a) {
    x = xa; y = ya;
  } else {
    i -= n8a;
    if (i >= n8b) return;
    x = xb; y = yb;
  }
  const float4 v0 = reinterpret_cast<const float4*>(x)[2 * i];
  const float4 v1 = reinterpret_cast<const float4*>(x)[2 * i + 1];
  uint4 rv;
  rv.x = (u32)f2b(v0.x) | ((u32)f2b(v0.y) << 16);
  rv.y = (u32)f2b(v0.z) | ((u32)f2b(v0.w) << 16);
  rv.z = (u32)f2b(v1.x) | ((u32)f2b(v1.y) << 16);
  rv.w = (u32)f2b(v1.z) | ((u32)f2b(v1.w) << 16);
  reinterpret_cast<uint4*>(y)[i] = rv;
}

// =====================================================================
// Transpose-convert, all 6 weights merged (W f32 [1536][1536] -> Wt^T bf16)
// =====================================================================
__device__ inline void transconv_body(const float* __restrict__ W, u16* __restrict__ Wt) {
  __shared__ u16 Ls[64 * 72];
  const int tid = threadIdx.x;
  const int k0 = blockIdx.y * 64;
  const int n0 = blockIdx.x * 64;
#pragma unroll
  for (int i = 0; i < 4; ++i) {
    const int c = tid + 256 * i;
    const int row = c >> 4;
    const int c4 = (c & 15) * 4;
    const float4 v = *reinterpret_cast<const float4*>(&W[(size_t)(k0 + row) * 1536 + n0 + c4]);
    Ls[(c4 + 0) * 72 + row] = f2b(v.x);
    Ls[(c4 + 1) * 72 + row] = f2b(v.y);
    Ls[(c4 + 2) * 72 + row] = f2b(v.z);
    Ls[(c4 + 3) * 72 + row] = f2b(v.w);
  }
  __syncthreads();
#pragma unroll
  for (int i = 0; i < 2; ++i) {
    const int c = tid + 256 * i;
    const int n = c >> 3;
    const int kc = (c & 7) * 8;
    u16 tmp[8];
#pragma unroll
    for (int j = 0; j < 8; ++j) tmp[j] = Ls[n * 72 + kc + j];
    *reinterpret_cast<uint4*>(&Wt[(size_t)(n0 + n) * 1536 + k0 + kc]) =
        *reinterpret_cast<const uint4*>(tmp);
  }
}

__global__ __launch_bounds__(256) void transconv6_kernel(
    const float* W0, const float* W1, const float* W2,
    const float* W3, const float* W4, const float* W5,
    u16* T0, u16* T1, u16* T2, u16* T3, u16* T4, u16* T5) {
  const int z = blockIdx.z;
  const float* W = z == 0 ? W0 : z == 1 ? W1 : z == 2 ? W2 : z == 3 ? W3 : z == 4 ? W4 : W5;
  u16* Wt = z == 0 ? T0 : z == 1 ? T1 : z == 2 ? T2 : z == 3 ? T3 : z == 4 ? T4 : T5;
  transconv_body(W, Wt);
}

// =====================================================================
// Merged RMSNorm: z=0 q-path (scaled by QS, plain+rope), z=1 k-path
// (rope), z=2 ref-k (1024 rows, plain). Verified r4-r6.
// =====================================================================
__global__ __launch_bounds__(256) void rmsnorm3_kernel(
    const u16* xq, const u16* xk, const u16* xkr,
    const float* gq, const float* gk,
    const float* rc, const float* rs,
    u16* oq_plain, u16* oq_rope, u16* ok_rope, u16* okr_plain) {
  __shared__ float red[4];
  const int z = blockIdx.y;
  const int row = blockIdx.x;
  if (z == 2 && row >= 1024) return;
  const u16* x; const float* g; u16* po; u16* pr; float sc;
  if (z == 0)      { x = xq;  g = gq; po = oq_plain; pr = oq_rope; sc = QS;  }
  else if (z == 1) { x = xk;  g = gk; po = nullptr;  pr = ok_rope; sc = 1.f; }
  else             { x = xkr; g = gk; po = okr_plain; pr = nullptr; sc = 1.f; }

  const int tid = threadIdx.x;
  const u32* xr = reinterpret_cast<const u32*>(x + (size_t)row * 1536);
  float xe[3], xo[3];
  float ss = 0.f;
#pragma unroll
  for (int j = 0; j < 3; ++j) {
    const u32 u = xr[tid + 256 * j];
    const float e = b2f((u16)(u & 0xffff));
    const float o = b2f((u16)(u >> 16));
    xe[j] = e; xo[j] = o;
    ss += e * e + o * o;
  }
#pragma unroll
  for (int off = 32; off; off >>= 1) ss += __shfl_xor(ss, off, 64);
  if ((tid & 63) == 0) red[tid >> 6] = ss;
  __syncthreads();
  const float total = red[0] + red[1] + red[2] + red[3];
  const float rinv = rsqrtf(total * (1.0f / 1536.0f) + 1e-6f) * sc;
  u32* po32 = po ? reinterpret_cast<u32*>(po + (size_t)row * 1536) : nullptr;
  u32* pr32 = pr ? reinterpret_cast<u32*>(pr + (size_t)row * 1536) : nullptr;
#pragma unroll
  for (int j = 0; j < 3; ++j) {
    const int p = tid + 256 * j;
    const float2 gg = reinterpret_cast<const float2*>(g)[p];
    const float e = xe[j] * rinv * gg.x;
    const float o = xo[j] * rinv * gg.y;
    if (po32) po32[p] = (u32)f2b(e) | ((u32)f2b(o) << 16);
    if (pr32) {
      const int i = p & 63;
      const float c = rc[row * 64 + i];
      const float s = rs[row * 64 + i];
      const float re = e * c - o * s;
      const float im = e * s + o * c;
      pr32[p] = (u32)f2b(re) | ((u32)f2b(im) << 16);
    }
  }
}

// =====================================================================
// Merged per-head V transpose (verified r4-r6)
// =====================================================================
__global__ __launch_bounds__(256) void vtrans2_kernel(
    const u16* __restrict__ V0, u16* __restrict__ Vt0,
    const u16* __restrict__ V1, u16* __restrict__ Vt1) {
  __shared__ u16 Ls[64 * 136];
  const int z = blockIdx.z;
  const int kvLen = z == 0 ? 4096 : 1024;
  const int kv0 = blockIdx.x * 64;
  if (kv0 >= kvLen) return;
  const u16* V = z == 0 ? V0 : V1;
  u16* Vt = z == 0 ? Vt0 : Vt1;
  const int tid = threadIdx.x;
  const int h = blockIdx.y;
#pragma unroll
  for (int i = 0; i < 4; ++i) {
    const int c = tid + 256 * i;
    const int row = c >> 4, c8 = c & 15;
    *reinterpret_cast<uint4*>(&Ls[row * 136 + 8 * c8]) =
        *reinterpret_cast<const uint4*>(V + (size_t)(kv0 + row) * 1536 + h * 128 + 8 * c8);
  }
  __syncthreads();
#pragma unroll
  for (int i = 0; i < 4; ++i) {
    const int c = tid + 256 * i;
    const int d = c >> 3, kc = c & 7;
    u16 tmp[8];
#pragma unroll
    for (int j = 0; j < 8; ++j) tmp[j] = Ls[(8 * kc + j) * 136 + d];
    *reinterpret_cast<uint4*>(Vt + ((size_t)h * 128 + d) * kvLen + kv0 + 8 * kc) =
        *reinterpret_cast<const uint4*>(tmp);
  }
}

// =====================================================================
// Flash attention, round-10: fat-wave fix for LDS bandwidth.
//  r9 post-mortem: V-from-global was TA-bound (16 scattered 64B segs
//  per load; 1536 transactions/CU/tile vs 1177-cyc budget) -> 532 µs.
//  Reverted to r8's LDS-staged V (235 µs base).
//  r8 diagnosis stands: LDS read BW ~72% busy. Root cause: 16 q/wave
//  means each wave reads the whole 16KB K+V tile for only 16 MFMAs.
//  FIX: 32 q-rows per wave (2 q-subtiles), 2 waves per block (64-q
//  block, grid unchanged 64x12=768 = 3 blk/CU balanced). K-frag and
//  V-frag each reused across both q-subtiles: 18 ds_reads feed 32
//  MFMAs (LDS bytes/FLOP halved). Occupancy 6 waves/CU - acceptable
//  because the binder is the shared LDS pipe, not latency.
//  Cross pass round-trips through f32 bO in global (block-private
//  rows, no sync hazard) instead of holding 64 VGPRs across main.
//  All swizzles / fragment mappings identical to r8 (qt-indexed).
// =====================================================================
__global__ __launch_bounds__(128, 2) void flash_kernel(
    const u16* __restrict__ Qc, const u16* __restrict__ Kc,
    const u16* __restrict__ Vc, int kvLenC,
    const u16* __restrict__ Qm, const u16* __restrict__ Km,
    const u16* __restrict__ Vm, int kvLenM,
    float* __restrict__ O, u16* __restrict__ Ob) {
  __shared__ u16 Ks[2][32 * 128];
  __shared__ u16 Vs[2][128 * 32];
  __shared__ u16 Pb[2][32 * 40];
  __shared__ float ab[4][16];

  const int tid = threadIdx.x;
  const int lane = tid & 63;
  const int w = tid >> 6;  // 0..1
  const int r = lane & 15;
  const int quad = lane >> 4;
  const int h = blockIdx.y;
  const int q0 = blockIdx.x * 64;
  const int fv = (r >> 1) & 3;  // V read-side involution (r8-verified)

  auto run_pass = [&](const u16* __restrict__ Q, const u16* __restrict__ K,
                      const u16* __restrict__ Vt, int kvLen, bool addO) {
    // Q fragments: qt-subtile q-row = q0 + 32w + 16qt + r
    short8 qf[2][4];
#pragma unroll
    for (int qt = 0; qt < 2; ++qt) {
      const u16* qbase = Q + (size_t)(q0 + 32 * w + 16 * qt + r) * 1536 + h * 128 + 8 * quad;
#pragma unroll
      for (int ks = 0; ks < 4; ++ks)
        qf[qt][ks] = *reinterpret_cast<const short8*>(qbase + 32 * ks);
    }

    // staging: uniform bases + 32-bit per-lane element offsets.
    // K tile 32x128: wave w stages rows 16w..16w+15 (4 async16).
    // V tile Vs[128][32]: wave w stages d rows 64w..64w+63 (4 async16).
    const u16* Kb = K + h * 128;
    const u16* Vb = Vt + (size_t)h * 128 * kvLen;
    u32 koff[4], voff[4];
    int klo[4], vlo[4];
    {
      const int p16 = lane & 15, rin = lane >> 4;
      const int p4 = lane & 3, din = lane >> 2;
#pragma unroll
      for (int j = 0; j < 4; ++j) {
        const int row = 16 * w + 4 * j + rin;
        koff[j] = (u32)row * 1536u + 8u * (u32)(p16 ^ (row & 15));
        klo[j] = (16 * w + 4 * j) * 128;
        const int d = 64 * w + 16 * j + din;
        voff[j] = (u32)d * (u32)kvLen + 8u * (u32)(p4 ^ ((d >> 1) & 3));
        vlo[j] = (64 * w + 16 * j) * 32;
      }
    }

    f32x4 Oc[2][8];
#pragma unroll
    for (int qt = 0; qt < 2; ++qt)
#pragma unroll
      for (int dt = 0; dt < 8; ++dt) Oc[qt][dt] = (f32x4){0.f, 0.f, 0.f, 0.f};
    float m_i[2] = {-1e30f, -1e30f}, l_i[2] = {0.f, 0.f};

    const int nt = kvLen >> 5;

    // prologue: stage tile 0 into buffer 0
#pragma unroll
    for (int j = 0; j < 4; ++j) async16(Kb + koff[j], &Ks[0][klo[j]]);
#pragma unroll
    for (int j = 0; j < 4; ++j) async16(Vb + voff[j], &Vs[0][vlo[j]]);

    for (int t = 0; t < nt; ++t) {
      const int buf = t & 1;
      __syncthreads();  // drains vmcnt(0): stage(t) complete AND all
                        // waves' buf^1 reads are done.
      if (t + 1 < nt) {
        const size_t ko = (size_t)(t + 1) * (32 * 1536);
        const size_t vo = (size_t)(t + 1) * 32;
#pragma unroll
        for (int j = 0; j < 4; ++j) async16(Kb + ko + koff[j], &Ks[buf ^ 1][klo[j]]);
#pragma unroll
        for (int j = 0; j < 4; ++j) async16(Vb + vo + voff[j], &Vs[buf ^ 1][vlo[j]]);
      }

      // S^T = K * Q^T (log2-domain; Q pre-scaled). K-frag shared by both qt.
      f32x4 St[2][2];
#pragma unroll
      for (int qt = 0; qt < 2; ++qt)
#pragma unroll
        for (int mt = 0; mt < 2; ++mt) St[qt][mt] = (f32x4){0.f, 0.f, 0.f, 0.f};
      __builtin_amdgcn_s_setprio(1);
#pragma unroll
      for (int mt = 0; mt < 2; ++mt) {
        const u16* kp = &Ks[buf][(16 * mt + r) * 128];
#pragma unroll
        for (int ks = 0; ks < 4; ++ks) {
          const short8 af = *reinterpret_cast<const short8*>(kp + 8 * ((quad + 4 * ks) ^ r));
#pragma unroll
          for (int qt = 0; qt < 2; ++qt)
            St[qt][mt] = __builtin_amdgcn_mfma_f32_16x16x32_bf16(af, qf[qt][ks], St[qt][mt], 0, 0, 0);
        }
      }
      __builtin_amdgcn_s_setprio(0);

      // online softmax per q-subtile (base 2); lane owns q-row 16qt+r
      uint2 pk[2][2];
#pragma unroll
      for (int qt = 0; qt < 2; ++qt) {
        float mloc = -1e30f;
#pragma unroll
        for (int mt = 0; mt < 2; ++mt)
#pragma unroll
          for (int rr = 0; rr < 4; ++rr) mloc = fmaxf(mloc, St[qt][mt][rr]);
        mloc = fmaxf(mloc, __shfl_xor(mloc, 16, 64));
        mloc = fmaxf(mloc, __shfl_xor(mloc, 32, 64));

        float alpha = 1.0f;
        if (__any(mloc > m_i[qt] + 11.5f)) {  // defer-max
          const float mn = fmaxf(m_i[qt], mloc);
          alpha = fexp2(m_i[qt] - mn);
          m_i[qt] = mn;
          if (quad == 0) ab[2 * w + qt][r] = alpha;
          const float4 a4 = *reinterpret_cast<const float4*>(&ab[2 * w + qt][4 * quad]);
#pragma unroll
          for (int dt = 0; dt < 8; ++dt) {
            Oc[qt][dt][0] *= a4.x; Oc[qt][dt][1] *= a4.y;
            Oc[qt][dt][2] *= a4.z; Oc[qt][dt][3] *= a4.w;
          }
        }

        float psum = 0.f;
#pragma unroll
        for (int mt = 0; mt < 2; ++mt) {
          const float p0 = fexp2(St[qt][mt][0] - m_i[qt]);
          const float p1 = fexp2(St[qt][mt][1] - m_i[qt]);
          const float p2 = fexp2(St[qt][mt][2] - m_i[qt]);
          const float p3 = fexp2(St[qt][mt][3] - m_i[qt]);
          psum += (p0 + p1) + (p2 + p3);
          pk[qt][mt].x = pack_bf16_rn(p0, p1);
          pk[qt][mt].y = pack_bf16_rn(p2, p3);
        }
        psum += __shfl_xor(psum, 16, 64);
        psum += __shfl_xor(psum, 32, 64);
        l_i[qt] = l_i[qt] * alpha + psum;
      }

      // PV: P is 32q x 32k; wave-private Pb; V-frag shared by both qt.
#pragma unroll
      for (int qt = 0; qt < 2; ++qt)
#pragma unroll
        for (int mt = 0; mt < 2; ++mt)
          *reinterpret_cast<uint2*>(&Pb[w][(16 * qt + r) * 40 + 16 * mt + 4 * quad]) = pk[qt][mt];
      {
        short8 pa[2];
#pragma unroll
        for (int qt = 0; qt < 2; ++qt)
          pa[qt] = *reinterpret_cast<const short8*>(&Pb[w][(16 * qt + r) * 40 + 8 * quad]);
        __builtin_amdgcn_s_setprio(1);
#pragma unroll
        for (int dt = 0; dt < 8; ++dt) {
          const int d = 16 * dt + r;
          const short8 b0 = *reinterpret_cast<const short8*>(&Vs[buf][d * 32 + 8 * (quad ^ fv)]);
#pragma unroll
          for (int qt = 0; qt < 2; ++qt)
            Oc[qt][dt] = __builtin_amdgcn_mfma_f32_16x16x32_bf16(pa[qt], b0, Oc[qt][dt], 0, 0, 0);
        }
        __builtin_amdgcn_s_setprio(0);
      }
    }

    // normalize by 1/l (LDS broadcast, wave-private) and store
#pragma unroll
    for (int qt = 0; qt < 2; ++qt) {
      if (quad == 0) ab[2 * w + qt][r] = 1.0f / l_i[qt];
      const float4 li4 = *reinterpret_cast<const float4*>(&ab[2 * w + qt][4 * quad]);
      const float lv[4] = {li4.x, li4.y, li4.z, li4.w};
      const int rowb = q0 + 32 * w + 16 * qt;
      float* obf = O + (size_t)rowb * 1536 + h * 128;
      u16* obb = Ob + (size_t)rowb * 1536 + h * 128;
#pragma unroll
      for (int rr = 0; rr < 4; ++rr) {
        float* orow = obf + (size_t)(4 * quad + rr) * 1536 + r;
        u16* brow = obb + (size_t)(4 * quad + rr) * 1536 + r;
#pragma unroll
        for (int dt = 0; dt < 8; ++dt) {
          float v = Oc[qt][dt][rr] * lv[rr];
          if (addO) {
            v += orow[16 * dt];
            brow[16 * dt] = f2b(v);
          } else {
            orow[16 * dt] = v;
          }
        }
      }
    }
  };

  // pass 1: cross-attn -> f32 bO (block-private rows; no sync hazard)
  run_pass(Qc, Kc, Vc, kvLenC, false);
  __syncthreads();  // all cross LDS reads done before main re-stages buf 0
  // pass 2: main attn, adds bO, writes bf16 bOb
  run_pass(Qm, Km, Vm, kvLenM, true);
}

// =====================================================================
// Host orchestration (8 dispatches)
// =====================================================================
extern "C" void kernel_launch(void* const* d_in, const int* in_sizes, int n_in,
                              void* d_out, int out_size, void* d_ws, size_t ws_size,
                              hipStream_t stream) {
  (void)in_sizes; (void)n_in; (void)out_size; (void)ws_size;
  constexpr int T = 4096, TR = 1024, DIM = 1536, NH = 12;

  const float* hs  = (const float*)d_in[0];
  const float* rhs = (const float*)d_in[1];
  const float* rc  = (const float*)d_in[2];
  const float* rs  = (const float*)d_in[3];
  const float* Wq  = (const float*)d_in[4];
  const float* bq  = (const float*)d_in[5];
  const float* Wk  = (const float*)d_in[6];
  const float* bk  = (const float*)d_in[7];
  const float* Wv  = (const float*)d_in[8];
  const float* bv  = (const float*)d_in[9];
  const float* Wkr = (const float*)d_in[10];
  const float* bkr = (const float*)d_in[11];
  const float* Wvr = (const float*)d_in[12];
  const float* bvr = (const float*)d_in[13];
  const float* Wo  = (const float*)d_in[14];
  const float* bo  = (const float*)d_in[15];
  const float* gq  = (const float*)d_in[16];
  const float* gk  = (const float*)d_in[17];
  float* out = (float*)d_out;

  char* ws = (char*)d_ws;
  size_t off = 0;
  auto alloc = [&](size_t bytes) -> void* {
    void* p = ws + off;
    off += (bytes + 255) & ~(size_t)255;
    return p;
  };
  u16* bQ    = (u16*)alloc((size_t)T * DIM * 2);
  u16* bQr   = (u16*)alloc((size_t)T * DIM * 2);
  u16* bK    = (u16*)alloc((size_t)T * DIM * 2);
  u16* bV    = (u16*)alloc((size_t)T * DIM * 2);
  u16* bKr   = (u16*)alloc((size_t)TR * DIM * 2);
  u16* bVr   = (u16*)alloc((size_t)TR * DIM * 2);
  float* bO  = (float*)alloc((size_t)T * DIM * 4);     // cross-attn out (f32)
  u16* bHs   = (u16*)alloc((size_t)T * DIM * 2);       // bf16 hs; ALIAS-> VtG
  u16* bRhs  = (u16*)alloc((size_t)TR * DIM * 2);      // bf16 rhs; ALIAS-> VtR
  u16* bWqkv = (u16*)alloc((size_t)3 * DIM * DIM * 2); // WqT|WkT|WvT; ALIAS-> bOb
  u16* bWr   = (u16*)alloc((size_t)2 * DIM * DIM * 2); // WkrT|WvrT
  u16* bWoT  = (u16*)alloc((size_t)DIM * DIM * 2);     // WoT (own slab)
  u16* VtG = bHs;
  u16* VtR = bRhs;
  u16* bOb = bWqkv;

  const dim3 blk(256);

  // 1. f32->bf16 converts (merged)
  conv2_kernel<<<dim3((T * DIM / 8 + TR * DIM / 8 + 255) / 256), blk, 0, stream>>>(
      hs, bHs, T * DIM / 8, rhs, bRhs, TR * DIM / 8);

  // 2. weight transpose-converts (all six merged)
  transconv6_kernel<<<dim3(24, 24, 6), blk, 0, stream>>>(
      Wq, Wk, Wv, Wkr, Wvr, Wo,
      bWqkv + 0 * (size_t)DIM * DIM, bWqkv + 1 * (size_t)DIM * DIM,
      bWqkv + 2 * (size_t)DIM * DIM, bWr + 0 * (size_t)DIM * DIM,
      bWr + 1 * (size_t)DIM * DIM, bWoT);

  // 3-4. projections (QKV fused 128-tile; KrVr 64-tile for occupancy)
  gemm128_kernel<4, u16><<<dim3(36, 32), blk, 0, stream>>>(
      bHs, DIM, bWqkv, DIM, bQ, bK, bV, DIM, bq, bk, bv, DIM);
  gemm128_kernel<2, u16><<<dim3(24, 16), blk, 0, stream>>>(
      bRhs, DIM, bWr, DIM, bKr, bVr, (u16*)nullptr, DIM, bkr, bvr, nullptr, DIM);

  // 5. rmsnorm/rope (merged; q-path pre-scaled by QS)
  rmsnorm3_kernel<<<dim3(T, 3), blk, 0, stream>>>(
      bQ, bK, bKr, gq, gk, rc, rs, bQ, bQr, bK, bKr);

  // 6. per-head V transposes (merged; alias buffers are dead)
  vtrans2_kernel<<<dim3(T / 64, NH, 2), blk, 0, stream>>>(bV, VtG, bVr, VtR);

  // 7. merged flash attention: cross (kv=1024, via f32 bO) + main (kv=4096)
  flash_kernel<<<dim3(T / 64, NH), dim3(128), 0, stream>>>(
      bQ, bKr, VtR, TR, bQr, bK, VtG, T, bO, bOb);

  // 8. output projection (64-row tiles for occupancy)
  gemm128_kernel<2, float><<<dim3(12, 64), blk, 0, stream>>>(
      bOb, DIM, bWoT, DIM, out, (float*)nullptr, (float*)nullptr, DIM, bo, nullptr, nullptr, DIM);
}

// Round 6
// 562.246 us; speedup vs baseline: 1.4710x; 1.0345x over previous
//
#include <hip/hip_runtime.h>

typedef unsigned short u16;
typedef unsigned int u32;
typedef __attribute__((ext_vector_type(8))) short short8;
typedef __attribute__((ext_vector_type(4))) short s16x4;
typedef __attribute__((ext_vector_type(2))) u32 u32x2;
typedef __attribute__((ext_vector_type(4))) float f32x4;

// ---------- bf16 helpers ----------
__device__ inline u16 f2b(float f) {  // RNE
  u32 u = __builtin_bit_cast(u32, f);
  u += 0x7fff + ((u >> 16) & 1);
  return (u16)(u >> 16);
}
__device__ inline float b2f(u16 u) {
  return __builtin_bit_cast(float, (u32)u << 16);
}
// round-to-nearest (ties away) pack — cheaper than RNE, used for P only
__device__ inline u32 pack_bf16_rn(float a, float b) {
  const u32 ua = __builtin_bit_cast(u32, a) + 0x8000u;
  const u32 ub = __builtin_bit_cast(u32, b) + 0x8000u;
  return (ua >> 16) | (ub & 0xffff0000u);
}
__device__ inline void c_store(float* p, float v) { *p = v; }
__device__ inline void c_store(u16* p, float v) { *p = f2b(v); }

__device__ inline float fexp2(float x) {
#if __has_builtin(__builtin_amdgcn_exp2f)
  return __builtin_amdgcn_exp2f(x);
#else
  return exp2f(x);
#endif
}

// 16x16x16 bf16 MFMA (K=16). A/B: 2 VGPRs (4 bf16, k = 4*quad + j);
// C/D: 16x16 standard layout (col = lane&15, row = 4*(lane>>4) + reg).
// Fallback: zero-padded K=32 via the (rounds-0-4-proven) 16x16x32
// intrinsic. Nonzero A slots land at k=8*quad+j and pair with the SAME
// B slots (8*quad+j) -> identical dot product; padded slots multiply
// by A=0 so B padding is irrelevant. No inline asm (r5 hardening).
__device__ inline f32x4 mfma16x16x16(s16x4 a, s16x4 b, f32x4 c) {
#if __has_builtin(__builtin_amdgcn_mfma_f32_16x16x16bf16_1k)
  return __builtin_amdgcn_mfma_f32_16x16x16bf16_1k(a, b, c, 0, 0, 0);
#else
  const short8 a8 = {a[0], a[1], a[2], a[3], 0, 0, 0, 0};
  const short8 b8 = {b[0], b[1], b[2], b[3], 0, 0, 0, 0};
  return __builtin_amdgcn_mfma_f32_16x16x32_bf16(a8, b8, c, 0, 0, 0);
#endif
}

// ---------- async global->LDS, 16B per lane ----------
typedef const __attribute__((address_space(1))) u32 gu32;
typedef __attribute__((address_space(3))) u32 lu32;
__device__ inline void async16(const u16* g, u16* l) {
  __builtin_amdgcn_global_load_lds((gu32*)g, (lu32*)l, 16, 0, 0);
}

// Q scale folded into rmsnorm producer: 1/sqrt(128) * log2(e)
#define QS (0.08838834764831843f * 1.4426950408889634f)

// =====================================================================
// (32*MI)x128x(K,BK=32) bf16 GEMM, m97 structure (verified r3-r6).
// =====================================================================
template <int MI, typename TC>
__global__ __launch_bounds__(256) void gemm128_kernel(
    const u16* __restrict__ A, long lda,
    const u16* __restrict__ Bt, long ldb,
    TC* __restrict__ C0, TC* __restrict__ C1, TC* __restrict__ C2, long ldc,
    const float* b0, const float* b1, const float* b2,
    int K) {
  __shared__ __align__(16) u16 As[32 * MI * 32];
  __shared__ __align__(16) u16 Bs[128 * 32];

  const int tid = threadIdx.x;
  const int lane = tid & 63;
  const int w = tid >> 6;
  const int r = lane & 15;
  const int quad = lane >> 4;
  const int m0 = blockIdx.y * (32 * MI);
  const int nb = blockIdx.x * 128;
  const int seg = nb / 1536;
  const int nc = nb - seg * 1536;
  TC* C = seg == 0 ? C0 : (seg == 1 ? C1 : C2);
  const float* bias = seg == 0 ? b0 : (seg == 1 ? b1 : b2);

  const int srow = lane >> 2;
  const int sx = ((lane & 3) ^ (srow & 3)) * 8;
  const u16* Ag = A + (size_t)(m0 + w * 8 * MI + srow) * lda + sx;
  const u16* Bg = Bt + (size_t)(nb + w * 32 + srow) * ldb + sx;
  u16* Al[MI / 2];
#pragma unroll
  for (int j = 0; j < MI / 2; ++j) Al[j] = &As[(w * 8 * MI + 16 * j) * 32];
  u16* const Bl0 = &Bs[(w * 32) * 32];
  u16* const Bl1 = &Bs[(w * 32 + 16) * 32];

  const int wm = (w >> 1) * (16 * MI);
  const int wn = (w & 1) * 64;

  f32x4 acc[MI][4];
#pragma unroll
  for (int i = 0; i < MI; ++i)
#pragma unroll
    for (int j = 0; j < 4; ++j) acc[i][j] = (f32x4){0.f, 0.f, 0.f, 0.f};

  const int fco = (quad ^ (r & 3)) * 8;

  for (int kk = 0; kk < K; kk += 32) {
    __syncthreads();
#pragma unroll
    for (int j = 0; j < MI / 2; ++j) async16(Ag + kk + (size_t)(16 * j) * lda, Al[j]);
    async16(Bg + kk, Bl0);
    async16(Bg + kk + 16 * ldb, Bl1);
    __syncthreads();

    short8 af[MI], bf[4];
#pragma unroll
    for (int mi = 0; mi < MI; ++mi)
      af[mi] = *reinterpret_cast<const short8*>(&As[(wm + 16 * mi + r) * 32 + fco]);
#pragma unroll
    for (int ni = 0; ni < 4; ++ni)
      bf[ni] = *reinterpret_cast<const short8*>(&Bs[(wn + 16 * ni + r) * 32 + fco]);
#pragma unroll
    for (int mi = 0; mi < MI; ++mi)
#pragma unroll
      for (int ni = 0; ni < 4; ++ni)
        acc[mi][ni] = __builtin_amdgcn_mfma_f32_16x16x32_bf16(af[mi], bf[ni], acc[mi][ni], 0, 0, 0);
  }

#pragma unroll
  for (int mi = 0; mi < MI; ++mi)
#pragma unroll
    for (int ni = 0; ni < 4; ++ni)
#pragma unroll
      for (int rr = 0; rr < 4; ++rr) {
        const int row = m0 + wm + 16 * mi + 4 * quad + rr;
        const int col = nc + wn + 16 * ni + r;
        c_store(&C[(size_t)row * ldc + col], acc[mi][ni][rr] + bias[col]);
      }
}

// =====================================================================
// Merged f32->bf16 convert for hs and rhs
// =====================================================================
__global__ __launch_bounds__(256) void conv2_kernel(
    const float* __restrict__ xa, u16* __restrict__ ya, int n8a,
    const float* __restrict__ xb, u16* __restrict__ yb, int n8b) {
  int i = blockIdx.x * 256 + threadIdx.x;
  const float* x;
  u16* y;
  if (i < n8a) {
    x = xa; y = ya;
  } else {
    i -= n8a;
    if (i >= n8b) return;
    x = xb; y = yb;
  }
  const float4 v0 = reinterpret_cast<const float4*>(x)[2 * i];
  const float4 v1 = reinterpret_cast<const float4*>(x)[2 * i + 1];
  uint4 rv;
  rv.x = (u32)f2b(v0.x) | ((u32)f2b(v0.y) << 16);
  rv.y = (u32)f2b(v0.z) | ((u32)f2b(v0.w) << 16);
  rv.z = (u32)f2b(v1.x) | ((u32)f2b(v1.y) << 16);
  rv.w = (u32)f2b(v1.z) | ((u32)f2b(v1.w) << 16);
  reinterpret_cast<uint4*>(y)[i] = rv;
}

// =====================================================================
// Transpose-convert, all 6 weights merged (W f32 [1536][1536] -> Wt^T bf16)
// =====================================================================
__device__ inline void transconv_body(const float* __restrict__ W, u16* __restrict__ Wt) {
  __shared__ __align__(16) u16 Ls[64 * 72];
  const int tid = threadIdx.x;
  const int k0 = blockIdx.y * 64;
  const int n0 = blockIdx.x * 64;
#pragma unroll
  for (int i = 0; i < 4; ++i) {
    const int c = tid + 256 * i;
    const int row = c >> 4;
    const int c4 = (c & 15) * 4;
    const float4 v = *reinterpret_cast<const float4*>(&W[(size_t)(k0 + row) * 1536 + n0 + c4]);
    Ls[(c4 + 0) * 72 + row] = f2b(v.x);
    Ls[(c4 + 1) * 72 + row] = f2b(v.y);
    Ls[(c4 + 2) * 72 + row] = f2b(v.z);
    Ls[(c4 + 3) * 72 + row] = f2b(v.w);
  }
  __syncthreads();
#pragma unroll
  for (int i = 0; i < 2; ++i) {
    const int c = tid + 256 * i;
    const int n = c >> 3;
    const int kc = (c & 7) * 8;
    u16 tmp[8];
#pragma unroll
    for (int j = 0; j < 8; ++j) tmp[j] = Ls[n * 72 + kc + j];
    *reinterpret_cast<uint4*>(&Wt[(size_t)(n0 + n) * 1536 + k0 + kc]) =
        *reinterpret_cast<const uint4*>(tmp);
  }
}

__global__ __launch_bounds__(256) void transconv6_kernel(
    const float* W0, const float* W1, const float* W2,
    const float* W3, const float* W4, const float* W5,
    u16* T0, u16* T1, u16* T2, u16* T3, u16* T4, u16* T5) {
  const int z = blockIdx.z;
  const float* W = z == 0 ? W0 : z == 1 ? W1 : z == 2 ? W2 : z == 3 ? W3 : z == 4 ? W4 : W5;
  u16* Wt = z == 0 ? T0 : z == 1 ? T1 : z == 2 ? T2 : z == 3 ? T3 : z == 4 ? T4 : T5;
  transconv_body(W, Wt);
}

// =====================================================================
// Merged RMSNorm: z=0 q-path (scaled by QS, plain+rope), z=1 k-path
// (rope), z=2 ref-k (1024 rows, plain). Verified r4-r6.
// =====================================================================
__global__ __launch_bounds__(256) void rmsnorm3_kernel(
    const u16* xq, const u16* xk, const u16* xkr,
    const float* gq, const float* gk,
    const float* rc, const float* rs,
    u16* oq_plain, u16* oq_rope, u16* ok_rope, u16* okr_plain) {
  __shared__ float red[4];
  const int z = blockIdx.y;
  const int row = blockIdx.x;
  if (z == 2 && row >= 1024) return;
  const u16* x; const float* g; u16* po; u16* pr; float sc;
  if (z == 0)      { x = xq;  g = gq; po = oq_plain; pr = oq_rope; sc = QS;  }
  else if (z == 1) { x = xk;  g = gk; po = nullptr;  pr = ok_rope; sc = 1.f; }
  else             { x = xkr; g = gk; po = okr_plain; pr = nullptr; sc = 1.f; }

  const int tid = threadIdx.x;
  const u32* xr = reinterpret_cast<const u32*>(x + (size_t)row * 1536);
  float xe[3], xo[3];
  float ss = 0.f;
#pragma unroll
  for (int j = 0; j < 3; ++j) {
    const u32 u = xr[tid + 256 * j];
    const float e = b2f((u16)(u & 0xffff));
    const float o = b2f((u16)(u >> 16));
    xe[j] = e; xo[j] = o;
    ss += e * e + o * o;
  }
#pragma unroll
  for (int off = 32; off; off >>= 1) ss += __shfl_xor(ss, off, 64);
  if ((tid & 63) == 0) red[tid >> 6] = ss;
  __syncthreads();
  const float total = red[0] + red[1] + red[2] + red[3];
  const float rinv = rsqrtf(total * (1.0f / 1536.0f) + 1e-6f) * sc;
  u32* po32 = po ? reinterpret_cast<u32*>(po + (size_t)row * 1536) : nullptr;
  u32* pr32 = pr ? reinterpret_cast<u32*>(pr + (size_t)row * 1536) : nullptr;
#pragma unroll
  for (int j = 0; j < 3; ++j) {
    const int p = tid + 256 * j;
    const float2 gg = reinterpret_cast<const float2*>(g)[p];
    const float e = xe[j] * rinv * gg.x;
    const float o = xo[j] * rinv * gg.y;
    if (po32) po32[p] = (u32)f2b(e) | ((u32)f2b(o) << 16);
    if (pr32) {
      const int i = p & 63;
      const float c = rc[row * 64 + i];
      const float s = rs[row * 64 + i];
      const float re = e * c - o * s;
      const float im = e * s + o * c;
      pr32[p] = (u32)f2b(re) | ((u32)f2b(im) << 16);
    }
  }
}

// =====================================================================
// Merged per-head V transpose (verified r4-r6)
// =====================================================================
__global__ __launch_bounds__(256) void vtrans2_kernel(
    const u16* __restrict__ V0, u16* __restrict__ Vt0,
    const u16* __restrict__ V1, u16* __restrict__ Vt1) {
  __shared__ __align__(16) u16 Ls[64 * 136];
  const int z = blockIdx.z;
  const int kvLen = z == 0 ? 4096 : 1024;
  const int kv0 = blockIdx.x * 64;
  if (kv0 >= kvLen) return;
  const u16* V = z == 0 ? V0 : V1;
  u16* Vt = z == 0 ? Vt0 : Vt1;
  const int tid = threadIdx.x;
  const int h = blockIdx.y;
#pragma unroll
  for (int i = 0; i < 4; ++i) {
    const int c = tid + 256 * i;
    const int row = c >> 4, c8 = c & 15;
    *reinterpret_cast<uint4*>(&Ls[row * 136 + 8 * c8]) =
        *reinterpret_cast<const uint4*>(V + (size_t)(kv0 + row) * 1536 + h * 128 + 8 * c8);
  }
  __syncthreads();
#pragma unroll
  for (int i = 0; i < 4; ++i) {
    const int c = tid + 256 * i;
    const int d = c >> 3, kc = c & 7;
    u16 tmp[8];
#pragma unroll
    for (int j = 0; j < 8; ++j) tmp[j] = Ls[(8 * kc + j) * 136 + d];
    *reinterpret_cast<uint4*>(Vt + ((size_t)h * 128 + d) * kvLen + kv0 + 8 * kc) =
        *reinterpret_cast<const uint4*>(tmp);
  }
}

// =====================================================================
// Flash attention, round-12 (= r11 hardened resubmit; no GPU signal r11).
//  Design: intra-tile kv-split pairs + fat-q.
//   - 4 waves/block (256 thr), grid 768 = 3 blocks/CU = 12 waves/CU.
//   - wave w: pair p=w>>1 owns kv rows [16p,16p+16) of EVERY 32-kv
//     tile; qh=w&1 owns q rows [32qh,32qh+32). Each wave reads only
//     half-K (4 b128) + half-V (8 b64) per tile.
//   - PV uses mfma 16x16x16 (K=16): its A-frag k-layout (4*quad+j)
//     EXACTLY matches QK^T's C-layout rows (4*quad+rr), so softmax
//     output feeds PV directly from registers — Pb LDS round-trip
//     deleted entirely.
//   - pairs run independent online-softmax over disjoint kv; merged
//     once per pass via LDS (scratch = K/V buffers, dead at merge).
//   - V b64 reads use the staging 16B-chunk swizzle (c ^ ((d>>1)&3)):
//     chunk c_lin = 2p + (quad>>1), half = quad&1 -> 2-way (free).
//  LDS: Ka 16K + Va 16K + small = ~33.3 KB. Cross pass result round-
//  trips through f32 bO (r4-style) to avoid 64-VGPR carry.
//  r12 hardening vs r11: no inline-asm MFMA fallback (zero-padded
//  16x16x32 instead); __align__(16) on LDS arrays.
// =====================================================================
__global__ __launch_bounds__(256, 3) void flash_kernel(
    const u16* __restrict__ Qc, const u16* __restrict__ Kc,
    const u16* __restrict__ Vc, int kvLenC,
    const u16* __restrict__ Qm, const u16* __restrict__ Km,
    const u16* __restrict__ Vm, int kvLenM,
    float* __restrict__ O, u16* __restrict__ Ob) {
  __shared__ __align__(16) u16 Ka[2][32 * 128];    // K tiles (dbuf); scratch qh=0
  __shared__ __align__(16) u16 Va[2][128 * 32];    // V^T tiles (dbuf); scratch qh=1
  __shared__ __align__(16) float ab[4][2][16];     // per-wave row-factor broadcast
  __shared__ __align__(16) float ab0[2][2][16];    // pair0 factor (merge)
  __shared__ __align__(16) float2 mlb[2][2][16];   // pair0 (m,l) (merge)

  const int tid = threadIdx.x;
  const int lane = tid & 63;
  const int w = tid >> 6;
  const int p = w >> 1;   // kv-half of each tile
  const int qh = w & 1;   // q-half of the 64-q block
  const int r = lane & 15;
  const int quad = lane >> 4;
  const int h = blockIdx.y;
  const int q0 = blockIdx.x * 64;

  auto run_pass = [&](const u16* __restrict__ Q, const u16* __restrict__ K,
                      const u16* __restrict__ Vt, int kvLen, bool addO) {
    __syncthreads();  // scratch reads from a previous merge are done

    // Q fragments: q-row = q0 + 32*qh + 16*qt + r
    short8 qf[2][4];
#pragma unroll
    for (int qt = 0; qt < 2; ++qt) {
      const u16* qbase = Q + (size_t)(q0 + 32 * qh + 16 * qt + r) * 1536 + h * 128 + 8 * quad;
#pragma unroll
      for (int ks = 0; ks < 4; ++ks)
        qf[qt][ks] = *reinterpret_cast<const short8*>(qbase + 32 * ks);
    }

    // cooperative staging (all 4 waves), identical swizzles to r2/r8
    const u16* Kb = K + h * 128;
    const u16* Vb = Vt + (size_t)h * 128 * kvLen;
    u32 koff[2], voff[2];
    int klo[2], vlo[2];
    {
      const int p16 = lane & 15, rin = lane >> 4;
      const int p4 = lane & 3, din = lane >> 2;
#pragma unroll
      for (int j = 0; j < 2; ++j) {
        const int row = 8 * w + 4 * j + rin;
        koff[j] = (u32)row * 1536u + 8u * (u32)(p16 ^ (row & 15));
        klo[j] = (8 * w + 4 * j) * 128;
        const int d = 32 * w + 16 * j + din;
        voff[j] = (u32)d * (u32)kvLen + 8u * (u32)(p4 ^ ((din >> 1) & 3));
        vlo[j] = (32 * w + 16 * j) * 32;
      }
    }

    f32x4 Oc[2][8];
#pragma unroll
    for (int qt = 0; qt < 2; ++qt)
#pragma unroll
      for (int dt = 0; dt < 8; ++dt) Oc[qt][dt] = (f32x4){0.f, 0.f, 0.f, 0.f};
    float m_i[2] = {-1e30f, -1e30f}, l_i[2] = {0.f, 0.f};

    const int nt = kvLen >> 5;

    // prologue: stage tile 0 into buffer 0
#pragma unroll
    for (int j = 0; j < 2; ++j) async16(Kb + koff[j], &Ka[0][klo[j]]);
#pragma unroll
    for (int j = 0; j < 2; ++j) async16(Vb + voff[j], &Va[0][vlo[j]]);

    for (int t = 0; t < nt; ++t) {
      const int buf = t & 1;
      __syncthreads();  // stage(t) complete; buf^1 reads (t-1) done
      if (t + 1 < nt) {
        const size_t ko = (size_t)(t + 1) * (32 * 1536);
        const size_t vo = (size_t)(t + 1) * 32;
#pragma unroll
        for (int j = 0; j < 2; ++j) async16(Kb + ko + koff[j], &Ka[buf ^ 1][klo[j]]);
#pragma unroll
        for (int j = 0; j < 2; ++j) async16(Vb + vo + voff[j], &Va[buf ^ 1][vlo[j]]);
      }

      // ---- QK^T over pair's 16 kv rows (m = kv = 16p + r) ----
      const u16* kp = &Ka[buf][(16 * p + r) * 128];
      short8 af[4];
#pragma unroll
      for (int ks = 0; ks < 4; ++ks)
        af[ks] = *reinterpret_cast<const short8*>(kp + 8 * ((quad + 4 * ks) ^ r));
      f32x4 St[2];
#pragma unroll
      for (int qt = 0; qt < 2; ++qt) St[qt] = (f32x4){0.f, 0.f, 0.f, 0.f};
      __builtin_amdgcn_s_setprio(1);
#pragma unroll
      for (int ks = 0; ks < 4; ++ks)
#pragma unroll
        for (int qt = 0; qt < 2; ++qt)
          St[qt] = __builtin_amdgcn_mfma_f32_16x16x32_bf16(af[ks], qf[qt][ks], St[qt], 0, 0, 0);
      __builtin_amdgcn_s_setprio(0);

      // ---- online softmax (base 2); lane owns q-row r, kv 4*quad+rr ----
      s16x4 pa[2];
#pragma unroll
      for (int qt = 0; qt < 2; ++qt) {
        float mloc = fmaxf(fmaxf(St[qt][0], St[qt][1]), fmaxf(St[qt][2], St[qt][3]));
        mloc = fmaxf(mloc, __shfl_xor(mloc, 16, 64));
        mloc = fmaxf(mloc, __shfl_xor(mloc, 32, 64));
        float alpha = 1.0f;
        if (__any(mloc > m_i[qt] + 11.5f)) {  // defer-max
          const float mn = fmaxf(m_i[qt], mloc);
          alpha = fexp2(m_i[qt] - mn);
          m_i[qt] = mn;
          if (quad == 0) ab[w][qt][r] = alpha;
          const float4 a4 = *reinterpret_cast<const float4*>(&ab[w][qt][4 * quad]);
#pragma unroll
          for (int dt = 0; dt < 8; ++dt) {
            Oc[qt][dt][0] *= a4.x; Oc[qt][dt][1] *= a4.y;
            Oc[qt][dt][2] *= a4.z; Oc[qt][dt][3] *= a4.w;
          }
        }
        const float p0 = fexp2(St[qt][0] - m_i[qt]);
        const float p1 = fexp2(St[qt][1] - m_i[qt]);
        const float p2 = fexp2(St[qt][2] - m_i[qt]);
        const float p3 = fexp2(St[qt][3] - m_i[qt]);
        float psum = (p0 + p1) + (p2 + p3);
        psum += __shfl_xor(psum, 16, 64);
        psum += __shfl_xor(psum, 32, 64);
        l_i[qt] = l_i[qt] * alpha + psum;
        // P -> bf16: (p0..p3) IS the 16x16x16 A-frag (k = 4*quad+j)
        pa[qt] = __builtin_bit_cast(s16x4, (u32x2){pack_bf16_rn(p0, p1), pack_bf16_rn(p2, p3)});
      }

      // ---- PV over pair's 16 kv (K=16 MFMA); A from regs, B from Va ----
      s16x4 vf[8];
#pragma unroll
      for (int dt = 0; dt < 8; ++dt) {
        const int d = 16 * dt + r;
        const int cst = (2 * p + (quad >> 1)) ^ ((r >> 1) & 3);
        vf[dt] = *reinterpret_cast<const s16x4*>(&Va[buf][d * 32 + 8 * cst + 4 * (quad & 1)]);
      }
      __builtin_amdgcn_s_setprio(1);
#pragma unroll
      for (int dt = 0; dt < 8; ++dt)
#pragma unroll
        for (int qt = 0; qt < 2; ++qt)
          Oc[qt][dt] = mfma16x16x16(pa[qt], vf[dt], Oc[qt][dt]);
      __builtin_amdgcn_s_setprio(0);
    }

    // ---- pair merge: combine (m,l,O) across p=0/1 for same q rows ----
    __syncthreads();  // all tile reads done; K/V buffers become scratch
    float* sc = (qh == 0) ? reinterpret_cast<float*>(&Ka[0][0])
                          : reinterpret_cast<float*>(&Va[0][0]);
    if (p == 0) {
      if (quad == 0) {
#pragma unroll
        for (int qt = 0; qt < 2; ++qt) mlb[qh][qt][r] = (float2){m_i[qt], l_i[qt]};
      }
#pragma unroll
      for (int qt = 0; qt < 2; ++qt)
#pragma unroll
        for (int dt = 0; dt < 8; ++dt)
#pragma unroll
          for (int rr = 0; rr < 4; ++rr)
            sc[(16 * qt + 4 * quad + rr) * 128 + 16 * dt + r] = Oc[qt][dt][rr];
    }
    __syncthreads();
    if (p == 1) {
#pragma unroll
      for (int qt = 0; qt < 2; ++qt) {
        const float2 ml0 = mlb[qh][qt][r];
        const float m = fmaxf(ml0.x, m_i[qt]);
        const float s0 = fexp2(ml0.x - m), s1 = fexp2(m_i[qt] - m);
        const float rinv = 1.0f / (ml0.y * s0 + l_i[qt] * s1);
        if (quad == 0) { ab[w][qt][r] = s1 * rinv; ab0[qh][qt][r] = s0 * rinv; }
      }
      // same-wave LDS in-order: reads below see quad0's writes
#pragma unroll
      for (int qt = 0; qt < 2; ++qt) {
        const float4 a1 = *reinterpret_cast<const float4*>(&ab[w][qt][4 * quad]);
        const float4 a0 = *reinterpret_cast<const float4*>(&ab0[qh][qt][4 * quad]);
        const float a1v[4] = {a1.x, a1.y, a1.z, a1.w};
        const float a0v[4] = {a0.x, a0.y, a0.z, a0.w};
        const int rowb = q0 + 32 * qh + 16 * qt;
#pragma unroll
        for (int rr = 0; rr < 4; ++rr) {
          float* orow = O + (size_t)(rowb + 4 * quad + rr) * 1536 + h * 128 + r;
          u16* brow = Ob + (size_t)(rowb + 4 * quad + rr) * 1536 + h * 128 + r;
#pragma unroll
          for (int dt = 0; dt < 8; ++dt) {
            const float o0 = sc[(16 * qt + 4 * quad + rr) * 128 + 16 * dt + r];
            float v = Oc[qt][dt][rr] * a1v[rr] + o0 * a0v[rr];
            if (addO) {
              v += orow[16 * dt];
              brow[16 * dt] = f2b(v);
            } else {
              orow[16 * dt] = v;
            }
          }
        }
      }
    }
  };

  // pass 1: cross-attn -> f32 bO (block-private rows; no sync hazard)
  run_pass(Qc, Kc, Vc, kvLenC, false);
  // pass 2: main attn, adds bO, writes bf16 bOb
  run_pass(Qm, Km, Vm, kvLenM, true);
}

// =====================================================================
// Host orchestration (8 dispatches)
// =====================================================================
extern "C" void kernel_launch(void* const* d_in, const int* in_sizes, int n_in,
                              void* d_out, int out_size, void* d_ws, size_t ws_size,
                              hipStream_t stream) {
  (void)in_sizes; (void)n_in; (void)out_size; (void)ws_size;
  constexpr int T = 4096, TR = 1024, DIM = 1536, NH = 12;

  const float* hs  = (const float*)d_in[0];
  const float* rhs = (const float*)d_in[1];
  const float* rc  = (const float*)d_in[2];
  const float* rs  = (const float*)d_in[3];
  const float* Wq  = (const float*)d_in[4];
  const float* bq  = (const float*)d_in[5];
  const float* Wk  = (const float*)d_in[6];
  const float* bk  = (const float*)d_in[7];
  const float* Wv  = (const float*)d_in[8];
  const float* bv  = (const float*)d_in[9];
  const float* Wkr = (const float*)d_in[10];
  const float* bkr = (const float*)d_in[11];
  const float* Wvr = (const float*)d_in[12];
  const float* bvr = (const float*)d_in[13];
  const float* Wo  = (const float*)d_in[14];
  const float* bo  = (const float*)d_in[15];
  const float* gq  = (const float*)d_in[16];
  const float* gk  = (const float*)d_in[17];
  float* out = (float*)d_out;

  char* ws = (char*)d_ws;
  size_t off = 0;
  auto alloc = [&](size_t bytes) -> void* {
    void* p = ws + off;
    off += (bytes + 255) & ~(size_t)255;
    return p;
  };
  u16* bQ    = (u16*)alloc((size_t)T * DIM * 2);
  u16* bQr   = (u16*)alloc((size_t)T * DIM * 2);
  u16* bK    = (u16*)alloc((size_t)T * DIM * 2);
  u16* bV    = (u16*)alloc((size_t)T * DIM * 2);
  u16* bKr   = (u16*)alloc((size_t)TR * DIM * 2);
  u16* bVr   = (u16*)alloc((size_t)TR * DIM * 2);
  float* bO  = (float*)alloc((size_t)T * DIM * 4);     // cross-attn out (f32)
  u16* bHs   = (u16*)alloc((size_t)T * DIM * 2);       // bf16 hs; ALIAS-> VtG
  u16* bRhs  = (u16*)alloc((size_t)TR * DIM * 2);      // bf16 rhs; ALIAS-> VtR
  u16* bWqkv = (u16*)alloc((size_t)3 * DIM * DIM * 2); // WqT|WkT|WvT; ALIAS-> bOb
  u16* bWr   = (u16*)alloc((size_t)2 * DIM * DIM * 2); // WkrT|WvrT
  u16* bWoT  = (u16*)alloc((size_t)DIM * DIM * 2);     // WoT (own slab)
  u16* VtG = bHs;
  u16* VtR = bRhs;
  u16* bOb = bWqkv;

  const dim3 blk(256);

  // 1. f32->bf16 converts (merged)
  conv2_kernel<<<dim3((T * DIM / 8 + TR * DIM / 8 + 255) / 256), blk, 0, stream>>>(
      hs, bHs, T * DIM / 8, rhs, bRhs, TR * DIM / 8);

  // 2. weight transpose-converts (all six merged)
  transconv6_kernel<<<dim3(24, 24, 6), blk, 0, stream>>>(
      Wq, Wk, Wv, Wkr, Wvr, Wo,
      bWqkv + 0 * (size_t)DIM * DIM, bWqkv + 1 * (size_t)DIM * DIM,
      bWqkv + 2 * (size_t)DIM * DIM, bWr + 0 * (size_t)DIM * DIM,
      bWr + 1 * (size_t)DIM * DIM, bWoT);

  // 3-4. projections (QKV fused 128-tile; KrVr 64-tile for occupancy)
  gemm128_kernel<4, u16><<<dim3(36, 32), blk, 0, stream>>>(
      bHs, DIM, bWqkv, DIM, bQ, bK, bV, DIM, bq, bk, bv, DIM);
  gemm128_kernel<2, u16><<<dim3(24, 16), blk, 0, stream>>>(
      bRhs, DIM, bWr, DIM, bKr, bVr, (u16*)nullptr, DIM, bkr, bvr, nullptr, DIM);

  // 5. rmsnorm/rope (merged; q-path pre-scaled by QS)
  rmsnorm3_kernel<<<dim3(T, 3), blk, 0, stream>>>(
      bQ, bK, bKr, gq, gk, rc, rs, bQ, bQr, bK, bKr);

  // 6. per-head V transposes (merged; alias buffers are dead)
  vtrans2_kernel<<<dim3(T / 64, NH, 2), blk, 0, stream>>>(bV, VtG, bVr, VtR);

  // 7. merged flash attention: cross (kv=1024, via f32 bO) + main (kv=4096)
  flash_kernel<<<dim3(T / 64, NH), blk, 0, stream>>>(
      bQ, bKr, VtR, TR, bQr, bK, VtG, T, bO, bOb);

  // 8. output projection (64-row tiles for occupancy)
  gemm128_kernel<2, float><<<dim3(12, 64), blk, 0, stream>>>(
      bOb, DIM, bWoT, DIM, out, (float*)nullptr, (float*)nullptr, DIM, bo, nullptr, nullptr, DIM);
}

// Round 7
// 533.280 us; speedup vs baseline: 1.5509x; 1.0543x over previous
//
#include <hip/hip_runtime.h>

typedef unsigned short u16;
typedef unsigned int u32;
typedef __attribute__((ext_vector_type(8))) short short8;
typedef __attribute__((ext_vector_type(4))) float f32x4;

// ---------- bf16 helpers ----------
__device__ inline u16 f2b(float f) {  // RNE
  u32 u = __builtin_bit_cast(u32, f);
  u += 0x7fff + ((u >> 16) & 1);
  return (u16)(u >> 16);
}
__device__ inline float b2f(u16 u) {
  return __builtin_bit_cast(float, (u32)u << 16);
}
// round-to-nearest (ties away) pack — cheaper than RNE, used for P only
__device__ inline u32 pack_bf16_rn(float a, float b) {
  const u32 ua = __builtin_bit_cast(u32, a) + 0x8000u;
  const u32 ub = __builtin_bit_cast(u32, b) + 0x8000u;
  return (ua >> 16) | (ub & 0xffff0000u);
}
__device__ inline void c_store(float* p, float v) { *p = v; }
__device__ inline void c_store(u16* p, float v) { *p = f2b(v); }

__device__ inline float fexp2(float x) {
#if __has_builtin(__builtin_amdgcn_exp2f)
  return __builtin_amdgcn_exp2f(x);
#else
  return exp2f(x);
#endif
}

// ---------- async global->LDS, 16B per lane ----------
typedef const __attribute__((address_space(1))) u32 gu32;
typedef __attribute__((address_space(3))) u32 lu32;
__device__ inline void async16(const u16* g, u16* l) {
  __builtin_amdgcn_global_load_lds((gu32*)g, (lu32*)l, 16, 0, 0);
}

// Q scale folded into rmsnorm producer: 1/sqrt(128) * log2(e)
#define QS (0.08838834764831843f * 1.4426950408889634f)

// =====================================================================
// (32*MI)x128x(K,BK=32) bf16 GEMM, m97 structure (verified r3-r6).
// MI=4: 128-row tile. MI=2: 64-row tile for occupancy-starved shapes.
// r13: XCD-locality block remap (T1 variant). Requires gridDim.y % 8
// == 0 (holds for all three call sites). XCD x (empirically lin%8)
// owns A-row panels by in [x*ny/8, (x+1)*ny/8) — per-XCD A chunk
// (<=3.1 MB) stays L2-resident; B panels stream, each shared by ny/8
// temporally-adjacent blocks. Cuts cross-XCD operand re-fetch.
// =====================================================================
template <int MI, typename TC>
__global__ __launch_bounds__(256) void gemm128_kernel(
    const u16* __restrict__ A, long lda,
    const u16* __restrict__ Bt, long ldb,
    TC* __restrict__ C0, TC* __restrict__ C1, TC* __restrict__ C2, long ldc,
    const float* b0, const float* b1, const float* b2,
    int K) {
  __shared__ __align__(16) u16 As[32 * MI * 32];
  __shared__ __align__(16) u16 Bs[128 * 32];

  const int tid = threadIdx.x;
  const int lane = tid & 63;
  const int w = tid >> 6;
  const int r = lane & 15;
  const int quad = lane >> 4;

  // ---- XCD-locality remap (bijective when ny % 8 == 0) ----
  int bx = blockIdx.x, by = blockIdx.y;
  {
    const int ny = gridDim.y;
    if ((ny & 7) == 0) {
      const int lin = by * gridDim.x + bx;
      const int xcd = lin & 7;
      const int k = lin >> 3;
      const int rpx = ny >> 3;                 // A-row panels per XCD
      by = xcd * rpx + (k % rpx);
      bx = k / rpx;
    }
  }
  const int m0 = by * (32 * MI);
  const int nb = bx * 128;
  const int seg = nb / 1536;
  const int nc = nb - seg * 1536;
  TC* C = seg == 0 ? C0 : (seg == 1 ? C1 : C2);
  const float* bias = seg == 0 ? b0 : (seg == 1 ? b1 : b2);

  const int srow = lane >> 2;
  const int sx = ((lane & 3) ^ (srow & 3)) * 8;
  const u16* Ag = A + (size_t)(m0 + w * 8 * MI + srow) * lda + sx;
  const u16* Bg = Bt + (size_t)(nb + w * 32 + srow) * ldb + sx;
  u16* Al[MI / 2];
#pragma unroll
  for (int j = 0; j < MI / 2; ++j) Al[j] = &As[(w * 8 * MI + 16 * j) * 32];
  u16* const Bl0 = &Bs[(w * 32) * 32];
  u16* const Bl1 = &Bs[(w * 32 + 16) * 32];

  const int wm = (w >> 1) * (16 * MI);
  const int wn = (w & 1) * 64;

  f32x4 acc[MI][4];
#pragma unroll
  for (int i = 0; i < MI; ++i)
#pragma unroll
    for (int j = 0; j < 4; ++j) acc[i][j] = (f32x4){0.f, 0.f, 0.f, 0.f};

  const int fco = (quad ^ (r & 3)) * 8;

  for (int kk = 0; kk < K; kk += 32) {
    __syncthreads();
#pragma unroll
    for (int j = 0; j < MI / 2; ++j) async16(Ag + kk + (size_t)(16 * j) * lda, Al[j]);
    async16(Bg + kk, Bl0);
    async16(Bg + kk + 16 * ldb, Bl1);
    __syncthreads();

    short8 af[MI], bf[4];
#pragma unroll
    for (int mi = 0; mi < MI; ++mi)
      af[mi] = *reinterpret_cast<const short8*>(&As[(wm + 16 * mi + r) * 32 + fco]);
#pragma unroll
    for (int ni = 0; ni < 4; ++ni)
      bf[ni] = *reinterpret_cast<const short8*>(&Bs[(wn + 16 * ni + r) * 32 + fco]);
#pragma unroll
    for (int mi = 0; mi < MI; ++mi)
#pragma unroll
      for (int ni = 0; ni < 4; ++ni)
        acc[mi][ni] = __builtin_amdgcn_mfma_f32_16x16x32_bf16(af[mi], bf[ni], acc[mi][ni], 0, 0, 0);
  }

#pragma unroll
  for (int mi = 0; mi < MI; ++mi)
#pragma unroll
    for (int ni = 0; ni < 4; ++ni)
#pragma unroll
      for (int rr = 0; rr < 4; ++rr) {
        const int row = m0 + wm + 16 * mi + 4 * quad + rr;
        const int col = nc + wn + 16 * ni + r;
        c_store(&C[(size_t)row * ldc + col], acc[mi][ni][rr] + bias[col]);
      }
}

// =====================================================================
// Merged f32->bf16 convert for hs and rhs
// =====================================================================
__global__ __launch_bounds__(256) void conv2_kernel(
    const float* __restrict__ xa, u16* __restrict__ ya, int n8a,
    const float* __restrict__ xb, u16* __restrict__ yb, int n8b) {
  int i = blockIdx.x * 256 + threadIdx.x;
  const float* x;
  u16* y;
  if (i < n8a) {
    x = xa; y = ya;
  } else {
    i -= n8a;
    if (i >= n8b) return;
    x = xb; y = yb;
  }
  const float4 v0 = reinterpret_cast<const float4*>(x)[2 * i];
  const float4 v1 = reinterpret_cast<const float4*>(x)[2 * i + 1];
  uint4 rv;
  rv.x = (u32)f2b(v0.x) | ((u32)f2b(v0.y) << 16);
  rv.y = (u32)f2b(v0.z) | ((u32)f2b(v0.w) << 16);
  rv.z = (u32)f2b(v1.x) | ((u32)f2b(v1.y) << 16);
  rv.w = (u32)f2b(v1.z) | ((u32)f2b(v1.w) << 16);
  reinterpret_cast<uint4*>(y)[i] = rv;
}

// =====================================================================
// Transpose-convert, all 6 weights merged (W f32 [1536][1536] -> Wt^T bf16)
// =====================================================================
__device__ inline void transconv_body(const float* __restrict__ W, u16* __restrict__ Wt) {
  __shared__ __align__(16) u16 Ls[64 * 72];
  const int tid = threadIdx.x;
  const int k0 = blockIdx.y * 64;
  const int n0 = blockIdx.x * 64;
#pragma unroll
  for (int i = 0; i < 4; ++i) {
    const int c = tid + 256 * i;
    const int row = c >> 4;
    const int c4 = (c & 15) * 4;
    const float4 v = *reinterpret_cast<const float4*>(&W[(size_t)(k0 + row) * 1536 + n0 + c4]);
    Ls[(c4 + 0) * 72 + row] = f2b(v.x);
    Ls[(c4 + 1) * 72 + row] = f2b(v.y);
    Ls[(c4 + 2) * 72 + row] = f2b(v.z);
    Ls[(c4 + 3) * 72 + row] = f2b(v.w);
  }
  __syncthreads();
#pragma unroll
  for (int i = 0; i < 2; ++i) {
    const int c = tid + 256 * i;
    const int n = c >> 3;
    const int kc = (c & 7) * 8;
    u16 tmp[8];
#pragma unroll
    for (int j = 0; j < 8; ++j) tmp[j] = Ls[n * 72 + kc + j];
    *reinterpret_cast<uint4*>(&Wt[(size_t)(n0 + n) * 1536 + k0 + kc]) =
        *reinterpret_cast<const uint4*>(tmp);
  }
}

__global__ __launch_bounds__(256) void transconv6_kernel(
    const float* W0, const float* W1, const float* W2,
    const float* W3, const float* W4, const float* W5,
    u16* T0, u16* T1, u16* T2, u16* T3, u16* T4, u16* T5) {
  const int z = blockIdx.z;
  const float* W = z == 0 ? W0 : z == 1 ? W1 : z == 2 ? W2 : z == 3 ? W3 : z == 4 ? W4 : W5;
  u16* Wt = z == 0 ? T0 : z == 1 ? T1 : z == 2 ? T2 : z == 3 ? T3 : z == 4 ? T4 : T5;
  transconv_body(W, Wt);
}

// =====================================================================
// Merged RMSNorm: z=0 q-path (scaled by QS, plain+rope), z=1 k-path
// (rope), z=2 ref-k (1024 rows, plain). Verified r4-r6.
// =====================================================================
__global__ __launch_bounds__(256) void rmsnorm3_kernel(
    const u16* xq, const u16* xk, const u16* xkr,
    const float* gq, const float* gk,
    const float* rc, const float* rs,
    u16* oq_plain, u16* oq_rope, u16* ok_rope, u16* okr_plain) {
  __shared__ float red[4];
  const int z = blockIdx.y;
  const int row = blockIdx.x;
  if (z == 2 && row >= 1024) return;
  const u16* x; const float* g; u16* po; u16* pr; float sc;
  if (z == 0)      { x = xq;  g = gq; po = oq_plain; pr = oq_rope; sc = QS;  }
  else if (z == 1) { x = xk;  g = gk; po = nullptr;  pr = ok_rope; sc = 1.f; }
  else             { x = xkr; g = gk; po = okr_plain; pr = nullptr; sc = 1.f; }

  const int tid = threadIdx.x;
  const u32* xr = reinterpret_cast<const u32*>(x + (size_t)row * 1536);
  float xe[3], xo[3];
  float ss = 0.f;
#pragma unroll
  for (int j = 0; j < 3; ++j) {
    const u32 u = xr[tid + 256 * j];
    const float e = b2f((u16)(u & 0xffff));
    const float o = b2f((u16)(u >> 16));
    xe[j] = e; xo[j] = o;
    ss += e * e + o * o;
  }
#pragma unroll
  for (int off = 32; off; off >>= 1) ss += __shfl_xor(ss, off, 64);
  if ((tid & 63) == 0) red[tid >> 6] = ss;
  __syncthreads();
  const float total = red[0] + red[1] + red[2] + red[3];
  const float rinv = rsqrtf(total * (1.0f / 1536.0f) + 1e-6f) * sc;
  u32* po32 = po ? reinterpret_cast<u32*>(po + (size_t)row * 1536) : nullptr;
  u32* pr32 = pr ? reinterpret_cast<u32*>(pr + (size_t)row * 1536) : nullptr;
#pragma unroll
  for (int j = 0; j < 3; ++j) {
    const int p = tid + 256 * j;
    const float2 gg = reinterpret_cast<const float2*>(g)[p];
    const float e = xe[j] * rinv * gg.x;
    const float o = xo[j] * rinv * gg.y;
    if (po32) po32[p] = (u32)f2b(e) | ((u32)f2b(o) << 16);
    if (pr32) {
      const int i = p & 63;
      const float c = rc[row * 64 + i];
      const float s = rs[row * 64 + i];
      const float re = e * c - o * s;
      const float im = e * s + o * c;
      pr32[p] = (u32)f2b(re) | ((u32)f2b(im) << 16);
    }
  }
}

// =====================================================================
// Merged per-head V transpose (verified r4-r6)
// =====================================================================
__global__ __launch_bounds__(256) void vtrans2_kernel(
    const u16* __restrict__ V0, u16* __restrict__ Vt0,
    const u16* __restrict__ V1, u16* __restrict__ Vt1) {
  __shared__ __align__(16) u16 Ls[64 * 136];
  const int z = blockIdx.z;
  const int kvLen = z == 0 ? 4096 : 1024;
  const int kv0 = blockIdx.x * 64;
  if (kv0 >= kvLen) return;
  const u16* V = z == 0 ? V0 : V1;
  u16* Vt = z == 0 ? Vt0 : Vt1;
  const int tid = threadIdx.x;
  const int h = blockIdx.y;
#pragma unroll
  for (int i = 0; i < 4; ++i) {
    const int c = tid + 256 * i;
    const int row = c >> 4, c8 = c & 15;
    *reinterpret_cast<uint4*>(&Ls[row * 136 + 8 * c8]) =
        *reinterpret_cast<const uint4*>(V + (size_t)(kv0 + row) * 1536 + h * 128 + 8 * c8);
  }
  __syncthreads();
#pragma unroll
  for (int i = 0; i < 4; ++i) {
    const int c = tid + 256 * i;
    const int d = c >> 3, kc = c & 7;
    u16 tmp[8];
#pragma unroll
    for (int j = 0; j < 8; ++j) tmp[j] = Ls[(8 * kc + j) * 136 + d];
    *reinterpret_cast<uint4*>(Vt + ((size_t)h * 128 + d) * kvLen + kv0 + 8 * kc) =
        *reinterpret_cast<const uint4*>(tmp);
  }
}

// =====================================================================
// Flash attention — EXACT r0 kernel (best measured: 183.5 µs main +
// ~48 µs cross). Reverted after r7-r12 restructures failed to beat it
// (r12 kv-split: +33% MfmaUtil but 16.5M bank conflicts, net slower).
// =====================================================================
__global__ __launch_bounds__(256, 4) void flash_kernel(
    const u16* __restrict__ Q, const u16* __restrict__ K,
    const u16* __restrict__ Vt, float* __restrict__ O,
    u16* __restrict__ Ob, int kvLen, int addO) {
  __shared__ __align__(16) u16 Ks[64 * 128];
  __shared__ __align__(16) u16 Vs[128 * 64];
  __shared__ __align__(16) u16 Pb[4][16 * 40];
  __shared__ __align__(16) float ab[4][16];

  const int tid = threadIdx.x;
  const int lane = tid & 63;
  const int w = tid >> 6;
  const int r = lane & 15;
  const int quad = lane >> 4;
  const int h = blockIdx.y;
  const int q0 = blockIdx.x * 64;
  const int qrow = q0 + 16 * w + r;
  const int sw = r & 7;

  // Q fragments (B-operand of S^T): lane holds Q[qrow][32ks+8quad+j]
  short8 qf[4];
  {
    const u16* qbase = Q + (size_t)qrow * 1536 + h * 128 + 8 * quad;
#pragma unroll
    for (int ks = 0; ks < 4; ++ks)
      qf[ks] = *reinterpret_cast<const short8*>(qbase + 32 * ks);
  }

  // staging: uniform bases + 32-bit per-lane element offsets
  const u16* Kb = K + h * 128;
  const u16* Vb = Vt + (size_t)h * 128 * kvLen;
  u32 koff[4], voff[4];
  int klo[4], vlo[4];
  {
    const int p16 = lane & 15, rin = lane >> 4;
    const int p8 = lane & 7, din = lane >> 3;
#pragma unroll
    for (int j = 0; j < 4; ++j) {
      const int row = 16 * w + 4 * j + rin;
      koff[j] = (u32)row * 1536u + 8u * (u32)(p16 ^ (row & 15));
      klo[j] = (16 * w + 4 * j) * 128;
      const int d = 32 * w + 8 * j + din;
      voff[j] = (u32)d * (u32)kvLen + 8u * (u32)(p8 ^ (d & 7));
      vlo[j] = (32 * w + 8 * j) * 64;
    }
  }

  f32x4 Oc[8];
#pragma unroll
  for (int dt = 0; dt < 8; ++dt) Oc[dt] = (f32x4){0.f, 0.f, 0.f, 0.f};
  float m_i = -1e30f, l_i = 0.f;

  const int nt = kvLen >> 6;
  for (int t = 0; t < nt; ++t) {
    __syncthreads();  // prior tile reads done
    {
      const size_t ko = (size_t)t * (64 * 1536);
      const size_t vo = (size_t)t * 64;
#pragma unroll
      for (int j = 0; j < 4; ++j) async16(Kb + ko + koff[j], &Ks[klo[j]]);
#pragma unroll
      for (int j = 0; j < 4; ++j) async16(Vb + vo + voff[j], &Vs[vlo[j]]);
    }
    __syncthreads();  // DMA complete

    // S^T = K * Q^T (log2-domain; Q pre-scaled)
    f32x4 St[4];
#pragma unroll
    for (int mt = 0; mt < 4; ++mt) St[mt] = (f32x4){0.f, 0.f, 0.f, 0.f};
#pragma unroll
    for (int mt = 0; mt < 4; ++mt) {
      const u16* kp = &Ks[(16 * mt + r) * 128];
#pragma unroll
      for (int ks = 0; ks < 4; ++ks) {
        const short8 af = *reinterpret_cast<const short8*>(kp + 8 * ((quad + 4 * ks) ^ r));
        St[mt] = __builtin_amdgcn_mfma_f32_16x16x32_bf16(af, qf[ks], St[mt], 0, 0, 0);
      }
    }

    // online softmax (base 2); lane owns q-row r
    float mloc = -1e30f;
#pragma unroll
    for (int mt = 0; mt < 4; ++mt)
#pragma unroll
      for (int rr = 0; rr < 4; ++rr) mloc = fmaxf(mloc, St[mt][rr]);
    mloc = fmaxf(mloc, __shfl_xor(mloc, 16, 64));
    mloc = fmaxf(mloc, __shfl_xor(mloc, 32, 64));
    const float mn = fmaxf(m_i, mloc);

    float alpha = 1.0f;
    if (__any(mloc > m_i)) {
      alpha = fexp2(m_i - mn);
      if (quad == 0) ab[w][r] = alpha;
      const float4 a4 = *reinterpret_cast<const float4*>(&ab[w][4 * quad]);
#pragma unroll
      for (int dt = 0; dt < 8; ++dt) {
        Oc[dt][0] *= a4.x; Oc[dt][1] *= a4.y; Oc[dt][2] *= a4.z; Oc[dt][3] *= a4.w;
      }
    }

    float psum = 0.f;
    uint2 pk[4];
#pragma unroll
    for (int mt = 0; mt < 4; ++mt) {
      const float p0 = fexp2(St[mt][0] - mn);
      const float p1 = fexp2(St[mt][1] - mn);
      const float p2 = fexp2(St[mt][2] - mn);
      const float p3 = fexp2(St[mt][3] - mn);
      psum += (p0 + p1) + (p2 + p3);
      pk[mt].x = pack_bf16_rn(p0, p1);
      pk[mt].y = pack_bf16_rn(p2, p3);
    }
    psum += __shfl_xor(psum, 16, 64);
    psum += __shfl_xor(psum, 32, 64);
    l_i = l_i * alpha + psum;
    m_i = mn;

    // PV in two k-halves, reusing the 16x40 wave-private Pb region.
    // half A: kpos 0..31
#pragma unroll
    for (int mt = 0; mt < 2; ++mt)
      *reinterpret_cast<uint2*>(&Pb[w][r * 40 + 16 * mt + 4 * quad]) = pk[mt];
    {
      const short8 pa0 = *reinterpret_cast<const short8*>(&Pb[w][r * 40 + 8 * quad]);
#pragma unroll
      for (int dt = 0; dt < 8; ++dt) {
        const int d = 16 * dt + r;
        const short8 b0 = *reinterpret_cast<const short8*>(&Vs[d * 64 + 8 * (quad ^ sw)]);
        Oc[dt] = __builtin_amdgcn_mfma_f32_16x16x32_bf16(pa0, b0, Oc[dt], 0, 0, 0);
      }
    }
    // half B: kpos 32..63 (same-wave LDS in-order: safe overwrite)
#pragma unroll
    for (int mt = 2; mt < 4; ++mt)
      *reinterpret_cast<uint2*>(&Pb[w][r * 40 + 16 * (mt - 2) + 4 * quad]) = pk[mt];
    {
      const short8 pa1 = *reinterpret_cast<const short8*>(&Pb[w][r * 40 + 8 * quad]);
#pragma unroll
      for (int dt = 0; dt < 8; ++dt) {
        const int d = 16 * dt + r;
        const short8 b1 = *reinterpret_cast<const short8*>(&Vs[d * 64 + 8 * ((4 + quad) ^ sw)]);
        Oc[dt] = __builtin_amdgcn_mfma_f32_16x16x32_bf16(pa1, b1, Oc[dt], 0, 0, 0);
      }
    }
  }

  // normalize by 1/l (LDS broadcast, wave-private) and store
  if (quad == 0) ab[w][r] = 1.0f / l_i;
  const float4 li4 = *reinterpret_cast<const float4*>(&ab[w][4 * quad]);
  const float lv[4] = {li4.x, li4.y, li4.z, li4.w};
  float* obf = O + (size_t)(q0 + 16 * w) * 1536 + h * 128;
  u16* obb = Ob + (size_t)(q0 + 16 * w) * 1536 + h * 128;
#pragma unroll
  for (int rr = 0; rr < 4; ++rr) {
    float* orow = obf + (size_t)(4 * quad + rr) * 1536 + r;
    u16* brow = obb + (size_t)(4 * quad + rr) * 1536 + r;
#pragma unroll
    for (int dt = 0; dt < 8; ++dt) {
      float v = Oc[dt][rr] * lv[rr];
      if (addO) {
        v += orow[16 * dt];
        brow[16 * dt] = f2b(v);
      } else {
        orow[16 * dt] = v;
      }
    }
  }
}

// =====================================================================
// Host orchestration (9 dispatches)
// =====================================================================
extern "C" void kernel_launch(void* const* d_in, const int* in_sizes, int n_in,
                              void* d_out, int out_size, void* d_ws, size_t ws_size,
                              hipStream_t stream) {
  (void)in_sizes; (void)n_in; (void)out_size; (void)ws_size;
  constexpr int T = 4096, TR = 1024, DIM = 1536, NH = 12;

  const float* hs  = (const float*)d_in[0];
  const float* rhs = (const float*)d_in[1];
  const float* rc  = (const float*)d_in[2];
  const float* rs  = (const float*)d_in[3];
  const float* Wq  = (const float*)d_in[4];
  const float* bq  = (const float*)d_in[5];
  const float* Wk  = (const float*)d_in[6];
  const float* bk  = (const float*)d_in[7];
  const float* Wv  = (const float*)d_in[8];
  const float* bv  = (const float*)d_in[9];
  const float* Wkr = (const float*)d_in[10];
  const float* bkr = (const float*)d_in[11];
  const float* Wvr = (const float*)d_in[12];
  const float* bvr = (const float*)d_in[13];
  const float* Wo  = (const float*)d_in[14];
  const float* bo  = (const float*)d_in[15];
  const float* gq  = (const float*)d_in[16];
  const float* gk  = (const float*)d_in[17];
  float* out = (float*)d_out;

  char* ws = (char*)d_ws;
  size_t off = 0;
  auto alloc = [&](size_t bytes) -> void* {
    void* p = ws + off;
    off += (bytes + 255) & ~(size_t)255;
    return p;
  };
  u16* bQ    = (u16*)alloc((size_t)T * DIM * 2);
  u16* bQr   = (u16*)alloc((size_t)T * DIM * 2);
  u16* bK    = (u16*)alloc((size_t)T * DIM * 2);
  u16* bV    = (u16*)alloc((size_t)T * DIM * 2);
  u16* bKr   = (u16*)alloc((size_t)TR * DIM * 2);
  u16* bVr   = (u16*)alloc((size_t)TR * DIM * 2);
  float* bO  = (float*)alloc((size_t)T * DIM * 4);     // cross-attn out (f32)
  u16* bHs   = (u16*)alloc((size_t)T * DIM * 2);       // bf16 hs; ALIAS-> VtG
  u16* bRhs  = (u16*)alloc((size_t)TR * DIM * 2);      // bf16 rhs; ALIAS-> VtR
  u16* bWqkv = (u16*)alloc((size_t)3 * DIM * DIM * 2); // WqT|WkT|WvT; ALIAS-> bOb
  u16* bWr   = (u16*)alloc((size_t)2 * DIM * DIM * 2); // WkrT|WvrT
  u16* bWoT  = (u16*)alloc((size_t)DIM * DIM * 2);     // WoT (own slab)
  u16* VtG = bHs;
  u16* VtR = bRhs;
  u16* bOb = bWqkv;

  const dim3 blk(256);

  // 1. f32->bf16 converts (merged)
  conv2_kernel<<<dim3((T * DIM / 8 + TR * DIM / 8 + 255) / 256), blk, 0, stream>>>(
      hs, bHs, T * DIM / 8, rhs, bRhs, TR * DIM / 8);

  // 2. weight transpose-converts (all six merged)
  transconv6_kernel<<<dim3(24, 24, 6), blk, 0, stream>>>(
      Wq, Wk, Wv, Wkr, Wvr, Wo,
      bWqkv + 0 * (size_t)DIM * DIM, bWqkv + 1 * (size_t)DIM * DIM,
      bWqkv + 2 * (size_t)DIM * DIM, bWr + 0 * (size_t)DIM * DIM,
      bWr + 1 * (size_t)DIM * DIM, bWoT);

  // 3-4. projections (QKV fused 128-tile; KrVr 64-tile for occupancy)
  gemm128_kernel<4, u16><<<dim3(36, 32), blk, 0, stream>>>(
      bHs, DIM, bWqkv, DIM, bQ, bK, bV, DIM, bq, bk, bv, DIM);
  gemm128_kernel<2, u16><<<dim3(24, 16), blk, 0, stream>>>(
      bRhs, DIM, bWr, DIM, bKr, bVr, (u16*)nullptr, DIM, bkr, bvr, nullptr, DIM);

  // 5. rmsnorm/rope (merged; q-path pre-scaled by QS)
  rmsnorm3_kernel<<<dim3(T, 3), blk, 0, stream>>>(
      bQ, bK, bKr, gq, gk, rc, rs, bQ, bQr, bK, bKr);

  // 6. per-head V transposes (merged; alias buffers are dead)
  vtrans2_kernel<<<dim3(T / 64, NH, 2), blk, 0, stream>>>(bV, VtG, bVr, VtR);

  // 7-8. flash attention: cross writes f32 bO; main adds + writes bf16 bOb
  flash_kernel<<<dim3(T / 64, NH), blk, 0, stream>>>(bQ, bKr, VtR, bO, bOb, TR, 0);
  flash_kernel<<<dim3(T / 64, NH), blk, 0, stream>>>(bQr, bK, VtG, bO, bOb, T, 1);

  // 9. output projection (64-row tiles for occupancy)
  gemm128_kernel<2, float><<<dim3(12, 64), blk, 0, stream>>>(
      bOb, DIM, bWoT, DIM, out, (float*)nullptr, (float*)nullptr, DIM, bo, nullptr, nullptr, DIM);
}

// Round 8
// 527.392 us; speedup vs baseline: 1.5682x; 1.0112x over previous
//
#include <hip/hip_runtime.h>

typedef unsigned short u16;
typedef unsigned int u32;
typedef __attribute__((ext_vector_type(8))) short short8;
typedef __attribute__((ext_vector_type(4))) float f32x4;

// ---------- bf16 helpers ----------
__device__ inline u16 f2b(float f) {  // RNE
  u32 u = __builtin_bit_cast(u32, f);
  u += 0x7fff + ((u >> 16) & 1);
  return (u16)(u >> 16);
}
__device__ inline float b2f(u16 u) {
  return __builtin_bit_cast(float, (u32)u << 16);
}
// round-to-nearest (ties away) pack — cheaper than RNE, used for P only
__device__ inline u32 pack_bf16_rn(float a, float b) {
  const u32 ua = __builtin_bit_cast(u32, a) + 0x8000u;
  const u32 ub = __builtin_bit_cast(u32, b) + 0x8000u;
  return (ua >> 16) | (ub & 0xffff0000u);
}
__device__ inline void c_store(float* p, float v) { *p = v; }
__device__ inline void c_store(u16* p, float v) { *p = f2b(v); }

__device__ inline float fexp2(float x) {
#if __has_builtin(__builtin_amdgcn_exp2f)
  return __builtin_amdgcn_exp2f(x);
#else
  return exp2f(x);
#endif
}

// ---------- async global->LDS, 16B per lane ----------
typedef const __attribute__((address_space(1))) u32 gu32;
typedef __attribute__((address_space(3))) u32 lu32;
__device__ inline void async16(const u16* g, u16* l) {
  __builtin_amdgcn_global_load_lds((gu32*)g, (lu32*)l, 16, 0, 0);
}

// Q scale folded into rmsnorm producer: 1/sqrt(128) * log2(e)
#define QS (0.08838834764831843f * 1.4426950408889634f)

// =====================================================================
// (32*MI)x128x(K,BK=32) bf16 GEMM.
// r14: single-barrier LDS double-buffer (same structure proven correct
// in flash r1-r4): prologue stages tile 0; each iter does
//   barrier -> stage(t+1)->buf^1 -> compute buf[t].
// The barrier's implicit vmcnt(0) then waits on loads issued a full
// compute phase earlier instead of ~0 cycles earlier -> per-iteration
// L2/HBM latency exposure removed. LDS: MI=4 32KB, MI=2 24KB (still
// >=4 blocks/CU by LDS; avoids m132's 64KB occupancy trap).
// Barrier-safety: at iter-t barrier every wave has (a) its stage(t)
// loads vmcnt-drained, (b) its buf^1 reads (iter t-1) lgkm-drained;
// stage(t+1) then safely overwrites buf^1.
// r13 XCD-locality remap kept (bijective when gridDim.y % 8 == 0).
// =====================================================================
template <int MI, typename TC>
__global__ __launch_bounds__(256) void gemm128_kernel(
    const u16* __restrict__ A, long lda,
    const u16* __restrict__ Bt, long ldb,
    TC* __restrict__ C0, TC* __restrict__ C1, TC* __restrict__ C2, long ldc,
    const float* b0, const float* b1, const float* b2,
    int K) {
  __shared__ __align__(16) u16 As[2][32 * MI * 32];
  __shared__ __align__(16) u16 Bs[2][128 * 32];

  const int tid = threadIdx.x;
  const int lane = tid & 63;
  const int w = tid >> 6;
  const int r = lane & 15;
  const int quad = lane >> 4;

  // ---- XCD-locality remap (bijective when ny % 8 == 0) ----
  int bx = blockIdx.x, by = blockIdx.y;
  {
    const int ny = gridDim.y;
    if ((ny & 7) == 0) {
      const int lin = by * gridDim.x + bx;
      const int xcd = lin & 7;
      const int k = lin >> 3;
      const int rpx = ny >> 3;                 // A-row panels per XCD
      by = xcd * rpx + (k % rpx);
      bx = k / rpx;
    }
  }
  const int m0 = by * (32 * MI);
  const int nb = bx * 128;
  const int seg = nb / 1536;
  const int nc = nb - seg * 1536;
  TC* C = seg == 0 ? C0 : (seg == 1 ? C1 : C2);
  const float* bias = seg == 0 ? b0 : (seg == 1 ? b1 : b2);

  const int srow = lane >> 2;
  const int sx = ((lane & 3) ^ (srow & 3)) * 8;
  const u16* Ag = A + (size_t)(m0 + w * 8 * MI + srow) * lda + sx;
  const u16* Bg = Bt + (size_t)(nb + w * 32 + srow) * ldb + sx;

  const int wm = (w >> 1) * (16 * MI);
  const int wn = (w & 1) * 64;

  f32x4 acc[MI][4];
#pragma unroll
  for (int i = 0; i < MI; ++i)
#pragma unroll
    for (int j = 0; j < 4; ++j) acc[i][j] = (f32x4){0.f, 0.f, 0.f, 0.f};

  const int fco = (quad ^ (r & 3)) * 8;

  const int nt = K >> 5;

  // prologue: stage tile 0 into buffer 0
#pragma unroll
  for (int j = 0; j < MI / 2; ++j)
    async16(Ag + (size_t)(16 * j) * lda, &As[0][(w * 8 * MI + 16 * j) * 32]);
  async16(Bg, &Bs[0][(w * 32) * 32]);
  async16(Bg + 16 * ldb, &Bs[0][(w * 32 + 16) * 32]);

  for (int t = 0; t < nt; ++t) {
    const int buf = t & 1;
    __syncthreads();  // stage(t) complete; buf^1 reads (iter t-1) done
    if (t + 1 < nt) {
      const int kk = 32 * (t + 1);
#pragma unroll
      for (int j = 0; j < MI / 2; ++j)
        async16(Ag + kk + (size_t)(16 * j) * lda, &As[buf ^ 1][(w * 8 * MI + 16 * j) * 32]);
      async16(Bg + kk, &Bs[buf ^ 1][(w * 32) * 32]);
      async16(Bg + kk + 16 * ldb, &Bs[buf ^ 1][(w * 32 + 16) * 32]);
    }

    short8 af[MI], bf[4];
#pragma unroll
    for (int mi = 0; mi < MI; ++mi)
      af[mi] = *reinterpret_cast<const short8*>(&As[buf][(wm + 16 * mi + r) * 32 + fco]);
#pragma unroll
    for (int ni = 0; ni < 4; ++ni)
      bf[ni] = *reinterpret_cast<const short8*>(&Bs[buf][(wn + 16 * ni + r) * 32 + fco]);
#pragma unroll
    for (int mi = 0; mi < MI; ++mi)
#pragma unroll
      for (int ni = 0; ni < 4; ++ni)
        acc[mi][ni] = __builtin_amdgcn_mfma_f32_16x16x32_bf16(af[mi], bf[ni], acc[mi][ni], 0, 0, 0);
  }

#pragma unroll
  for (int mi = 0; mi < MI; ++mi)
#pragma unroll
    for (int ni = 0; ni < 4; ++ni)
#pragma unroll
      for (int rr = 0; rr < 4; ++rr) {
        const int row = m0 + wm + 16 * mi + 4 * quad + rr;
        const int col = nc + wn + 16 * ni + r;
        c_store(&C[(size_t)row * ldc + col], acc[mi][ni][rr] + bias[col]);
      }
}

// =====================================================================
// Merged f32->bf16 convert for hs and rhs
// =====================================================================
__global__ __launch_bounds__(256) void conv2_kernel(
    const float* __restrict__ xa, u16* __restrict__ ya, int n8a,
    const float* __restrict__ xb, u16* __restrict__ yb, int n8b) {
  int i = blockIdx.x * 256 + threadIdx.x;
  const float* x;
  u16* y;
  if (i < n8a) {
    x = xa; y = ya;
  } else {
    i -= n8a;
    if (i >= n8b) return;
    x = xb; y = yb;
  }
  const float4 v0 = reinterpret_cast<const float4*>(x)[2 * i];
  const float4 v1 = reinterpret_cast<const float4*>(x)[2 * i + 1];
  uint4 rv;
  rv.x = (u32)f2b(v0.x) | ((u32)f2b(v0.y) << 16);
  rv.y = (u32)f2b(v0.z) | ((u32)f2b(v0.w) << 16);
  rv.z = (u32)f2b(v1.x) | ((u32)f2b(v1.y) << 16);
  rv.w = (u32)f2b(v1.z) | ((u32)f2b(v1.w) << 16);
  reinterpret_cast<uint4*>(y)[i] = rv;
}

// =====================================================================
// Transpose-convert, all 6 weights merged (W f32 [1536][1536] -> Wt^T bf16)
// =====================================================================
__device__ inline void transconv_body(const float* __restrict__ W, u16* __restrict__ Wt) {
  __shared__ __align__(16) u16 Ls[64 * 72];
  const int tid = threadIdx.x;
  const int k0 = blockIdx.y * 64;
  const int n0 = blockIdx.x * 64;
#pragma unroll
  for (int i = 0; i < 4; ++i) {
    const int c = tid + 256 * i;
    const int row = c >> 4;
    const int c4 = (c & 15) * 4;
    const float4 v = *reinterpret_cast<const float4*>(&W[(size_t)(k0 + row) * 1536 + n0 + c4]);
    Ls[(c4 + 0) * 72 + row] = f2b(v.x);
    Ls[(c4 + 1) * 72 + row] = f2b(v.y);
    Ls[(c4 + 2) * 72 + row] = f2b(v.z);
    Ls[(c4 + 3) * 72 + row] = f2b(v.w);
  }
  __syncthreads();
#pragma unroll
  for (int i = 0; i < 2; ++i) {
    const int c = tid + 256 * i;
    const int n = c >> 3;
    const int kc = (c & 7) * 8;
    u16 tmp[8];
#pragma unroll
    for (int j = 0; j < 8; ++j) tmp[j] = Ls[n * 72 + kc + j];
    *reinterpret_cast<uint4*>(&Wt[(size_t)(n0 + n) * 1536 + k0 + kc]) =
        *reinterpret_cast<const uint4*>(tmp);
  }
}

__global__ __launch_bounds__(256) void transconv6_kernel(
    const float* W0, const float* W1, const float* W2,
    const float* W3, const float* W4, const float* W5,
    u16* T0, u16* T1, u16* T2, u16* T3, u16* T4, u16* T5) {
  const int z = blockIdx.z;
  const float* W = z == 0 ? W0 : z == 1 ? W1 : z == 2 ? W2 : z == 3 ? W3 : z == 4 ? W4 : W5;
  u16* Wt = z == 0 ? T0 : z == 1 ? T1 : z == 2 ? T2 : z == 3 ? T3 : z == 4 ? T4 : T5;
  transconv_body(W, Wt);
}

// =====================================================================
// Merged RMSNorm: z=0 q-path (scaled by QS, plain+rope), z=1 k-path
// (rope), z=2 ref-k (1024 rows, plain). Verified r4-r6.
// =====================================================================
__global__ __launch_bounds__(256) void rmsnorm3_kernel(
    const u16* xq, const u16* xk, const u16* xkr,
    const float* gq, const float* gk,
    const float* rc, const float* rs,
    u16* oq_plain, u16* oq_rope, u16* ok_rope, u16* okr_plain) {
  __shared__ float red[4];
  const int z = blockIdx.y;
  const int row = blockIdx.x;
  if (z == 2 && row >= 1024) return;
  const u16* x; const float* g; u16* po; u16* pr; float sc;
  if (z == 0)      { x = xq;  g = gq; po = oq_plain; pr = oq_rope; sc = QS;  }
  else if (z == 1) { x = xk;  g = gk; po = nullptr;  pr = ok_rope; sc = 1.f; }
  else             { x = xkr; g = gk; po = okr_plain; pr = nullptr; sc = 1.f; }

  const int tid = threadIdx.x;
  const u32* xr = reinterpret_cast<const u32*>(x + (size_t)row * 1536);
  float xe[3], xo[3];
  float ss = 0.f;
#pragma unroll
  for (int j = 0; j < 3; ++j) {
    const u32 u = xr[tid + 256 * j];
    const float e = b2f((u16)(u & 0xffff));
    const float o = b2f((u16)(u >> 16));
    xe[j] = e; xo[j] = o;
    ss += e * e + o * o;
  }
#pragma unroll
  for (int off = 32; off; off >>= 1) ss += __shfl_xor(ss, off, 64);
  if ((tid & 63) == 0) red[tid >> 6] = ss;
  __syncthreads();
  const float total = red[0] + red[1] + red[2] + red[3];
  const float rinv = rsqrtf(total * (1.0f / 1536.0f) + 1e-6f) * sc;
  u32* po32 = po ? reinterpret_cast<u32*>(po + (size_t)row * 1536) : nullptr;
  u32* pr32 = pr ? reinterpret_cast<u32*>(pr + (size_t)row * 1536) : nullptr;
#pragma unroll
  for (int j = 0; j < 3; ++j) {
    const int p = tid + 256 * j;
    const float2 gg = reinterpret_cast<const float2*>(g)[p];
    const float e = xe[j] * rinv * gg.x;
    const float o = xo[j] * rinv * gg.y;
    if (po32) po32[p] = (u32)f2b(e) | ((u32)f2b(o) << 16);
    if (pr32) {
      const int i = p & 63;
      const float c = rc[row * 64 + i];
      const float s = rs[row * 64 + i];
      const float re = e * c - o * s;
      const float im = e * s + o * c;
      pr32[p] = (u32)f2b(re) | ((u32)f2b(im) << 16);
    }
  }
}

// =====================================================================
// Merged per-head V transpose (verified r4-r6)
// =====================================================================
__global__ __launch_bounds__(256) void vtrans2_kernel(
    const u16* __restrict__ V0, u16* __restrict__ Vt0,
    const u16* __restrict__ V1, u16* __restrict__ Vt1) {
  __shared__ __align__(16) u16 Ls[64 * 136];
  const int z = blockIdx.z;
  const int kvLen = z == 0 ? 4096 : 1024;
  const int kv0 = blockIdx.x * 64;
  if (kv0 >= kvLen) return;
  const u16* V = z == 0 ? V0 : V1;
  u16* Vt = z == 0 ? Vt0 : Vt1;
  const int tid = threadIdx.x;
  const int h = blockIdx.y;
#pragma unroll
  for (int i = 0; i < 4; ++i) {
    const int c = tid + 256 * i;
    const int row = c >> 4, c8 = c & 15;
    *reinterpret_cast<uint4*>(&Ls[row * 136 + 8 * c8]) =
        *reinterpret_cast<const uint4*>(V + (size_t)(kv0 + row) * 1536 + h * 128 + 8 * c8);
  }
  __syncthreads();
#pragma unroll
  for (int i = 0; i < 4; ++i) {
    const int c = tid + 256 * i;
    const int d = c >> 3, kc = c & 7;
    u16 tmp[8];
#pragma unroll
    for (int j = 0; j < 8; ++j) tmp[j] = Ls[(8 * kc + j) * 136 + d];
    *reinterpret_cast<uint4*>(Vt + ((size_t)h * 128 + d) * kvLen + kv0 + 8 * kc) =
        *reinterpret_cast<const uint4*>(tmp);
  }
}

// =====================================================================
// Flash attention — EXACT r0 kernel (best measured: 184.8 µs main +
// ~48 µs cross). Kept byte-identical as the control for this round's
// GEMM-only change.
// =====================================================================
__global__ __launch_bounds__(256, 4) void flash_kernel(
    const u16* __restrict__ Q, const u16* __restrict__ K,
    const u16* __restrict__ Vt, float* __restrict__ O,
    u16* __restrict__ Ob, int kvLen, int addO) {
  __shared__ __align__(16) u16 Ks[64 * 128];
  __shared__ __align__(16) u16 Vs[128 * 64];
  __shared__ __align__(16) u16 Pb[4][16 * 40];
  __shared__ __align__(16) float ab[4][16];

  const int tid = threadIdx.x;
  const int lane = tid & 63;
  const int w = tid >> 6;
  const int r = lane & 15;
  const int quad = lane >> 4;
  const int h = blockIdx.y;
  const int q0 = blockIdx.x * 64;
  const int qrow = q0 + 16 * w + r;
  const int sw = r & 7;

  // Q fragments (B-operand of S^T): lane holds Q[qrow][32ks+8quad+j]
  short8 qf[4];
  {
    const u16* qbase = Q + (size_t)qrow * 1536 + h * 128 + 8 * quad;
#pragma unroll
    for (int ks = 0; ks < 4; ++ks)
      qf[ks] = *reinterpret_cast<const short8*>(qbase + 32 * ks);
  }

  // staging: uniform bases + 32-bit per-lane element offsets
  const u16* Kb = K + h * 128;
  const u16* Vb = Vt + (size_t)h * 128 * kvLen;
  u32 koff[4], voff[4];
  int klo[4], vlo[4];
  {
    const int p16 = lane & 15, rin = lane >> 4;
    const int p8 = lane & 7, din = lane >> 3;
#pragma unroll
    for (int j = 0; j < 4; ++j) {
      const int row = 16 * w + 4 * j + rin;
      koff[j] = (u32)row * 1536u + 8u * (u32)(p16 ^ (row & 15));
      klo[j] = (16 * w + 4 * j) * 128;
      const int d = 32 * w + 8 * j + din;
      voff[j] = (u32)d * (u32)kvLen + 8u * (u32)(p8 ^ (d & 7));
      vlo[j] = (32 * w + 8 * j) * 64;
    }
  }

  f32x4 Oc[8];
#pragma unroll
  for (int dt = 0; dt < 8; ++dt) Oc[dt] = (f32x4){0.f, 0.f, 0.f, 0.f};
  float m_i = -1e30f, l_i = 0.f;

  const int nt = kvLen >> 6;
  for (int t = 0; t < nt; ++t) {
    __syncthreads();  // prior tile reads done
    {
      const size_t ko = (size_t)t * (64 * 1536);
      const size_t vo = (size_t)t * 64;
#pragma unroll
      for (int j = 0; j < 4; ++j) async16(Kb + ko + koff[j], &Ks[klo[j]]);
#pragma unroll
      for (int j = 0; j < 4; ++j) async16(Vb + vo + voff[j], &Vs[vlo[j]]);
    }
    __syncthreads();  // DMA complete

    // S^T = K * Q^T (log2-domain; Q pre-scaled)
    f32x4 St[4];
#pragma unroll
    for (int mt = 0; mt < 4; ++mt) St[mt] = (f32x4){0.f, 0.f, 0.f, 0.f};
#pragma unroll
    for (int mt = 0; mt < 4; ++mt) {
      const u16* kp = &Ks[(16 * mt + r) * 128];
#pragma unroll
      for (int ks = 0; ks < 4; ++ks) {
        const short8 af = *reinterpret_cast<const short8*>(kp + 8 * ((quad + 4 * ks) ^ r));
        St[mt] = __builtin_amdgcn_mfma_f32_16x16x32_bf16(af, qf[ks], St[mt], 0, 0, 0);
      }
    }

    // online softmax (base 2); lane owns q-row r
    float mloc = -1e30f;
#pragma unroll
    for (int mt = 0; mt < 4; ++mt)
#pragma unroll
      for (int rr = 0; rr < 4; ++rr) mloc = fmaxf(mloc, St[mt][rr]);
    mloc = fmaxf(mloc, __shfl_xor(mloc, 16, 64));
    mloc = fmaxf(mloc, __shfl_xor(mloc, 32, 64));
    const float mn = fmaxf(m_i, mloc);

    float alpha = 1.0f;
    if (__any(mloc > m_i)) {
      alpha = fexp2(m_i - mn);
      if (quad == 0) ab[w][r] = alpha;
      const float4 a4 = *reinterpret_cast<const float4*>(&ab[w][4 * quad]);
#pragma unroll
      for (int dt = 0; dt < 8; ++dt) {
        Oc[dt][0] *= a4.x; Oc[dt][1] *= a4.y; Oc[dt][2] *= a4.z; Oc[dt][3] *= a4.w;
      }
    }

    float psum = 0.f;
    uint2 pk[4];
#pragma unroll
    for (int mt = 0; mt < 4; ++mt) {
      const float p0 = fexp2(St[mt][0] - mn);
      const float p1 = fexp2(St[mt][1] - mn);
      const float p2 = fexp2(St[mt][2] - mn);
      const float p3 = fexp2(St[mt][3] - mn);
      psum += (p0 + p1) + (p2 + p3);
      pk[mt].x = pack_bf16_rn(p0, p1);
      pk[mt].y = pack_bf16_rn(p2, p3);
    }
    psum += __shfl_xor(psum, 16, 64);
    psum += __shfl_xor(psum, 32, 64);
    l_i = l_i * alpha + psum;
    m_i = mn;

    // PV in two k-halves, reusing the 16x40 wave-private Pb region.
    // half A: kpos 0..31
#pragma unroll
    for (int mt = 0; mt < 2; ++mt)
      *reinterpret_cast<uint2*>(&Pb[w][r * 40 + 16 * mt + 4 * quad]) = pk[mt];
    {
      const short8 pa0 = *reinterpret_cast<const short8*>(&Pb[w][r * 40 + 8 * quad]);
#pragma unroll
      for (int dt = 0; dt < 8; ++dt) {
        const int d = 16 * dt + r;
        const short8 b0 = *reinterpret_cast<const short8*>(&Vs[d * 64 + 8 * (quad ^ sw)]);
        Oc[dt] = __builtin_amdgcn_mfma_f32_16x16x32_bf16(pa0, b0, Oc[dt], 0, 0, 0);
      }
    }
    // half B: kpos 32..63 (same-wave LDS in-order: safe overwrite)
#pragma unroll
    for (int mt = 2; mt < 4; ++mt)
      *reinterpret_cast<uint2*>(&Pb[w][r * 40 + 16 * (mt - 2) + 4 * quad]) = pk[mt];
    {
      const short8 pa1 = *reinterpret_cast<const short8*>(&Pb[w][r * 40 + 8 * quad]);
#pragma unroll
      for (int dt = 0; dt < 8; ++dt) {
        const int d = 16 * dt + r;
        const short8 b1 = *reinterpret_cast<const short8*>(&Vs[d * 64 + 8 * ((4 + quad) ^ sw)]);
        Oc[dt] = __builtin_amdgcn_mfma_f32_16x16x32_bf16(pa1, b1, Oc[dt], 0, 0, 0);
      }
    }
  }

  // normalize by 1/l (LDS broadcast, wave-private) and store
  if (quad == 0) ab[w][r] = 1.0f / l_i;
  const float4 li4 = *reinterpret_cast<const float4*>(&ab[w][4 * quad]);
  const float lv[4] = {li4.x, li4.y, li4.z, li4.w};
  float* obf = O + (size_t)(q0 + 16 * w) * 1536 + h * 128;
  u16* obb = Ob + (size_t)(q0 + 16 * w) * 1536 + h * 128;
#pragma unroll
  for (int rr = 0; rr < 4; ++rr) {
    float* orow = obf + (size_t)(4 * quad + rr) * 1536 + r;
    u16* brow = obb + (size_t)(4 * quad + rr) * 1536 + r;
#pragma unroll
    for (int dt = 0; dt < 8; ++dt) {
      float v = Oc[dt][rr] * lv[rr];
      if (addO) {
        v += orow[16 * dt];
        brow[16 * dt] = f2b(v);
      } else {
        orow[16 * dt] = v;
      }
    }
  }
}

// =====================================================================
// Host orchestration (9 dispatches)
// =====================================================================
extern "C" void kernel_launch(void* const* d_in, const int* in_sizes, int n_in,
                              void* d_out, int out_size, void* d_ws, size_t ws_size,
                              hipStream_t stream) {
  (void)in_sizes; (void)n_in; (void)out_size; (void)ws_size;
  constexpr int T = 4096, TR = 1024, DIM = 1536, NH = 12;

  const float* hs  = (const float*)d_in[0];
  const float* rhs = (const float*)d_in[1];
  const float* rc  = (const float*)d_in[2];
  const float* rs  = (const float*)d_in[3];
  const float* Wq  = (const float*)d_in[4];
  const float* bq  = (const float*)d_in[5];
  const float* Wk  = (const float*)d_in[6];
  const float* bk  = (const float*)d_in[7];
  const float* Wv  = (const float*)d_in[8];
  const float* bv  = (const float*)d_in[9];
  const float* Wkr = (const float*)d_in[10];
  const float* bkr = (const float*)d_in[11];
  const float* Wvr = (const float*)d_in[12];
  const float* bvr = (const float*)d_in[13];
  const float* Wo  = (const float*)d_in[14];
  const float* bo  = (const float*)d_in[15];
  const float* gq  = (const float*)d_in[16];
  const float* gk  = (const float*)d_in[17];
  float* out = (float*)d_out;

  char* ws = (char*)d_ws;
  size_t off = 0;
  auto alloc = [&](size_t bytes) -> void* {
    void* p = ws + off;
    off += (bytes + 255) & ~(size_t)255;
    return p;
  };
  u16* bQ    = (u16*)alloc((size_t)T * DIM * 2);
  u16* bQr   = (u16*)alloc((size_t)T * DIM * 2);
  u16* bK    = (u16*)alloc((size_t)T * DIM * 2);
  u16* bV    = (u16*)alloc((size_t)T * DIM * 2);
  u16* bKr   = (u16*)alloc((size_t)TR * DIM * 2);
  u16* bVr   = (u16*)alloc((size_t)TR * DIM * 2);
  float* bO  = (float*)alloc((size_t)T * DIM * 4);     // cross-attn out (f32)
  u16* bHs   = (u16*)alloc((size_t)T * DIM * 2);       // bf16 hs; ALIAS-> VtG
  u16* bRhs  = (u16*)alloc((size_t)TR * DIM * 2);      // bf16 rhs; ALIAS-> VtR
  u16* bWqkv = (u16*)alloc((size_t)3 * DIM * DIM * 2); // WqT|WkT|WvT; ALIAS-> bOb
  u16* bWr   = (u16*)alloc((size_t)2 * DIM * DIM * 2); // WkrT|WvrT
  u16* bWoT  = (u16*)alloc((size_t)DIM * DIM * 2);     // WoT (own slab)
  u16* VtG = bHs;
  u16* VtR = bRhs;
  u16* bOb = bWqkv;

  const dim3 blk(256);

  // 1. f32->bf16 converts (merged)
  conv2_kernel<<<dim3((T * DIM / 8 + TR * DIM / 8 + 255) / 256), blk, 0, stream>>>(
      hs, bHs, T * DIM / 8, rhs, bRhs, TR * DIM / 8);

  // 2. weight transpose-converts (all six merged)
  transconv6_kernel<<<dim3(24, 24, 6), blk, 0, stream>>>(
      Wq, Wk, Wv, Wkr, Wvr, Wo,
      bWqkv + 0 * (size_t)DIM * DIM, bWqkv + 1 * (size_t)DIM * DIM,
      bWqkv + 2 * (size_t)DIM * DIM, bWr + 0 * (size_t)DIM * DIM,
      bWr + 1 * (size_t)DIM * DIM, bWoT);

  // 3-4. projections (QKV fused 128-tile; KrVr 64-tile for occupancy)
  gemm128_kernel<4, u16><<<dim3(36, 32), blk, 0, stream>>>(
      bHs, DIM, bWqkv, DIM, bQ, bK, bV, DIM, bq, bk, bv, DIM);
  gemm128_kernel<2, u16><<<dim3(24, 16), blk, 0, stream>>>(
      bRhs, DIM, bWr, DIM, bKr, bVr, (u16*)nullptr, DIM, bkr, bvr, nullptr, DIM);

  // 5. rmsnorm/rope (merged; q-path pre-scaled by QS)
  rmsnorm3_kernel<<<dim3(T, 3), blk, 0, stream>>>(
      bQ, bK, bKr, gq, gk, rc, rs, bQ, bQr, bK, bKr);

  // 6. per-head V transposes (merged; alias buffers are dead)
  vtrans2_kernel<<<dim3(T / 64, NH, 2), blk, 0, stream>>>(bV, VtG, bVr, VtR);

  // 7-8. flash attention: cross writes f32 bO; main adds + writes bf16 bOb
  flash_kernel<<<dim3(T / 64, NH), blk, 0, stream>>>(bQ, bKr, VtR, bO, bOb, TR, 0);
  flash_kernel<<<dim3(T / 64, NH), blk, 0, stream>>>(bQr, bK, VtG, bO, bOb, T, 1);

  // 9. output projection (64-row tiles for occupancy)
  gemm128_kernel<2, float><<<dim3(12, 64), blk, 0, stream>>>(
      bOb, DIM, bWoT, DIM, out, (float*)nullptr, (float*)nullptr, DIM, bo, nullptr, nullptr, DIM);
}

// Round 12
// 517.173 us; speedup vs baseline: 1.5992x; 1.0198x over previous
//
#include <hip/hip_runtime.h>

typedef unsigned short u16;
typedef unsigned int u32;
typedef __attribute__((ext_vector_type(8))) short short8;
typedef __attribute__((ext_vector_type(4))) float f32x4;

// ---------- bf16 helpers ----------
__device__ inline u16 f2b(float f) {  // RNE
  u32 u = __builtin_bit_cast(u32, f);
  u += 0x7fff + ((u >> 16) & 1);
  return (u16)(u >> 16);
}
__device__ inline float b2f(u16 u) {
  return __builtin_bit_cast(float, (u32)u << 16);
}
// round-to-nearest (ties away) pack — cheaper than RNE, used for P only
__device__ inline u32 pack_bf16_rn(float a, float b) {
  const u32 ua = __builtin_bit_cast(u32, a) + 0x8000u;
  const u32 ub = __builtin_bit_cast(u32, b) + 0x8000u;
  return (ua >> 16) | (ub & 0xffff0000u);
}
__device__ inline void c_store(float* p, float v) { *p = v; }
__device__ inline void c_store(u16* p, float v) { *p = f2b(v); }

__device__ inline float fexp2(float x) {
#if __has_builtin(__builtin_amdgcn_exp2f)
  return __builtin_amdgcn_exp2f(x);
#else
  return exp2f(x);
#endif
}

// ---------- async global->LDS, 16B per lane ----------
typedef const __attribute__((address_space(1))) u32 gu32;
typedef __attribute__((address_space(3))) u32 lu32;
__device__ inline void async16(const u16* g, u16* l) {
  __builtin_amdgcn_global_load_lds((gu32*)g, (lu32*)l, 16, 0, 0);
}

// Q scale folded into rmsnorm producer: 1/sqrt(128) * log2(e)
#define QS (0.08838834764831843f * 1.4426950408889634f)

// =====================================================================
// (32*MI)x128x(K,BK=32) bf16 GEMM. r14 structure (verified r8):
// single-barrier LDS double-buffer + r13 XCD-locality remap.
// =====================================================================
template <int MI, typename TC>
__global__ __launch_bounds__(256) void gemm128_kernel(
    const u16* __restrict__ A, long lda,
    const u16* __restrict__ Bt, long ldb,
    TC* __restrict__ C0, TC* __restrict__ C1, TC* __restrict__ C2, long ldc,
    const float* b0, const float* b1, const float* b2,
    int K) {
  __shared__ __align__(16) u16 As[2][32 * MI * 32];
  __shared__ __align__(16) u16 Bs[2][128 * 32];

  const int tid = threadIdx.x;
  const int lane = tid & 63;
  const int w = tid >> 6;
  const int r = lane & 15;
  const int quad = lane >> 4;

  // ---- XCD-locality remap (bijective when ny % 8 == 0) ----
  int bx = blockIdx.x, by = blockIdx.y;
  {
    const int ny = gridDim.y;
    if ((ny & 7) == 0) {
      const int lin = by * gridDim.x + bx;
      const int xcd = lin & 7;
      const int k = lin >> 3;
      const int rpx = ny >> 3;                 // A-row panels per XCD
      by = xcd * rpx + (k % rpx);
      bx = k / rpx;
    }
  }
  const int m0 = by * (32 * MI);
  const int nb = bx * 128;
  const int seg = nb / 1536;
  const int nc = nb - seg * 1536;
  TC* C = seg == 0 ? C0 : (seg == 1 ? C1 : C2);
  const float* bias = seg == 0 ? b0 : (seg == 1 ? b1 : b2);

  const int srow = lane >> 2;
  const int sx = ((lane & 3) ^ (srow & 3)) * 8;
  const u16* Ag = A + (size_t)(m0 + w * 8 * MI + srow) * lda + sx;
  const u16* Bg = Bt + (size_t)(nb + w * 32 + srow) * ldb + sx;

  const int wm = (w >> 1) * (16 * MI);
  const int wn = (w & 1) * 64;

  f32x4 acc[MI][4];
#pragma unroll
  for (int i = 0; i < MI; ++i)
#pragma unroll
    for (int j = 0; j < 4; ++j) acc[i][j] = (f32x4){0.f, 0.f, 0.f, 0.f};

  const int fco = (quad ^ (r & 3)) * 8;

  const int nt = K >> 5;

  // prologue: stage tile 0 into buffer 0
#pragma unroll
  for (int j = 0; j < MI / 2; ++j)
    async16(Ag + (size_t)(16 * j) * lda, &As[0][(w * 8 * MI + 16 * j) * 32]);
  async16(Bg, &Bs[0][(w * 32) * 32]);
  async16(Bg + 16 * ldb, &Bs[0][(w * 32 + 16) * 32]);

  for (int t = 0; t < nt; ++t) {
    const int buf = t & 1;
    __syncthreads();  // stage(t) complete; buf^1 reads (iter t-1) done
    if (t + 1 < nt) {
      const int kk = 32 * (t + 1);
#pragma unroll
      for (int j = 0; j < MI / 2; ++j)
        async16(Ag + kk + (size_t)(16 * j) * lda, &As[buf ^ 1][(w * 8 * MI + 16 * j) * 32]);
      async16(Bg + kk, &Bs[buf ^ 1][(w * 32) * 32]);
      async16(Bg + kk + 16 * ldb, &Bs[buf ^ 1][(w * 32 + 16) * 32]);
    }

    short8 af[MI], bf[4];
#pragma unroll
    for (int mi = 0; mi < MI; ++mi)
      af[mi] = *reinterpret_cast<const short8*>(&As[buf][(wm + 16 * mi + r) * 32 + fco]);
#pragma unroll
    for (int ni = 0; ni < 4; ++ni)
      bf[ni] = *reinterpret_cast<const short8*>(&Bs[buf][(wn + 16 * ni + r) * 32 + fco]);
#pragma unroll
    for (int mi = 0; mi < MI; ++mi)
#pragma unroll
      for (int ni = 0; ni < 4; ++ni)
        acc[mi][ni] = __builtin_amdgcn_mfma_f32_16x16x32_bf16(af[mi], bf[ni], acc[mi][ni], 0, 0, 0);
  }

#pragma unroll
  for (int mi = 0; mi < MI; ++mi)
#pragma unroll
    for (int ni = 0; ni < 4; ++ni)
#pragma unroll
      for (int rr = 0; rr < 4; ++rr) {
        const int row = m0 + wm + 16 * mi + 4 * quad + rr;
        const int col = nc + wn + 16 * ni + r;
        c_store(&C[(size_t)row * ldc + col], acc[mi][ni][rr] + bias[col]);
      }
}

// =====================================================================
// Merged f32->bf16 convert for hs and rhs
// =====================================================================
__global__ __launch_bounds__(256) void conv2_kernel(
    const float* __restrict__ xa, u16* __restrict__ ya, int n8a,
    const float* __restrict__ xb, u16* __restrict__ yb, int n8b) {
  int i = blockIdx.x * 256 + threadIdx.x;
  const float* x;
  u16* y;
  if (i < n8a) {
    x = xa; y = ya;
  } else {
    i -= n8a;
    if (i >= n8b) return;
    x = xb; y = yb;
  }
  const float4 v0 = reinterpret_cast<const float4*>(x)[2 * i];
  const float4 v1 = reinterpret_cast<const float4*>(x)[2 * i + 1];
  uint4 rv;
  rv.x = (u32)f2b(v0.x) | ((u32)f2b(v0.y) << 16);
  rv.y = (u32)f2b(v0.z) | ((u32)f2b(v0.w) << 16);
  rv.z = (u32)f2b(v1.x) | ((u32)f2b(v1.y) << 16);
  rv.w = (u32)f2b(v1.z) | ((u32)f2b(v1.w) << 16);
  reinterpret_cast<uint4*>(y)[i] = rv;
}

// =====================================================================
// Transpose-convert, all 6 weights merged (W f32 [1536][1536] -> Wt^T bf16)
// =====================================================================
__device__ inline void transconv_body(const float* __restrict__ W, u16* __restrict__ Wt) {
  __shared__ __align__(16) u16 Ls[64 * 72];
  const int tid = threadIdx.x;
  const int k0 = blockIdx.y * 64;
  const int n0 = blockIdx.x * 64;
#pragma unroll
  for (int i = 0; i < 4; ++i) {
    const int c = tid + 256 * i;
    const int row = c >> 4;
    const int c4 = (c & 15) * 4;
    const float4 v = *reinterpret_cast<const float4*>(&W[(size_t)(k0 + row) * 1536 + n0 + c4]);
    Ls[(c4 + 0) * 72 + row] = f2b(v.x);
    Ls[(c4 + 1) * 72 + row] = f2b(v.y);
    Ls[(c4 + 2) * 72 + row] = f2b(v.z);
    Ls[(c4 + 3) * 72 + row] = f2b(v.w);
  }
  __syncthreads();
#pragma unroll
  for (int i = 0; i < 2; ++i) {
    const int c = tid + 256 * i;
    const int n = c >> 3;
    const int kc = (c & 7) * 8;
    u16 tmp[8];
#pragma unroll
    for (int j = 0; j < 8; ++j) tmp[j] = Ls[n * 72 + kc + j];
    *reinterpret_cast<uint4*>(&Wt[(size_t)(n0 + n) * 1536 + k0 + kc]) =
        *reinterpret_cast<const uint4*>(tmp);
  }
}

__global__ __launch_bounds__(256) void transconv6_kernel(
    const float* W0, const float* W1, const float* W2,
    const float* W3, const float* W4, const float* W5,
    u16* T0, u16* T1, u16* T2, u16* T3, u16* T4, u16* T5) {
  const int z = blockIdx.z;
  const float* W = z == 0 ? W0 : z == 1 ? W1 : z == 2 ? W2 : z == 3 ? W3 : z == 4 ? W4 : W5;
  u16* Wt = z == 0 ? T0 : z == 1 ? T1 : z == 2 ? T2 : z == 3 ? T3 : z == 4 ? T4 : T5;
  transconv_body(W, Wt);
}

// =====================================================================
// Merged RMSNorm: z=0 q-path (scaled by QS, plain+rope), z=1 k-path
// (rope), z=2 ref-k (1024 rows, plain). Verified r4-r6.
// =====================================================================
__global__ __launch_bounds__(256) void rmsnorm3_kernel(
    const u16* xq, const u16* xk, const u16* xkr,
    const float* gq, const float* gk,
    const float* rc, const float* rs,
    u16* oq_plain, u16* oq_rope, u16* ok_rope, u16* okr_plain) {
  __shared__ float red[4];
  const int z = blockIdx.y;
  const int row = blockIdx.x;
  if (z == 2 && row >= 1024) return;
  const u16* x; const float* g; u16* po; u16* pr; float sc;
  if (z == 0)      { x = xq;  g = gq; po = oq_plain; pr = oq_rope; sc = QS;  }
  else if (z == 1) { x = xk;  g = gk; po = nullptr;  pr = ok_rope; sc = 1.f; }
  else             { x = xkr; g = gk; po = okr_plain; pr = nullptr; sc = 1.f; }

  const int tid = threadIdx.x;
  const u32* xr = reinterpret_cast<const u32*>(x + (size_t)row * 1536);
  float xe[3], xo[3];
  float ss = 0.f;
#pragma unroll
  for (int j = 0; j < 3; ++j) {
    const u32 u = xr[tid + 256 * j];
    const float e = b2f((u16)(u & 0xffff));
    const float o = b2f((u16)(u >> 16));
    xe[j] = e; xo[j] = o;
    ss += e * e + o * o;
  }
#pragma unroll
  for (int off = 32; off; off >>= 1) ss += __shfl_xor(ss, off, 64);
  if ((tid & 63) == 0) red[tid >> 6] = ss;
  __syncthreads();
  const float total = red[0] + red[1] + red[2] + red[3];
  const float rinv = rsqrtf(total * (1.0f / 1536.0f) + 1e-6f) * sc;
  u32* po32 = po ? reinterpret_cast<u32*>(po + (size_t)row * 1536) : nullptr;
  u32* pr32 = pr ? reinterpret_cast<u32*>(pr + (size_t)row * 1536) : nullptr;
#pragma unroll
  for (int j = 0; j < 3; ++j) {
    const int p = tid + 256 * j;
    const float2 gg = reinterpret_cast<const float2*>(g)[p];
    const float e = xe[j] * rinv * gg.x;
    const float o = xo[j] * rinv * gg.y;
    if (po32) po32[p] = (u32)f2b(e) | ((u32)f2b(o) << 16);
    if (pr32) {
      const int i = p & 63;
      const float c = rc[row * 64 + i];
      const float s = rs[row * 64 + i];
      const float re = e * c - o * s;
      const float im = e * s + o * c;
      pr32[p] = (u32)f2b(re) | ((u32)f2b(im) << 16);
    }
  }
}

// =====================================================================
// Merged per-head V transpose (verified r4-r6)
// =====================================================================
__global__ __launch_bounds__(256) void vtrans2_kernel(
    const u16* __restrict__ V0, u16* __restrict__ Vt0,
    const u16* __restrict__ V1, u16* __restrict__ Vt1) {
  __shared__ __align__(16) u16 Ls[64 * 136];
  const int z = blockIdx.z;
  const int kvLen = z == 0 ? 4096 : 1024;
  const int kv0 = blockIdx.x * 64;
  if (kv0 >= kvLen) return;
  const u16* V = z == 0 ? V0 : V1;
  u16* Vt = z == 0 ? Vt0 : Vt1;
  const int tid = threadIdx.x;
  const int h = blockIdx.y;
#pragma unroll
  for (int i = 0; i < 4; ++i) {
    const int c = tid + 256 * i;
    const int row = c >> 4, c8 = c & 15;
    *reinterpret_cast<uint4*>(&Ls[row * 136 + 8 * c8]) =
        *reinterpret_cast<const uint4*>(V + (size_t)(kv0 + row) * 1536 + h * 128 + 8 * c8);
  }
  __syncthreads();
#pragma unroll
  for (int i = 0; i < 4; ++i) {
    const int c = tid + 256 * i;
    const int d = c >> 3, kc = c & 7;
    u16 tmp[8];
#pragma unroll
    for (int j = 0; j < 8; ++j) tmp[j] = Ls[(8 * kc + j) * 136 + d];
    *reinterpret_cast<uint4*>(Vt + ((size_t)h * 128 + d) * kvLen + kv0 + 8 * kc) =
        *reinterpret_cast<const uint4*>(tmp);
  }
}

// =====================================================================
// Flash attention, round-18: merge of two VALIDATED pieces only.
//  - Inner loop: EXACT r0 structure (two barriers/tile, joint K+V
//    staging, ab-LDS broadcast, no defer-max) — passed r0/r7/r8.
//  - Merge mechanics: r2's run_pass lambda (cross result normalized,
//    held in 32 VGPRs, register add in epilogue) — passed r2.
//  Deletes the f32 bO round-trip (25MB W + 25MB R) and one dispatch.
//  Register add is bit-identical to the f32 bO path -> absmax must
//  equal r0's 0.001464844.
//  r15/r17 phase-shifted schedule family ABANDONED (2 correctness
//  fails; cause not identifiable blind). Inner loop below is frozen
//  to harness-validated form.
//  LDS 38400 B; launch_bounds (256,3): Ocr[8] (+32 VGPR) live through
//  pass 2, cap 170 ample; grid 768 = 3 blocks/CU regardless.
// =====================================================================
__global__ __launch_bounds__(256, 3) void flash_kernel(
    const u16* __restrict__ Qc, const u16* __restrict__ Kc,
    const u16* __restrict__ Vc, int kvLenC,
    const u16* __restrict__ Qm, const u16* __restrict__ Km,
    const u16* __restrict__ Vm, int kvLenM,
    u16* __restrict__ Ob) {
  __shared__ __align__(16) u16 Ks[64 * 128];
  __shared__ __align__(16) u16 Vs[128 * 64];
  __shared__ __align__(16) u16 Pb[4][16 * 40];
  __shared__ __align__(16) float ab[4][16];

  const int tid = threadIdx.x;
  const int lane = tid & 63;
  const int w = tid >> 6;
  const int r = lane & 15;
  const int quad = lane >> 4;
  const int h = blockIdx.y;
  const int q0 = blockIdx.x * 64;
  const int qrow = q0 + 16 * w + r;
  const int sw = r & 7;

  auto run_pass = [&](const u16* __restrict__ Q, const u16* __restrict__ K,
                      const u16* __restrict__ Vt, int kvLen, f32x4* Oc) {
    // Q fragments (B-operand of S^T): lane holds Q[qrow][32ks+8quad+j]
    short8 qf[4];
    {
      const u16* qbase = Q + (size_t)qrow * 1536 + h * 128 + 8 * quad;
#pragma unroll
      for (int ks = 0; ks < 4; ++ks)
        qf[ks] = *reinterpret_cast<const short8*>(qbase + 32 * ks);
    }

    // staging: uniform bases + 32-bit per-lane element offsets (r0 layout)
    const u16* Kb = K + h * 128;
    const u16* Vb = Vt + (size_t)h * 128 * kvLen;
    u32 koff[4], voff[4];
    int klo[4], vlo[4];
    {
      const int p16 = lane & 15, rin = lane >> 4;
      const int p8 = lane & 7, din = lane >> 3;
#pragma unroll
      for (int j = 0; j < 4; ++j) {
        const int row = 16 * w + 4 * j + rin;
        koff[j] = (u32)row * 1536u + 8u * (u32)(p16 ^ (row & 15));
        klo[j] = (16 * w + 4 * j) * 128;
        const int d = 32 * w + 8 * j + din;
        voff[j] = (u32)d * (u32)kvLen + 8u * (u32)(p8 ^ (d & 7));
        vlo[j] = (32 * w + 8 * j) * 64;
      }
    }

#pragma unroll
    for (int dt = 0; dt < 8; ++dt) Oc[dt] = (f32x4){0.f, 0.f, 0.f, 0.f};
    float m_i = -1e30f, l_i = 0.f;

    const int nt = kvLen >> 6;
    for (int t = 0; t < nt; ++t) {
      __syncthreads();  // prior tile reads done
      {
        const size_t ko = (size_t)t * (64 * 1536);
        const size_t vo = (size_t)t * 64;
#pragma unroll
        for (int j = 0; j < 4; ++j) async16(Kb + ko + koff[j], &Ks[klo[j]]);
#pragma unroll
        for (int j = 0; j < 4; ++j) async16(Vb + vo + voff[j], &Vs[vlo[j]]);
      }
      __syncthreads();  // DMA complete

      // S^T = K * Q^T (log2-domain; Q pre-scaled)
      f32x4 St[4];
#pragma unroll
      for (int mt = 0; mt < 4; ++mt) St[mt] = (f32x4){0.f, 0.f, 0.f, 0.f};
#pragma unroll
      for (int mt = 0; mt < 4; ++mt) {
        const u16* kp = &Ks[(16 * mt + r) * 128];
#pragma unroll
        for (int ks = 0; ks < 4; ++ks) {
          const short8 af = *reinterpret_cast<const short8*>(kp + 8 * ((quad + 4 * ks) ^ r));
          St[mt] = __builtin_amdgcn_mfma_f32_16x16x32_bf16(af, qf[ks], St[mt], 0, 0, 0);
        }
      }

      // online softmax (base 2); lane owns q-row r
      float mloc = -1e30f;
#pragma unroll
      for (int mt = 0; mt < 4; ++mt)
#pragma unroll
        for (int rr = 0; rr < 4; ++rr) mloc = fmaxf(mloc, St[mt][rr]);
      mloc = fmaxf(mloc, __shfl_xor(mloc, 16, 64));
      mloc = fmaxf(mloc, __shfl_xor(mloc, 32, 64));
      const float mn = fmaxf(m_i, mloc);

      float alpha = 1.0f;
      if (__any(mloc > m_i)) {
        alpha = fexp2(m_i - mn);
        if (quad == 0) ab[w][r] = alpha;
        const float4 a4 = *reinterpret_cast<const float4*>(&ab[w][4 * quad]);
#pragma unroll
        for (int dt = 0; dt < 8; ++dt) {
          Oc[dt][0] *= a4.x; Oc[dt][1] *= a4.y; Oc[dt][2] *= a4.z; Oc[dt][3] *= a4.w;
        }
      }

      float psum = 0.f;
      uint2 pk[4];
#pragma unroll
      for (int mt = 0; mt < 4; ++mt) {
        const float p0 = fexp2(St[mt][0] - mn);
        const float p1 = fexp2(St[mt][1] - mn);
        const float p2 = fexp2(St[mt][2] - mn);
        const float p3 = fexp2(St[mt][3] - mn);
        psum += (p0 + p1) + (p2 + p3);
        pk[mt].x = pack_bf16_rn(p0, p1);
        pk[mt].y = pack_bf16_rn(p2, p3);
      }
      psum += __shfl_xor(psum, 16, 64);
      psum += __shfl_xor(psum, 32, 64);
      l_i = l_i * alpha + psum;
      m_i = mn;

      // PV in two k-halves, reusing the 16x40 wave-private Pb region.
      // half A: kpos 0..31
#pragma unroll
      for (int mt = 0; mt < 2; ++mt)
        *reinterpret_cast<uint2*>(&Pb[w][r * 40 + 16 * mt + 4 * quad]) = pk[mt];
      {
        const short8 pa0 = *reinterpret_cast<const short8*>(&Pb[w][r * 40 + 8 * quad]);
#pragma unroll
        for (int dt = 0; dt < 8; ++dt) {
          const int d = 16 * dt + r;
          const short8 b0 = *reinterpret_cast<const short8*>(&Vs[d * 64 + 8 * (quad ^ sw)]);
          Oc[dt] = __builtin_amdgcn_mfma_f32_16x16x32_bf16(pa0, b0, Oc[dt], 0, 0, 0);
        }
      }
      // half B: kpos 32..63 (same-wave LDS in-order: safe overwrite)
#pragma unroll
      for (int mt = 2; mt < 4; ++mt)
        *reinterpret_cast<uint2*>(&Pb[w][r * 40 + 16 * (mt - 2) + 4 * quad]) = pk[mt];
      {
        const short8 pa1 = *reinterpret_cast<const short8*>(&Pb[w][r * 40 + 8 * quad]);
#pragma unroll
        for (int dt = 0; dt < 8; ++dt) {
          const int d = 16 * dt + r;
          const short8 b1 = *reinterpret_cast<const short8*>(&Vs[d * 64 + 8 * ((4 + quad) ^ sw)]);
          Oc[dt] = __builtin_amdgcn_mfma_f32_16x16x32_bf16(pa1, b1, Oc[dt], 0, 0, 0);
        }
      }
    }

    // normalize by 1/l (LDS broadcast, wave-private)
    if (quad == 0) ab[w][r] = 1.0f / l_i;
    const float4 li4 = *reinterpret_cast<const float4*>(&ab[w][4 * quad]);
#pragma unroll
    for (int dt = 0; dt < 8; ++dt) {
      Oc[dt][0] *= li4.x; Oc[dt][1] *= li4.y; Oc[dt][2] *= li4.z; Oc[dt][3] *= li4.w;
    }
  };

  f32x4 Ocr[8];  // cross-attn result, normalized, held in regs
  run_pass(Qc, Kc, Vc, kvLenC, Ocr);
  __syncthreads();  // all cross LDS reads done before main re-stages
  f32x4 Oc[8];
  run_pass(Qm, Km, Vm, kvLenM, Oc);

  // store bf16: main + cross (register add; bit-identical to bO path)
  u16* obb = Ob + (size_t)(q0 + 16 * w) * 1536 + h * 128;
#pragma unroll
  for (int rr = 0; rr < 4; ++rr) {
    u16* brow = obb + (size_t)(4 * quad + rr) * 1536 + r;
#pragma unroll
    for (int dt = 0; dt < 8; ++dt)
      brow[16 * dt] = f2b(Oc[dt][rr] + Ocr[dt][rr]);
  }
}

// =====================================================================
// Host orchestration (8 dispatches)
// =====================================================================
extern "C" void kernel_launch(void* const* d_in, const int* in_sizes, int n_in,
                              void* d_out, int out_size, void* d_ws, size_t ws_size,
                              hipStream_t stream) {
  (void)in_sizes; (void)n_in; (void)out_size; (void)ws_size;
  constexpr int T = 4096, TR = 1024, DIM = 1536, NH = 12;

  const float* hs  = (const float*)d_in[0];
  const float* rhs = (const float*)d_in[1];
  const float* rc  = (const float*)d_in[2];
  const float* rs  = (const float*)d_in[3];
  const float* Wq  = (const float*)d_in[4];
  const float* bq  = (const float*)d_in[5];
  const float* Wk  = (const float*)d_in[6];
  const float* bk  = (const float*)d_in[7];
  const float* Wv  = (const float*)d_in[8];
  const float* bv  = (const float*)d_in[9];
  const float* Wkr = (const float*)d_in[10];
  const float* bkr = (const float*)d_in[11];
  const float* Wvr = (const float*)d_in[12];
  const float* bvr = (const float*)d_in[13];
  const float* Wo  = (const float*)d_in[14];
  const float* bo  = (const float*)d_in[15];
  const float* gq  = (const float*)d_in[16];
  const float* gk  = (const float*)d_in[17];
  float* out = (float*)d_out;

  char* ws = (char*)d_ws;
  size_t off = 0;
  auto alloc = [&](size_t bytes) -> void* {
    void* p = ws + off;
    off += (bytes + 255) & ~(size_t)255;
    return p;
  };
  u16* bQ    = (u16*)alloc((size_t)T * DIM * 2);
  u16* bQr   = (u16*)alloc((size_t)T * DIM * 2);
  u16* bK    = (u16*)alloc((size_t)T * DIM * 2);
  u16* bV    = (u16*)alloc((size_t)T * DIM * 2);
  u16* bKr   = (u16*)alloc((size_t)TR * DIM * 2);
  u16* bVr   = (u16*)alloc((size_t)TR * DIM * 2);
  u16* bHs   = (u16*)alloc((size_t)T * DIM * 2);       // bf16 hs; ALIAS-> VtG
  u16* bRhs  = (u16*)alloc((size_t)TR * DIM * 2);      // bf16 rhs; ALIAS-> VtR
  u16* bWqkv = (u16*)alloc((size_t)3 * DIM * DIM * 2); // WqT|WkT|WvT; ALIAS-> bOb
  u16* bWr   = (u16*)alloc((size_t)2 * DIM * DIM * 2); // WkrT|WvrT
  u16* bWoT  = (u16*)alloc((size_t)DIM * DIM * 2);     // WoT (own slab)
  u16* VtG = bHs;
  u16* VtR = bRhs;
  u16* bOb = bWqkv;

  const dim3 blk(256);

  // 1. f32->bf16 converts (merged)
  conv2_kernel<<<dim3((T * DIM / 8 + TR * DIM / 8 + 255) / 256), blk, 0, stream>>>(
      hs, bHs, T * DIM / 8, rhs, bRhs, TR * DIM / 8);

  // 2. weight transpose-converts (all six merged)
  transconv6_kernel<<<dim3(24, 24, 6), blk, 0, stream>>>(
      Wq, Wk, Wv, Wkr, Wvr, Wo,
      bWqkv + 0 * (size_t)DIM * DIM, bWqkv + 1 * (size_t)DIM * DIM,
      bWqkv + 2 * (size_t)DIM * DIM, bWr + 0 * (size_t)DIM * DIM,
      bWr + 1 * (size_t)DIM * DIM, bWoT);

  // 3-4. projections (QKV fused 128-tile; KrVr 64-tile for occupancy)
  gemm128_kernel<4, u16><<<dim3(36, 32), blk, 0, stream>>>(
      bHs, DIM, bWqkv, DIM, bQ, bK, bV, DIM, bq, bk, bv, DIM);
  gemm128_kernel<2, u16><<<dim3(24, 16), blk, 0, stream>>>(
      bRhs, DIM, bWr, DIM, bKr, bVr, (u16*)nullptr, DIM, bkr, bvr, nullptr, DIM);

  // 5. rmsnorm/rope (merged; q-path pre-scaled by QS)
  rmsnorm3_kernel<<<dim3(T, 3), blk, 0, stream>>>(
      bQ, bK, bKr, gq, gk, rc, rs, bQ, bQr, bK, bKr);

  // 6. per-head V transposes (merged; alias buffers are dead)
  vtrans2_kernel<<<dim3(T / 64, NH, 2), blk, 0, stream>>>(bV, VtG, bVr, VtR);

  // 7. merged flash attention: cross (kv=1024) + main (kv=4096), adds in regs
  flash_kernel<<<dim3(T / 64, NH), blk, 0, stream>>>(
      bQ, bKr, VtR, TR, bQr, bK, VtG, T, bOb);

  // 8. output projection (64-row tiles for occupancy)
  gemm128_kernel<2, float><<<dim3(12, 64), blk, 0, stream>>>(
      bOb, DIM, bWoT, DIM, out, (float*)nullptr, (float*)nullptr, DIM, bo, nullptr, nullptr, DIM);
}

// Round 13
// 497.715 us; speedup vs baseline: 1.6617x; 1.0391x over previous
//
#include <hip/hip_runtime.h>

typedef unsigned short u16;
typedef unsigned int u32;
typedef __attribute__((ext_vector_type(8))) short short8;
typedef __attribute__((ext_vector_type(4))) float f32x4;

// ---------- bf16 helpers ----------
__device__ inline u16 f2b(float f) {  // RNE
  u32 u = __builtin_bit_cast(u32, f);
  u += 0x7fff + ((u >> 16) & 1);
  return (u16)(u >> 16);
}
__device__ inline float b2f(u16 u) {
  return __builtin_bit_cast(float, (u32)u << 16);
}
// round-to-nearest (ties away) pack — cheaper than RNE, used for P only
__device__ inline u32 pack_bf16_rn(float a, float b) {
  const u32 ua = __builtin_bit_cast(u32, a) + 0x8000u;
  const u32 ub = __builtin_bit_cast(u32, b) + 0x8000u;
  return (ua >> 16) | (ub & 0xffff0000u);
}
__device__ inline void c_store(float* p, float v) { *p = v; }
__device__ inline void c_store(u16* p, float v) { *p = f2b(v); }

__device__ inline float fexp2(float x) {
#if __has_builtin(__builtin_amdgcn_exp2f)
  return __builtin_amdgcn_exp2f(x);
#else
  return exp2f(x);
#endif
}

// ---------- async global->LDS, 16B per lane ----------
typedef const __attribute__((address_space(1))) u32 gu32;
typedef __attribute__((address_space(3))) u32 lu32;
__device__ inline void async16(const u16* g, u16* l) {
  __builtin_amdgcn_global_load_lds((gu32*)g, (lu32*)l, 16, 0, 0);
}

// Q scale folded into rmsnorm producer: 1/sqrt(128) * log2(e)
#define QS (0.08838834764831843f * 1.4426950408889634f)

// =====================================================================
// (32*MI)x128x(K,BK=32) bf16 GEMM. r14 structure (verified r8):
// single-barrier LDS double-buffer + r13 XCD-locality remap.
// Used for the output projection only (QKV/KrVr moved to the merged
// kernel below).
// =====================================================================
template <int MI, typename TC>
__global__ __launch_bounds__(256) void gemm128_kernel(
    const u16* __restrict__ A, long lda,
    const u16* __restrict__ Bt, long ldb,
    TC* __restrict__ C0, TC* __restrict__ C1, TC* __restrict__ C2, long ldc,
    const float* b0, const float* b1, const float* b2,
    int K) {
  __shared__ __align__(16) u16 As[2][32 * MI * 32];
  __shared__ __align__(16) u16 Bs[2][128 * 32];

  const int tid = threadIdx.x;
  const int lane = tid & 63;
  const int w = tid >> 6;
  const int r = lane & 15;
  const int quad = lane >> 4;

  // ---- XCD-locality remap (bijective when ny % 8 == 0) ----
  int bx = blockIdx.x, by = blockIdx.y;
  {
    const int ny = gridDim.y;
    if ((ny & 7) == 0) {
      const int lin = by * gridDim.x + bx;
      const int xcd = lin & 7;
      const int k = lin >> 3;
      const int rpx = ny >> 3;                 // A-row panels per XCD
      by = xcd * rpx + (k % rpx);
      bx = k / rpx;
    }
  }
  const int m0 = by * (32 * MI);
  const int nb = bx * 128;
  const int seg = nb / 1536;
  const int nc = nb - seg * 1536;
  TC* C = seg == 0 ? C0 : (seg == 1 ? C1 : C2);
  const float* bias = seg == 0 ? b0 : (seg == 1 ? b1 : b2);

  const int srow = lane >> 2;
  const int sx = ((lane & 3) ^ (srow & 3)) * 8;
  const u16* Ag = A + (size_t)(m0 + w * 8 * MI + srow) * lda + sx;
  const u16* Bg = Bt + (size_t)(nb + w * 32 + srow) * ldb + sx;

  const int wm = (w >> 1) * (16 * MI);
  const int wn = (w & 1) * 64;

  f32x4 acc[MI][4];
#pragma unroll
  for (int i = 0; i < MI; ++i)
#pragma unroll
    for (int j = 0; j < 4; ++j) acc[i][j] = (f32x4){0.f, 0.f, 0.f, 0.f};

  const int fco = (quad ^ (r & 3)) * 8;

  const int nt = K >> 5;

  // prologue: stage tile 0 into buffer 0
#pragma unroll
  for (int j = 0; j < MI / 2; ++j)
    async16(Ag + (size_t)(16 * j) * lda, &As[0][(w * 8 * MI + 16 * j) * 32]);
  async16(Bg, &Bs[0][(w * 32) * 32]);
  async16(Bg + 16 * ldb, &Bs[0][(w * 32 + 16) * 32]);

  for (int t = 0; t < nt; ++t) {
    const int buf = t & 1;
    __syncthreads();  // stage(t) complete; buf^1 reads (iter t-1) done
    if (t + 1 < nt) {
      const int kk = 32 * (t + 1);
#pragma unroll
      for (int j = 0; j < MI / 2; ++j)
        async16(Ag + kk + (size_t)(16 * j) * lda, &As[buf ^ 1][(w * 8 * MI + 16 * j) * 32]);
      async16(Bg + kk, &Bs[buf ^ 1][(w * 32) * 32]);
      async16(Bg + kk + 16 * ldb, &Bs[buf ^ 1][(w * 32 + 16) * 32]);
    }

    short8 af[MI], bf[4];
#pragma unroll
    for (int mi = 0; mi < MI; ++mi)
      af[mi] = *reinterpret_cast<const short8*>(&As[buf][(wm + 16 * mi + r) * 32 + fco]);
#pragma unroll
    for (int ni = 0; ni < 4; ++ni)
      bf[ni] = *reinterpret_cast<const short8*>(&Bs[buf][(wn + 16 * ni + r) * 32 + fco]);
#pragma unroll
    for (int mi = 0; mi < MI; ++mi)
#pragma unroll
      for (int ni = 0; ni < 4; ++ni)
        acc[mi][ni] = __builtin_amdgcn_mfma_f32_16x16x32_bf16(af[mi], bf[ni], acc[mi][ni], 0, 0, 0);
  }

#pragma unroll
  for (int mi = 0; mi < MI; ++mi)
#pragma unroll
    for (int ni = 0; ni < 4; ++ni)
#pragma unroll
      for (int rr = 0; rr < 4; ++rr) {
        const int row = m0 + wm + 16 * mi + 4 * quad + rr;
        const int col = nc + wn + 16 * ni + r;
        c_store(&C[(size_t)row * ldc + col], acc[mi][ni][rr] + bias[col]);
      }
}

// =====================================================================
// Merged QKV + KrVr GEMM (r19). Body = gemm128 MI=4 verbatim (verified
// r8/r12); only NEW code is the block-decode preamble (same category as
// the r13 remap). 1344 blocks = 1152 QKV (M=4096, N=4608) + 192 KrVr
// (M=1024, N=3072, now MI=4: occupancy comes from the merged grid).
// XCD swizzle: 1344 = 8*168 -> swz = (lin&7)*168 + (lin>>3), bijective.
// Fixes KrVr's 1.5-blocks/CU occupancy starvation + fills QKV's tail.
// All dims are the common 1536 (lda=ldb=ldc=1536, K=1536).
// =====================================================================
__global__ __launch_bounds__(256) void gemm_qkvr_kernel(
    const u16* __restrict__ A1, const u16* __restrict__ B1,
    u16* __restrict__ Cq, u16* __restrict__ Ck, u16* __restrict__ Cv,
    const float* bq, const float* bk, const float* bv,
    const u16* __restrict__ A2, const u16* __restrict__ B2,
    u16* __restrict__ Ckr, u16* __restrict__ Cvr,
    const float* bkr, const float* bvr) {
  constexpr int MI = 4;
  __shared__ __align__(16) u16 As[2][32 * MI * 32];
  __shared__ __align__(16) u16 Bs[2][128 * 32];

  const int tid = threadIdx.x;
  const int lane = tid & 63;
  const int w = tid >> 6;
  const int r = lane & 15;
  const int quad = lane >> 4;

  // ---- decode: XCD swizzle then GEMM select ----
  const int lin = blockIdx.x;                 // 0..1343
  const int swz = (lin & 7) * 168 + (lin >> 3);
  const u16 *A, *Bt;
  u16* C;
  const float* bias;
  int m0, nb, nc;
  if (swz < 1152) {                           // QKV
    const int by = swz / 36, bx = swz - 36 * by;
    m0 = by * 128;
    nb = bx * 128;
    const int seg = nb / 1536;
    nc = nb - seg * 1536;
    A = A1; Bt = B1;
    C = seg == 0 ? Cq : (seg == 1 ? Ck : Cv);
    bias = seg == 0 ? bq : (seg == 1 ? bk : bv);
  } else {                                    // KrVr
    const int s2 = swz - 1152;                // 0..191
    const int by = s2 / 24, bx = s2 - 24 * by;
    m0 = by * 128;                            // < 1024
    nb = bx * 128;                            // < 3072
    const int seg = (nb >= 1536) ? 1 : 0;
    nc = nb - seg * 1536;
    A = A2; Bt = B2;
    C = seg == 0 ? Ckr : Cvr;
    bias = seg == 0 ? bkr : bvr;
  }

  const int srow = lane >> 2;
  const int sx = ((lane & 3) ^ (srow & 3)) * 8;
  const u16* Ag = A + (size_t)(m0 + w * 8 * MI + srow) * 1536 + sx;
  const u16* Bg = Bt + (size_t)(nb + w * 32 + srow) * 1536 + sx;

  const int wm = (w >> 1) * (16 * MI);
  const int wn = (w & 1) * 64;

  f32x4 acc[MI][4];
#pragma unroll
  for (int i = 0; i < MI; ++i)
#pragma unroll
    for (int j = 0; j < 4; ++j) acc[i][j] = (f32x4){0.f, 0.f, 0.f, 0.f};

  const int fco = (quad ^ (r & 3)) * 8;

  const int nt = 1536 >> 5;  // 48

  // prologue: stage tile 0 into buffer 0
#pragma unroll
  for (int j = 0; j < MI / 2; ++j)
    async16(Ag + (size_t)(16 * j) * 1536, &As[0][(w * 8 * MI + 16 * j) * 32]);
  async16(Bg, &Bs[0][(w * 32) * 32]);
  async16(Bg + 16 * 1536, &Bs[0][(w * 32 + 16) * 32]);

  for (int t = 0; t < nt; ++t) {
    const int buf = t & 1;
    __syncthreads();  // stage(t) complete; buf^1 reads (iter t-1) done
    if (t + 1 < nt) {
      const int kk = 32 * (t + 1);
#pragma unroll
      for (int j = 0; j < MI / 2; ++j)
        async16(Ag + kk + (size_t)(16 * j) * 1536, &As[buf ^ 1][(w * 8 * MI + 16 * j) * 32]);
      async16(Bg + kk, &Bs[buf ^ 1][(w * 32) * 32]);
      async16(Bg + kk + 16 * 1536, &Bs[buf ^ 1][(w * 32 + 16) * 32]);
    }

    short8 af[MI], bf[4];
#pragma unroll
    for (int mi = 0; mi < MI; ++mi)
      af[mi] = *reinterpret_cast<const short8*>(&As[buf][(wm + 16 * mi + r) * 32 + fco]);
#pragma unroll
    for (int ni = 0; ni < 4; ++ni)
      bf[ni] = *reinterpret_cast<const short8*>(&Bs[buf][(wn + 16 * ni + r) * 32 + fco]);
#pragma unroll
    for (int mi = 0; mi < MI; ++mi)
#pragma unroll
      for (int ni = 0; ni < 4; ++ni)
        acc[mi][ni] = __builtin_amdgcn_mfma_f32_16x16x32_bf16(af[mi], bf[ni], acc[mi][ni], 0, 0, 0);
  }

#pragma unroll
  for (int mi = 0; mi < MI; ++mi)
#pragma unroll
    for (int ni = 0; ni < 4; ++ni)
#pragma unroll
      for (int rr = 0; rr < 4; ++rr) {
        const int row = m0 + wm + 16 * mi + 4 * quad + rr;
        const int col = nc + wn + 16 * ni + r;
        c_store(&C[(size_t)row * 1536 + col], acc[mi][ni][rr] + bias[col]);
      }
}

// =====================================================================
// Merged f32->bf16 convert for hs and rhs
// =====================================================================
__global__ __launch_bounds__(256) void conv2_kernel(
    const float* __restrict__ xa, u16* __restrict__ ya, int n8a,
    const float* __restrict__ xb, u16* __restrict__ yb, int n8b) {
  int i = blockIdx.x * 256 + threadIdx.x;
  const float* x;
  u16* y;
  if (i < n8a) {
    x = xa; y = ya;
  } else {
    i -= n8a;
    if (i >= n8b) return;
    x = xb; y = yb;
  }
  const float4 v0 = reinterpret_cast<const float4*>(x)[2 * i];
  const float4 v1 = reinterpret_cast<const float4*>(x)[2 * i + 1];
  uint4 rv;
  rv.x = (u32)f2b(v0.x) | ((u32)f2b(v0.y) << 16);
  rv.y = (u32)f2b(v0.z) | ((u32)f2b(v0.w) << 16);
  rv.z = (u32)f2b(v1.x) | ((u32)f2b(v1.y) << 16);
  rv.w = (u32)f2b(v1.z) | ((u32)f2b(v1.w) << 16);
  reinterpret_cast<uint4*>(y)[i] = rv;
}

// =====================================================================
// Transpose-convert, all 6 weights merged (W f32 [1536][1536] -> Wt^T bf16)
// =====================================================================
__device__ inline void transconv_body(const float* __restrict__ W, u16* __restrict__ Wt) {
  __shared__ __align__(16) u16 Ls[64 * 72];
  const int tid = threadIdx.x;
  const int k0 = blockIdx.y * 64;
  const int n0 = blockIdx.x * 64;
#pragma unroll
  for (int i = 0; i < 4; ++i) {
    const int c = tid + 256 * i;
    const int row = c >> 4;
    const int c4 = (c & 15) * 4;
    const float4 v = *reinterpret_cast<const float4*>(&W[(size_t)(k0 + row) * 1536 + n0 + c4]);
    Ls[(c4 + 0) * 72 + row] = f2b(v.x);
    Ls[(c4 + 1) * 72 + row] = f2b(v.y);
    Ls[(c4 + 2) * 72 + row] = f2b(v.z);
    Ls[(c4 + 3) * 72 + row] = f2b(v.w);
  }
  __syncthreads();
#pragma unroll
  for (int i = 0; i < 2; ++i) {
    const int c = tid + 256 * i;
    const int n = c >> 3;
    const int kc = (c & 7) * 8;
    u16 tmp[8];
#pragma unroll
    for (int j = 0; j < 8; ++j) tmp[j] = Ls[n * 72 + kc + j];
    *reinterpret_cast<uint4*>(&Wt[(size_t)(n0 + n) * 1536 + k0 + kc]) =
        *reinterpret_cast<const uint4*>(tmp);
  }
}

__global__ __launch_bounds__(256) void transconv6_kernel(
    const float* W0, const float* W1, const float* W2,
    const float* W3, const float* W4, const float* W5,
    u16* T0, u16* T1, u16* T2, u16* T3, u16* T4, u16* T5) {
  const int z = blockIdx.z;
  const float* W = z == 0 ? W0 : z == 1 ? W1 : z == 2 ? W2 : z == 3 ? W3 : z == 4 ? W4 : W5;
  u16* Wt = z == 0 ? T0 : z == 1 ? T1 : z == 2 ? T2 : z == 3 ? T3 : z == 4 ? T4 : T5;
  transconv_body(W, Wt);
}

// =====================================================================
// Merged RMSNorm: z=0 q-path (scaled by QS, plain+rope), z=1 k-path
// (rope), z=2 ref-k (1024 rows, plain). Verified r4-r6.
// =====================================================================
__global__ __launch_bounds__(256) void rmsnorm3_kernel(
    const u16* xq, const u16* xk, const u16* xkr,
    const float* gq, const float* gk,
    const float* rc, const float* rs,
    u16* oq_plain, u16* oq_rope, u16* ok_rope, u16* okr_plain) {
  __shared__ float red[4];
  const int z = blockIdx.y;
  const int row = blockIdx.x;
  if (z == 2 && row >= 1024) return;
  const u16* x; const float* g; u16* po; u16* pr; float sc;
  if (z == 0)      { x = xq;  g = gq; po = oq_plain; pr = oq_rope; sc = QS;  }
  else if (z == 1) { x = xk;  g = gk; po = nullptr;  pr = ok_rope; sc = 1.f; }
  else             { x = xkr; g = gk; po = okr_plain; pr = nullptr; sc = 1.f; }

  const int tid = threadIdx.x;
  const u32* xr = reinterpret_cast<const u32*>(x + (size_t)row * 1536);
  float xe[3], xo[3];
  float ss = 0.f;
#pragma unroll
  for (int j = 0; j < 3; ++j) {
    const u32 u = xr[tid + 256 * j];
    const float e = b2f((u16)(u & 0xffff));
    const float o = b2f((u16)(u >> 16));
    xe[j] = e; xo[j] = o;
    ss += e * e + o * o;
  }
#pragma unroll
  for (int off = 32; off; off >>= 1) ss += __shfl_xor(ss, off, 64);
  if ((tid & 63) == 0) red[tid >> 6] = ss;
  __syncthreads();
  const float total = red[0] + red[1] + red[2] + red[3];
  const float rinv = rsqrtf(total * (1.0f / 1536.0f) + 1e-6f) * sc;
  u32* po32 = po ? reinterpret_cast<u32*>(po + (size_t)row * 1536) : nullptr;
  u32* pr32 = pr ? reinterpret_cast<u32*>(pr + (size_t)row * 1536) : nullptr;
#pragma unroll
  for (int j = 0; j < 3; ++j) {
    const int p = tid + 256 * j;
    const float2 gg = reinterpret_cast<const float2*>(g)[p];
    const float e = xe[j] * rinv * gg.x;
    const float o = xo[j] * rinv * gg.y;
    if (po32) po32[p] = (u32)f2b(e) | ((u32)f2b(o) << 16);
    if (pr32) {
      const int i = p & 63;
      const float c = rc[row * 64 + i];
      const float s = rs[row * 64 + i];
      const float re = e * c - o * s;
      const float im = e * s + o * c;
      pr32[p] = (u32)f2b(re) | ((u32)f2b(im) << 16);
    }
  }
}

// =====================================================================
// Merged per-head V transpose (verified r4-r6)
// =====================================================================
__global__ __launch_bounds__(256) void vtrans2_kernel(
    const u16* __restrict__ V0, u16* __restrict__ Vt0,
    const u16* __restrict__ V1, u16* __restrict__ Vt1) {
  __shared__ __align__(16) u16 Ls[64 * 136];
  const int z = blockIdx.z;
  const int kvLen = z == 0 ? 4096 : 1024;
  const int kv0 = blockIdx.x * 64;
  if (kv0 >= kvLen) return;
  const u16* V = z == 0 ? V0 : V1;
  u16* Vt = z == 0 ? Vt0 : Vt1;
  const int tid = threadIdx.x;
  const int h = blockIdx.y;
#pragma unroll
  for (int i = 0; i < 4; ++i) {
    const int c = tid + 256 * i;
    const int row = c >> 4, c8 = c & 15;
    *reinterpret_cast<uint4*>(&Ls[row * 136 + 8 * c8]) =
        *reinterpret_cast<const uint4*>(V + (size_t)(kv0 + row) * 1536 + h * 128 + 8 * c8);
  }
  __syncthreads();
#pragma unroll
  for (int i = 0; i < 4; ++i) {
    const int c = tid + 256 * i;
    const int d = c >> 3, kc = c & 7;
    u16 tmp[8];
#pragma unroll
    for (int j = 0; j < 8; ++j) tmp[j] = Ls[(8 * kc + j) * 136 + d];
    *reinterpret_cast<uint4*>(Vt + ((size_t)h * 128 + d) * kvLen + kv0 + 8 * kc) =
        *reinterpret_cast<const uint4*>(tmp);
  }
}

// =====================================================================
// Flash attention (r19): r12's merged kernel (passed, 219 µs) with ONE
// triple-validated addition: defer-max (T13, thr 11.5 log2) exactly as
// in r1/r2/r6 (all passed, absmax 0.001464844). Inner loop otherwise
// frozen to the r0-validated form.
// =====================================================================
__global__ __launch_bounds__(256, 3) void flash_kernel(
    const u16* __restrict__ Qc, const u16* __restrict__ Kc,
    const u16* __restrict__ Vc, int kvLenC,
    const u16* __restrict__ Qm, const u16* __restrict__ Km,
    const u16* __restrict__ Vm, int kvLenM,
    u16* __restrict__ Ob) {
  __shared__ __align__(16) u16 Ks[64 * 128];
  __shared__ __align__(16) u16 Vs[128 * 64];
  __shared__ __align__(16) u16 Pb[4][16 * 40];
  __shared__ __align__(16) float ab[4][16];

  const int tid = threadIdx.x;
  const int lane = tid & 63;
  const int w = tid >> 6;
  const int r = lane & 15;
  const int quad = lane >> 4;
  const int h = blockIdx.y;
  const int q0 = blockIdx.x * 64;
  const int qrow = q0 + 16 * w + r;
  const int sw = r & 7;

  auto run_pass = [&](const u16* __restrict__ Q, const u16* __restrict__ K,
                      const u16* __restrict__ Vt, int kvLen, f32x4* Oc) {
    // Q fragments (B-operand of S^T): lane holds Q[qrow][32ks+8quad+j]
    short8 qf[4];
    {
      const u16* qbase = Q + (size_t)qrow * 1536 + h * 128 + 8 * quad;
#pragma unroll
      for (int ks = 0; ks < 4; ++ks)
        qf[ks] = *reinterpret_cast<const short8*>(qbase + 32 * ks);
    }

    // staging: uniform bases + 32-bit per-lane element offsets (r0 layout)
    const u16* Kb = K + h * 128;
    const u16* Vb = Vt + (size_t)h * 128 * kvLen;
    u32 koff[4], voff[4];
    int klo[4], vlo[4];
    {
      const int p16 = lane & 15, rin = lane >> 4;
      const int p8 = lane & 7, din = lane >> 3;
#pragma unroll
      for (int j = 0; j < 4; ++j) {
        const int row = 16 * w + 4 * j + rin;
        koff[j] = (u32)row * 1536u + 8u * (u32)(p16 ^ (row & 15));
        klo[j] = (16 * w + 4 * j) * 128;
        const int d = 32 * w + 8 * j + din;
        voff[j] = (u32)d * (u32)kvLen + 8u * (u32)(p8 ^ (d & 7));
        vlo[j] = (32 * w + 8 * j) * 64;
      }
    }

#pragma unroll
    for (int dt = 0; dt < 8; ++dt) Oc[dt] = (f32x4){0.f, 0.f, 0.f, 0.f};
    float m_i = -1e30f, l_i = 0.f;

    const int nt = kvLen >> 6;
    for (int t = 0; t < nt; ++t) {
      __syncthreads();  // prior tile reads done
      {
        const size_t ko = (size_t)t * (64 * 1536);
        const size_t vo = (size_t)t * 64;
#pragma unroll
        for (int j = 0; j < 4; ++j) async16(Kb + ko + koff[j], &Ks[klo[j]]);
#pragma unroll
        for (int j = 0; j < 4; ++j) async16(Vb + vo + voff[j], &Vs[vlo[j]]);
      }
      __syncthreads();  // DMA complete

      // S^T = K * Q^T (log2-domain; Q pre-scaled)
      f32x4 St[4];
#pragma unroll
      for (int mt = 0; mt < 4; ++mt) St[mt] = (f32x4){0.f, 0.f, 0.f, 0.f};
#pragma unroll
      for (int mt = 0; mt < 4; ++mt) {
        const u16* kp = &Ks[(16 * mt + r) * 128];
#pragma unroll
        for (int ks = 0; ks < 4; ++ks) {
          const short8 af = *reinterpret_cast<const short8*>(kp + 8 * ((quad + 4 * ks) ^ r));
          St[mt] = __builtin_amdgcn_mfma_f32_16x16x32_bf16(af, qf[ks], St[mt], 0, 0, 0);
        }
      }

      // online softmax (base 2); lane owns q-row r; defer-max (r2/r6 form)
      float mloc = -1e30f;
#pragma unroll
      for (int mt = 0; mt < 4; ++mt)
#pragma unroll
        for (int rr = 0; rr < 4; ++rr) mloc = fmaxf(mloc, St[mt][rr]);
      mloc = fmaxf(mloc, __shfl_xor(mloc, 16, 64));
      mloc = fmaxf(mloc, __shfl_xor(mloc, 32, 64));

      float alpha = 1.0f;
      if (__any(mloc > m_i + 11.5f)) {  // defer-max: rescale only on big growth
        const float mn = fmaxf(m_i, mloc);
        alpha = fexp2(m_i - mn);
        m_i = mn;
        if (quad == 0) ab[w][r] = alpha;
        const float4 a4 = *reinterpret_cast<const float4*>(&ab[w][4 * quad]);
#pragma unroll
        for (int dt = 0; dt < 8; ++dt) {
          Oc[dt][0] *= a4.x; Oc[dt][1] *= a4.y; Oc[dt][2] *= a4.z; Oc[dt][3] *= a4.w;
        }
      }

      float psum = 0.f;
      uint2 pk[4];
#pragma unroll
      for (int mt = 0; mt < 4; ++mt) {
        const float p0 = fexp2(St[mt][0] - m_i);
        const float p1 = fexp2(St[mt][1] - m_i);
        const float p2 = fexp2(St[mt][2] - m_i);
        const float p3 = fexp2(St[mt][3] - m_i);
        psum += (p0 + p1) + (p2 + p3);
        pk[mt].x = pack_bf16_rn(p0, p1);
        pk[mt].y = pack_bf16_rn(p2, p3);
      }
      psum += __shfl_xor(psum, 16, 64);
      psum += __shfl_xor(psum, 32, 64);
      l_i = l_i * alpha + psum;

      // PV in two k-halves, reusing the 16x40 wave-private Pb region.
      // half A: kpos 0..31
#pragma unroll
      for (int mt = 0; mt < 2; ++mt)
        *reinterpret_cast<uint2*>(&Pb[w][r * 40 + 16 * mt + 4 * quad]) = pk[mt];
      {
        const short8 pa0 = *reinterpret_cast<const short8*>(&Pb[w][r * 40 + 8 * quad]);
#pragma unroll
        for (int dt = 0; dt < 8; ++dt) {
          const int d = 16 * dt + r;
          const short8 b0 = *reinterpret_cast<const short8*>(&Vs[d * 64 + 8 * (quad ^ sw)]);
          Oc[dt] = __builtin_amdgcn_mfma_f32_16x16x32_bf16(pa0, b0, Oc[dt], 0, 0, 0);
        }
      }
      // half B: kpos 32..63 (same-wave LDS in-order: safe overwrite)
#pragma unroll
      for (int mt = 2; mt < 4; ++mt)
        *reinterpret_cast<uint2*>(&Pb[w][r * 40 + 16 * (mt - 2) + 4 * quad]) = pk[mt];
      {
        const short8 pa1 = *reinterpret_cast<const short8*>(&Pb[w][r * 40 + 8 * quad]);
#pragma unroll
        for (int dt = 0; dt < 8; ++dt) {
          const int d = 16 * dt + r;
          const short8 b1 = *reinterpret_cast<const short8*>(&Vs[d * 64 + 8 * ((4 + quad) ^ sw)]);
          Oc[dt] = __builtin_amdgcn_mfma_f32_16x16x32_bf16(pa1, b1, Oc[dt], 0, 0, 0);
        }
      }
    }

    // normalize by 1/l (LDS broadcast, wave-private)
    if (quad == 0) ab[w][r] = 1.0f / l_i;
    const float4 li4 = *reinterpret_cast<const float4*>(&ab[w][4 * quad]);
#pragma unroll
    for (int dt = 0; dt < 8; ++dt) {
      Oc[dt][0] *= li4.x; Oc[dt][1] *= li4.y; Oc[dt][2] *= li4.z; Oc[dt][3] *= li4.w;
    }
  };

  f32x4 Ocr[8];  // cross-attn result, normalized, held in regs
  run_pass(Qc, Kc, Vc, kvLenC, Ocr);
  __syncthreads();  // all cross LDS reads done before main re-stages
  f32x4 Oc[8];
  run_pass(Qm, Km, Vm, kvLenM, Oc);

  // store bf16: main + cross (register add)
  u16* obb = Ob + (size_t)(q0 + 16 * w) * 1536 + h * 128;
#pragma unroll
  for (int rr = 0; rr < 4; ++rr) {
    u16* brow = obb + (size_t)(4 * quad + rr) * 1536 + r;
#pragma unroll
    for (int dt = 0; dt < 8; ++dt)
      brow[16 * dt] = f2b(Oc[dt][rr] + Ocr[dt][rr]);
  }
}

// =====================================================================
// Host orchestration (7 dispatches)
// =====================================================================
extern "C" void kernel_launch(void* const* d_in, const int* in_sizes, int n_in,
                              void* d_out, int out_size, void* d_ws, size_t ws_size,
                              hipStream_t stream) {
  (void)in_sizes; (void)n_in; (void)out_size; (void)ws_size;
  constexpr int T = 4096, TR = 1024, DIM = 1536, NH = 12;

  const float* hs  = (const float*)d_in[0];
  const float* rhs = (const float*)d_in[1];
  const float* rc  = (const float*)d_in[2];
  const float* rs  = (const float*)d_in[3];
  const float* Wq  = (const float*)d_in[4];
  const float* bq  = (const float*)d_in[5];
  const float* Wk  = (const float*)d_in[6];
  const float* bk  = (const float*)d_in[7];
  const float* Wv  = (const float*)d_in[8];
  const float* bv  = (const float*)d_in[9];
  const float* Wkr = (const float*)d_in[10];
  const float* bkr = (const float*)d_in[11];
  const float* Wvr = (const float*)d_in[12];
  const float* bvr = (const float*)d_in[13];
  const float* Wo  = (const float*)d_in[14];
  const float* bo  = (const float*)d_in[15];
  const float* gq  = (const float*)d_in[16];
  const float* gk  = (const float*)d_in[17];
  float* out = (float*)d_out;

  char* ws = (char*)d_ws;
  size_t off = 0;
  auto alloc = [&](size_t bytes) -> void* {
    void* p = ws + off;
    off += (bytes + 255) & ~(size_t)255;
    return p;
  };
  u16* bQ    = (u16*)alloc((size_t)T * DIM * 2);
  u16* bQr   = (u16*)alloc((size_t)T * DIM * 2);
  u16* bK    = (u16*)alloc((size_t)T * DIM * 2);
  u16* bV    = (u16*)alloc((size_t)T * DIM * 2);
  u16* bKr   = (u16*)alloc((size_t)TR * DIM * 2);
  u16* bVr   = (u16*)alloc((size_t)TR * DIM * 2);
  u16* bHs   = (u16*)alloc((size_t)T * DIM * 2);       // bf16 hs; ALIAS-> VtG
  u16* bRhs  = (u16*)alloc((size_t)TR * DIM * 2);      // bf16 rhs; ALIAS-> VtR
  u16* bWqkv = (u16*)alloc((size_t)3 * DIM * DIM * 2); // WqT|WkT|WvT; ALIAS-> bOb
  u16* bWr   = (u16*)alloc((size_t)2 * DIM * DIM * 2); // WkrT|WvrT
  u16* bWoT  = (u16*)alloc((size_t)DIM * DIM * 2);     // WoT (own slab)
  u16* VtG = bHs;
  u16* VtR = bRhs;
  u16* bOb = bWqkv;

  const dim3 blk(256);

  // 1. f32->bf16 converts (merged)
  conv2_kernel<<<dim3((T * DIM / 8 + TR * DIM / 8 + 255) / 256), blk, 0, stream>>>(
      hs, bHs, T * DIM / 8, rhs, bRhs, TR * DIM / 8);

  // 2. weight transpose-converts (all six merged)
  transconv6_kernel<<<dim3(24, 24, 6), blk, 0, stream>>>(
      Wq, Wk, Wv, Wkr, Wvr, Wo,
      bWqkv + 0 * (size_t)DIM * DIM, bWqkv + 1 * (size_t)DIM * DIM,
      bWqkv + 2 * (size_t)DIM * DIM, bWr + 0 * (size_t)DIM * DIM,
      bWr + 1 * (size_t)DIM * DIM, bWoT);

  // 3. merged projections: QKV (1152 blocks) + KrVr (192 blocks)
  gemm_qkvr_kernel<<<dim3(1344), blk, 0, stream>>>(
      bHs, bWqkv, bQ, bK, bV, bq, bk, bv,
      bRhs, bWr, bKr, bVr, bkr, bvr);

  // 4. rmsnorm/rope (merged; q-path pre-scaled by QS)
  rmsnorm3_kernel<<<dim3(T, 3), blk, 0, stream>>>(
      bQ, bK, bKr, gq, gk, rc, rs, bQ, bQr, bK, bKr);

  // 5. per-head V transposes (merged; alias buffers are dead)
  vtrans2_kernel<<<dim3(T / 64, NH, 2), blk, 0, stream>>>(bV, VtG, bVr, VtR);

  // 6. merged flash attention: cross (kv=1024) + main (kv=4096), adds in regs
  flash_kernel<<<dim3(T / 64, NH), blk, 0, stream>>>(
      bQ, bKr, VtR, TR, bQr, bK, VtG, T, bOb);

  // 7. output projection (64-row tiles for occupancy)
  gemm128_kernel<2, float><<<dim3(12, 64), blk, 0, stream>>>(
      bOb, DIM, bWoT, DIM, out, (float*)nullptr, (float*)nullptr, DIM, bo, nullptr, nullptr, DIM);
}

// Round 14
// 485.377 us; speedup vs baseline: 1.7040x; 1.0254x over previous
//
#include <hip/hip_runtime.h>

typedef unsigned short u16;
typedef unsigned int u32;
typedef __attribute__((ext_vector_type(8))) short short8;
typedef __attribute__((ext_vector_type(4))) float f32x4;

// ---------- bf16 helpers ----------
__device__ inline u16 f2b(float f) {  // RNE
  u32 u = __builtin_bit_cast(u32, f);
  u += 0x7fff + ((u >> 16) & 1);
  return (u16)(u >> 16);
}
__device__ inline float b2f(u16 u) {
  return __builtin_bit_cast(float, (u32)u << 16);
}
// round-to-nearest (ties away) pack — cheaper than RNE, used for P only
__device__ inline u32 pack_bf16_rn(float a, float b) {
  const u32 ua = __builtin_bit_cast(u32, a) + 0x8000u;
  const u32 ub = __builtin_bit_cast(u32, b) + 0x8000u;
  return (ua >> 16) | (ub & 0xffff0000u);
}
__device__ inline void c_store(float* p, float v) { *p = v; }
__device__ inline void c_store(u16* p, float v) { *p = f2b(v); }

__device__ inline float fexp2(float x) {
#if __has_builtin(__builtin_amdgcn_exp2f)
  return __builtin_amdgcn_exp2f(x);
#else
  return exp2f(x);
#endif
}

// ---------- async global->LDS, 16B per lane ----------
typedef const __attribute__((address_space(1))) u32 gu32;
typedef __attribute__((address_space(3))) u32 lu32;
__device__ inline void async16(const u16* g, u16* l) {
  __builtin_amdgcn_global_load_lds((gu32*)g, (lu32*)l, 16, 0, 0);
}

// Q scale folded into rmsnorm producer: 1/sqrt(128) * log2(e)
#define QS (0.08838834764831843f * 1.4426950408889634f)

// =====================================================================
// (32*MI)x128x(K,BK=32) bf16 GEMM. r14 structure (verified r8/r12/r13):
// single-barrier LDS double-buffer + XCD-locality remap.
// Used for the output projection only.
// =====================================================================
template <int MI, typename TC>
__global__ __launch_bounds__(256) void gemm128_kernel(
    const u16* __restrict__ A, long lda,
    const u16* __restrict__ Bt, long ldb,
    TC* __restrict__ C0, TC* __restrict__ C1, TC* __restrict__ C2, long ldc,
    const float* b0, const float* b1, const float* b2,
    int K) {
  __shared__ __align__(16) u16 As[2][32 * MI * 32];
  __shared__ __align__(16) u16 Bs[2][128 * 32];

  const int tid = threadIdx.x;
  const int lane = tid & 63;
  const int w = tid >> 6;
  const int r = lane & 15;
  const int quad = lane >> 4;

  // ---- XCD-locality remap (bijective when ny % 8 == 0) ----
  int bx = blockIdx.x, by = blockIdx.y;
  {
    const int ny = gridDim.y;
    if ((ny & 7) == 0) {
      const int lin = by * gridDim.x + bx;
      const int xcd = lin & 7;
      const int k = lin >> 3;
      const int rpx = ny >> 3;                 // A-row panels per XCD
      by = xcd * rpx + (k % rpx);
      bx = k / rpx;
    }
  }
  const int m0 = by * (32 * MI);
  const int nb = bx * 128;
  const int seg = nb / 1536;
  const int nc = nb - seg * 1536;
  TC* C = seg == 0 ? C0 : (seg == 1 ? C1 : C2);
  const float* bias = seg == 0 ? b0 : (seg == 1 ? b1 : b2);

  const int srow = lane >> 2;
  const int sx = ((lane & 3) ^ (srow & 3)) * 8;
  const u16* Ag = A + (size_t)(m0 + w * 8 * MI + srow) * lda + sx;
  const u16* Bg = Bt + (size_t)(nb + w * 32 + srow) * ldb + sx;

  const int wm = (w >> 1) * (16 * MI);
  const int wn = (w & 1) * 64;

  f32x4 acc[MI][4];
#pragma unroll
  for (int i = 0; i < MI; ++i)
#pragma unroll
    for (int j = 0; j < 4; ++j) acc[i][j] = (f32x4){0.f, 0.f, 0.f, 0.f};

  const int fco = (quad ^ (r & 3)) * 8;

  const int nt = K >> 5;

  // prologue: stage tile 0 into buffer 0
#pragma unroll
  for (int j = 0; j < MI / 2; ++j)
    async16(Ag + (size_t)(16 * j) * lda, &As[0][(w * 8 * MI + 16 * j) * 32]);
  async16(Bg, &Bs[0][(w * 32) * 32]);
  async16(Bg + 16 * ldb, &Bs[0][(w * 32 + 16) * 32]);

  for (int t = 0; t < nt; ++t) {
    const int buf = t & 1;
    __syncthreads();  // stage(t) complete; buf^1 reads (iter t-1) done
    if (t + 1 < nt) {
      const int kk = 32 * (t + 1);
#pragma unroll
      for (int j = 0; j < MI / 2; ++j)
        async16(Ag + kk + (size_t)(16 * j) * lda, &As[buf ^ 1][(w * 8 * MI + 16 * j) * 32]);
      async16(Bg + kk, &Bs[buf ^ 1][(w * 32) * 32]);
      async16(Bg + kk + 16 * ldb, &Bs[buf ^ 1][(w * 32 + 16) * 32]);
    }

    short8 af[MI], bf[4];
#pragma unroll
    for (int mi = 0; mi < MI; ++mi)
      af[mi] = *reinterpret_cast<const short8*>(&As[buf][(wm + 16 * mi + r) * 32 + fco]);
#pragma unroll
    for (int ni = 0; ni < 4; ++ni)
      bf[ni] = *reinterpret_cast<const short8*>(&Bs[buf][(wn + 16 * ni + r) * 32 + fco]);
#pragma unroll
    for (int mi = 0; mi < MI; ++mi)
#pragma unroll
      for (int ni = 0; ni < 4; ++ni)
        acc[mi][ni] = __builtin_amdgcn_mfma_f32_16x16x32_bf16(af[mi], bf[ni], acc[mi][ni], 0, 0, 0);
  }

#pragma unroll
  for (int mi = 0; mi < MI; ++mi)
#pragma unroll
    for (int ni = 0; ni < 4; ++ni)
#pragma unroll
      for (int rr = 0; rr < 4; ++rr) {
        const int row = m0 + wm + 16 * mi + 4 * quad + rr;
        const int col = nc + wn + 16 * ni + r;
        c_store(&C[(size_t)row * ldc + col], acc[mi][ni][rr] + bias[col]);
      }
}

// =====================================================================
// Merged QKV + KrVr GEMM (verified r13). Body = gemm128 MI=4 verbatim;
// block-decode preamble selects GEMM. 1344 = 8*168, swizzle bijective.
// =====================================================================
__global__ __launch_bounds__(256) void gemm_qkvr_kernel(
    const u16* __restrict__ A1, const u16* __restrict__ B1,
    u16* __restrict__ Cq, u16* __restrict__ Ck, u16* __restrict__ Cv,
    const float* bq, const float* bk, const float* bv,
    const u16* __restrict__ A2, const u16* __restrict__ B2,
    u16* __restrict__ Ckr, u16* __restrict__ Cvr,
    const float* bkr, const float* bvr) {
  constexpr int MI = 4;
  __shared__ __align__(16) u16 As[2][32 * MI * 32];
  __shared__ __align__(16) u16 Bs[2][128 * 32];

  const int tid = threadIdx.x;
  const int lane = tid & 63;
  const int w = tid >> 6;
  const int r = lane & 15;
  const int quad = lane >> 4;

  // ---- decode: XCD swizzle then GEMM select ----
  const int lin = blockIdx.x;                 // 0..1343
  const int swz = (lin & 7) * 168 + (lin >> 3);
  const u16 *A, *Bt;
  u16* C;
  const float* bias;
  int m0, nb, nc;
  if (swz < 1152) {                           // QKV
    const int by = swz / 36, bx = swz - 36 * by;
    m0 = by * 128;
    nb = bx * 128;
    const int seg = nb / 1536;
    nc = nb - seg * 1536;
    A = A1; Bt = B1;
    C = seg == 0 ? Cq : (seg == 1 ? Ck : Cv);
    bias = seg == 0 ? bq : (seg == 1 ? bk : bv);
  } else {                                    // KrVr
    const int s2 = swz - 1152;                // 0..191
    const int by = s2 / 24, bx = s2 - 24 * by;
    m0 = by * 128;                            // < 1024
    nb = bx * 128;                            // < 3072
    const int seg = (nb >= 1536) ? 1 : 0;
    nc = nb - seg * 1536;
    A = A2; Bt = B2;
    C = seg == 0 ? Ckr : Cvr;
    bias = seg == 0 ? bkr : bvr;
  }

  const int srow = lane >> 2;
  const int sx = ((lane & 3) ^ (srow & 3)) * 8;
  const u16* Ag = A + (size_t)(m0 + w * 8 * MI + srow) * 1536 + sx;
  const u16* Bg = Bt + (size_t)(nb + w * 32 + srow) * 1536 + sx;

  const int wm = (w >> 1) * (16 * MI);
  const int wn = (w & 1) * 64;

  f32x4 acc[MI][4];
#pragma unroll
  for (int i = 0; i < MI; ++i)
#pragma unroll
    for (int j = 0; j < 4; ++j) acc[i][j] = (f32x4){0.f, 0.f, 0.f, 0.f};

  const int fco = (quad ^ (r & 3)) * 8;

  const int nt = 1536 >> 5;  // 48

  // prologue: stage tile 0 into buffer 0
#pragma unroll
  for (int j = 0; j < MI / 2; ++j)
    async16(Ag + (size_t)(16 * j) * 1536, &As[0][(w * 8 * MI + 16 * j) * 32]);
  async16(Bg, &Bs[0][(w * 32) * 32]);
  async16(Bg + 16 * 1536, &Bs[0][(w * 32 + 16) * 32]);

  for (int t = 0; t < nt; ++t) {
    const int buf = t & 1;
    __syncthreads();  // stage(t) complete; buf^1 reads (iter t-1) done
    if (t + 1 < nt) {
      const int kk = 32 * (t + 1);
#pragma unroll
      for (int j = 0; j < MI / 2; ++j)
        async16(Ag + kk + (size_t)(16 * j) * 1536, &As[buf ^ 1][(w * 8 * MI + 16 * j) * 32]);
      async16(Bg + kk, &Bs[buf ^ 1][(w * 32) * 32]);
      async16(Bg + kk + 16 * 1536, &Bs[buf ^ 1][(w * 32 + 16) * 32]);
    }

    short8 af[MI], bf[4];
#pragma unroll
    for (int mi = 0; mi < MI; ++mi)
      af[mi] = *reinterpret_cast<const short8*>(&As[buf][(wm + 16 * mi + r) * 32 + fco]);
#pragma unroll
    for (int ni = 0; ni < 4; ++ni)
      bf[ni] = *reinterpret_cast<const short8*>(&Bs[buf][(wn + 16 * ni + r) * 32 + fco]);
#pragma unroll
    for (int mi = 0; mi < MI; ++mi)
#pragma unroll
      for (int ni = 0; ni < 4; ++ni)
        acc[mi][ni] = __builtin_amdgcn_mfma_f32_16x16x32_bf16(af[mi], bf[ni], acc[mi][ni], 0, 0, 0);
  }

#pragma unroll
  for (int mi = 0; mi < MI; ++mi)
#pragma unroll
    for (int ni = 0; ni < 4; ++ni)
#pragma unroll
      for (int rr = 0; rr < 4; ++rr) {
        const int row = m0 + wm + 16 * mi + 4 * quad + rr;
        const int col = nc + wn + 16 * ni + r;
        c_store(&C[(size_t)row * 1536 + col], acc[mi][ni][rr] + bias[col]);
      }
}

// =====================================================================
// Fused prep (r20): conv2 (z=0) + transconv6 (z=1) in one dispatch.
// Bodies verbatim from the validated kernels; only a z/lin selector.
// grid = dim3(3840, 1, 2); z=1 uses first 3456 blocks (24*24*6).
// =====================================================================
__global__ __launch_bounds__(256) void prep_kernel(
    const float* __restrict__ hs, u16* __restrict__ yhs, int n8a,
    const float* __restrict__ rhs, u16* __restrict__ yrhs, int n8b,
    const float* W0, const float* W1, const float* W2,
    const float* W3, const float* W4, const float* W5,
    u16* T0, u16* T1, u16* T2, u16* T3, u16* T4, u16* T5) {
  const int tid = threadIdx.x;
  if (blockIdx.z == 0) {
    // ---- conv2 body (verified r0-r13) ----
    int i = blockIdx.x * 256 + tid;
    const float* x;
    u16* y;
    if (i < n8a) {
      x = hs; y = yhs;
    } else {
      i -= n8a;
      if (i >= n8b) return;
      x = rhs; y = yrhs;
    }
    const float4 v0 = reinterpret_cast<const float4*>(x)[2 * i];
    const float4 v1 = reinterpret_cast<const float4*>(x)[2 * i + 1];
    uint4 rv;
    rv.x = (u32)f2b(v0.x) | ((u32)f2b(v0.y) << 16);
    rv.y = (u32)f2b(v0.z) | ((u32)f2b(v0.w) << 16);
    rv.z = (u32)f2b(v1.x) | ((u32)f2b(v1.y) << 16);
    rv.w = (u32)f2b(v1.z) | ((u32)f2b(v1.w) << 16);
    reinterpret_cast<uint4*>(y)[i] = rv;
    return;
  }
  // ---- transconv6 body (verified r0-r13), lin-decoded ----
  const int lin = blockIdx.x;
  if (lin >= 3456) return;
  const int bx = lin % 24;
  const int by = (lin / 24) % 24;
  const int z = lin / 576;
  const float* W = z == 0 ? W0 : z == 1 ? W1 : z == 2 ? W2 : z == 3 ? W3 : z == 4 ? W4 : W5;
  u16* Wt = z == 0 ? T0 : z == 1 ? T1 : z == 2 ? T2 : z == 3 ? T3 : z == 4 ? T4 : T5;

  __shared__ __align__(16) u16 Ls[64 * 72];
  const int k0 = by * 64;
  const int n0 = bx * 64;
#pragma unroll
  for (int i = 0; i < 4; ++i) {
    const int c = tid + 256 * i;
    const int row = c >> 4;
    const int c4 = (c & 15) * 4;
    const float4 v = *reinterpret_cast<const float4*>(&W[(size_t)(k0 + row) * 1536 + n0 + c4]);
    Ls[(c4 + 0) * 72 + row] = f2b(v.x);
    Ls[(c4 + 1) * 72 + row] = f2b(v.y);
    Ls[(c4 + 2) * 72 + row] = f2b(v.z);
    Ls[(c4 + 3) * 72 + row] = f2b(v.w);
  }
  __syncthreads();
#pragma unroll
  for (int i = 0; i < 2; ++i) {
    const int c = tid + 256 * i;
    const int n = c >> 3;
    const int kc = (c & 7) * 8;
    u16 tmp[8];
#pragma unroll
    for (int j = 0; j < 8; ++j) tmp[j] = Ls[n * 72 + kc + j];
    *reinterpret_cast<uint4*>(&Wt[(size_t)(n0 + n) * 1536 + k0 + kc]) =
        *reinterpret_cast<const uint4*>(tmp);
  }
}

// =====================================================================
// Fused norm (r20): rmsnorm3 (lin<12288) + vtrans2 (lin>=12288), one
// dispatch. Bodies verbatim from the validated kernels; disjoint data
// (rmsnorm: bQ/bK/bKr; vtrans: bV/bVr -> VtG/VtR). grid = 13824.
// =====================================================================
__global__ __launch_bounds__(256) void normtrans_kernel(
    const u16* xq, const u16* xk, const u16* xkr,
    const float* gq, const float* gk,
    const float* rc, const float* rs,
    u16* oq_plain, u16* oq_rope, u16* ok_rope, u16* okr_plain,
    const u16* __restrict__ V0, u16* __restrict__ Vt0,
    const u16* __restrict__ V1, u16* __restrict__ Vt1) {
  const int tid = threadIdx.x;
  const int lin = blockIdx.x;
  __shared__ __align__(16) u16 LsV[64 * 136];  // vtrans scratch (max LDS)

  if (lin < 12288) {
    // ---- rmsnorm3 body (verified r4-r13) ----
    __shared__ float red[4];
    const int z = lin >> 12;
    const int row = lin & 4095;
    if (z == 2 && row >= 1024) return;
    const u16* x; const float* g; u16* po; u16* pr; float sc;
    if (z == 0)      { x = xq;  g = gq; po = oq_plain; pr = oq_rope; sc = QS;  }
    else if (z == 1) { x = xk;  g = gk; po = nullptr;  pr = ok_rope; sc = 1.f; }
    else             { x = xkr; g = gk; po = okr_plain; pr = nullptr; sc = 1.f; }

    const u32* xr = reinterpret_cast<const u32*>(x + (size_t)row * 1536);
    float xe[3], xo[3];
    float ss = 0.f;
#pragma unroll
    for (int j = 0; j < 3; ++j) {
      const u32 u = xr[tid + 256 * j];
      const float e = b2f((u16)(u & 0xffff));
      const float o = b2f((u16)(u >> 16));
      xe[j] = e; xo[j] = o;
      ss += e * e + o * o;
    }
#pragma unroll
    for (int off = 32; off; off >>= 1) ss += __shfl_xor(ss, off, 64);
    if ((tid & 63) == 0) red[tid >> 6] = ss;
    __syncthreads();
    const float total = red[0] + red[1] + red[2] + red[3];
    const float rinv = rsqrtf(total * (1.0f / 1536.0f) + 1e-6f) * sc;
    u32* po32 = po ? reinterpret_cast<u32*>(po + (size_t)row * 1536) : nullptr;
    u32* pr32 = pr ? reinterpret_cast<u32*>(pr + (size_t)row * 1536) : nullptr;
#pragma unroll
    for (int j = 0; j < 3; ++j) {
      const int p = tid + 256 * j;
      const float2 gg = reinterpret_cast<const float2*>(g)[p];
      const float e = xe[j] * rinv * gg.x;
      const float o = xo[j] * rinv * gg.y;
      if (po32) po32[p] = (u32)f2b(e) | ((u32)f2b(o) << 16);
      if (pr32) {
        const int i = p & 63;
        const float c = rc[row * 64 + i];
        const float s = rs[row * 64 + i];
        const float re = e * c - o * s;
        const float im = e * s + o * c;
        pr32[p] = (u32)f2b(re) | ((u32)f2b(im) << 16);
      }
    }
    return;
  }

  // ---- vtrans2 body (verified r4-r13), lin-decoded ----
  const int s = lin - 12288;         // 0..1535
  const int xb = s & 63;
  const int h = (s >> 6) % 12;
  const int zz = s / 768;
  const int kvLen = zz == 0 ? 4096 : 1024;
  const int kv0 = xb * 64;
  if (kv0 >= kvLen) return;
  const u16* V = zz == 0 ? V0 : V1;
  u16* Vt = zz == 0 ? Vt0 : Vt1;
#pragma unroll
  for (int i = 0; i < 4; ++i) {
    const int c = tid + 256 * i;
    const int row = c >> 4, c8 = c & 15;
    *reinterpret_cast<uint4*>(&LsV[row * 136 + 8 * c8]) =
        *reinterpret_cast<const uint4*>(V + (size_t)(kv0 + row) * 1536 + h * 128 + 8 * c8);
  }
  __syncthreads();
#pragma unroll
  for (int i = 0; i < 4; ++i) {
    const int c = tid + 256 * i;
    const int d = c >> 3, kc = c & 7;
    u16 tmp[8];
#pragma unroll
    for (int j = 0; j < 8; ++j) tmp[j] = LsV[(8 * kc + j) * 136 + d];
    *reinterpret_cast<uint4*>(Vt + ((size_t)h * 128 + d) * kvLen + kv0 + 8 * kc) =
        *reinterpret_cast<const uint4*>(tmp);
  }
}

// =====================================================================
// Flash attention (r20): r13's merged kernel (passed, 209 µs) + ONE
// correctness-validated addition: s_setprio(1/0) around the MFMA
// clusters (present in the passing r1/r2/r4 kernels; catalog: attn
// +4-7% with multiple independent blocks/CU — we have 3).
// Inner loop otherwise frozen to the r13-validated form.
// =====================================================================
__global__ __launch_bounds__(256, 3) void flash_kernel(
    const u16* __restrict__ Qc, const u16* __restrict__ Kc,
    const u16* __restrict__ Vc, int kvLenC,
    const u16* __restrict__ Qm, const u16* __restrict__ Km,
    const u16* __restrict__ Vm, int kvLenM,
    u16* __restrict__ Ob) {
  __shared__ __align__(16) u16 Ks[64 * 128];
  __shared__ __align__(16) u16 Vs[128 * 64];
  __shared__ __align__(16) u16 Pb[4][16 * 40];
  __shared__ __align__(16) float ab[4][16];

  const int tid = threadIdx.x;
  const int lane = tid & 63;
  const int w = tid >> 6;
  const int r = lane & 15;
  const int quad = lane >> 4;
  const int h = blockIdx.y;
  const int q0 = blockIdx.x * 64;
  const int qrow = q0 + 16 * w + r;
  const int sw = r & 7;

  auto run_pass = [&](const u16* __restrict__ Q, const u16* __restrict__ K,
                      const u16* __restrict__ Vt, int kvLen, f32x4* Oc) {
    // Q fragments (B-operand of S^T): lane holds Q[qrow][32ks+8quad+j]
    short8 qf[4];
    {
      const u16* qbase = Q + (size_t)qrow * 1536 + h * 128 + 8 * quad;
#pragma unroll
      for (int ks = 0; ks < 4; ++ks)
        qf[ks] = *reinterpret_cast<const short8*>(qbase + 32 * ks);
    }

    // staging: uniform bases + 32-bit per-lane element offsets (r0 layout)
    const u16* Kb = K + h * 128;
    const u16* Vb = Vt + (size_t)h * 128 * kvLen;
    u32 koff[4], voff[4];
    int klo[4], vlo[4];
    {
      const int p16 = lane & 15, rin = lane >> 4;
      const int p8 = lane & 7, din = lane >> 3;
#pragma unroll
      for (int j = 0; j < 4; ++j) {
        const int row = 16 * w + 4 * j + rin;
        koff[j] = (u32)row * 1536u + 8u * (u32)(p16 ^ (row & 15));
        klo[j] = (16 * w + 4 * j) * 128;
        const int d = 32 * w + 8 * j + din;
        voff[j] = (u32)d * (u32)kvLen + 8u * (u32)(p8 ^ (d & 7));
        vlo[j] = (32 * w + 8 * j) * 64;
      }
    }

#pragma unroll
    for (int dt = 0; dt < 8; ++dt) Oc[dt] = (f32x4){0.f, 0.f, 0.f, 0.f};
    float m_i = -1e30f, l_i = 0.f;

    const int nt = kvLen >> 6;
    for (int t = 0; t < nt; ++t) {
      __syncthreads();  // prior tile reads done
      {
        const size_t ko = (size_t)t * (64 * 1536);
        const size_t vo = (size_t)t * 64;
#pragma unroll
        for (int j = 0; j < 4; ++j) async16(Kb + ko + koff[j], &Ks[klo[j]]);
#pragma unroll
        for (int j = 0; j < 4; ++j) async16(Vb + vo + voff[j], &Vs[vlo[j]]);
      }
      __syncthreads();  // DMA complete

      // S^T = K * Q^T (log2-domain; Q pre-scaled)
      f32x4 St[4];
#pragma unroll
      for (int mt = 0; mt < 4; ++mt) St[mt] = (f32x4){0.f, 0.f, 0.f, 0.f};
      __builtin_amdgcn_s_setprio(1);
#pragma unroll
      for (int mt = 0; mt < 4; ++mt) {
        const u16* kp = &Ks[(16 * mt + r) * 128];
#pragma unroll
        for (int ks = 0; ks < 4; ++ks) {
          const short8 af = *reinterpret_cast<const short8*>(kp + 8 * ((quad + 4 * ks) ^ r));
          St[mt] = __builtin_amdgcn_mfma_f32_16x16x32_bf16(af, qf[ks], St[mt], 0, 0, 0);
        }
      }
      __builtin_amdgcn_s_setprio(0);

      // online softmax (base 2); lane owns q-row r; defer-max (r13 form)
      float mloc = -1e30f;
#pragma unroll
      for (int mt = 0; mt < 4; ++mt)
#pragma unroll
        for (int rr = 0; rr < 4; ++rr) mloc = fmaxf(mloc, St[mt][rr]);
      mloc = fmaxf(mloc, __shfl_xor(mloc, 16, 64));
      mloc = fmaxf(mloc, __shfl_xor(mloc, 32, 64));

      float alpha = 1.0f;
      if (__any(mloc > m_i + 11.5f)) {  // defer-max: rescale only on big growth
        const float mn = fmaxf(m_i, mloc);
        alpha = fexp2(m_i - mn);
        m_i = mn;
        if (quad == 0) ab[w][r] = alpha;
        const float4 a4 = *reinterpret_cast<const float4*>(&ab[w][4 * quad]);
#pragma unroll
        for (int dt = 0; dt < 8; ++dt) {
          Oc[dt][0] *= a4.x; Oc[dt][1] *= a4.y; Oc[dt][2] *= a4.z; Oc[dt][3] *= a4.w;
        }
      }

      float psum = 0.f;
      uint2 pk[4];
#pragma unroll
      for (int mt = 0; mt < 4; ++mt) {
        const float p0 = fexp2(St[mt][0] - m_i);
        const float p1 = fexp2(St[mt][1] - m_i);
        const float p2 = fexp2(St[mt][2] - m_i);
        const float p3 = fexp2(St[mt][3] - m_i);
        psum += (p0 + p1) + (p2 + p3);
        pk[mt].x = pack_bf16_rn(p0, p1);
        pk[mt].y = pack_bf16_rn(p2, p3);
      }
      psum += __shfl_xor(psum, 16, 64);
      psum += __shfl_xor(psum, 32, 64);
      l_i = l_i * alpha + psum;

      // PV in two k-halves, reusing the 16x40 wave-private Pb region.
      // half A: kpos 0..31
#pragma unroll
      for (int mt = 0; mt < 2; ++mt)
        *reinterpret_cast<uint2*>(&Pb[w][r * 40 + 16 * mt + 4 * quad]) = pk[mt];
      {
        const short8 pa0 = *reinterpret_cast<const short8*>(&Pb[w][r * 40 + 8 * quad]);
        __builtin_amdgcn_s_setprio(1);
#pragma unroll
        for (int dt = 0; dt < 8; ++dt) {
          const int d = 16 * dt + r;
          const short8 b0 = *reinterpret_cast<const short8*>(&Vs[d * 64 + 8 * (quad ^ sw)]);
          Oc[dt] = __builtin_amdgcn_mfma_f32_16x16x32_bf16(pa0, b0, Oc[dt], 0, 0, 0);
        }
        __builtin_amdgcn_s_setprio(0);
      }
      // half B: kpos 32..63 (same-wave LDS in-order: safe overwrite)
#pragma unroll
      for (int mt = 2; mt < 4; ++mt)
        *reinterpret_cast<uint2*>(&Pb[w][r * 40 + 16 * (mt - 2) + 4 * quad]) = pk[mt];
      {
        const short8 pa1 = *reinterpret_cast<const short8*>(&Pb[w][r * 40 + 8 * quad]);
        __builtin_amdgcn_s_setprio(1);
#pragma unroll
        for (int dt = 0; dt < 8; ++dt) {
          const int d = 16 * dt + r;
          const short8 b1 = *reinterpret_cast<const short8*>(&Vs[d * 64 + 8 * ((4 + quad) ^ sw)]);
          Oc[dt] = __builtin_amdgcn_mfma_f32_16x16x32_bf16(pa1, b1, Oc[dt], 0, 0, 0);
        }
        __builtin_amdgcn_s_setprio(0);
      }
    }

    // normalize by 1/l (LDS broadcast, wave-private)
    if (quad == 0) ab[w][r] = 1.0f / l_i;
    const float4 li4 = *reinterpret_cast<const float4*>(&ab[w][4 * quad]);
#pragma unroll
    for (int dt = 0; dt < 8; ++dt) {
      Oc[dt][0] *= li4.x; Oc[dt][1] *= li4.y; Oc[dt][2] *= li4.z; Oc[dt][3] *= li4.w;
    }
  };

  f32x4 Ocr[8];  // cross-attn result, normalized, held in regs
  run_pass(Qc, Kc, Vc, kvLenC, Ocr);
  __syncthreads();  // all cross LDS reads done before main re-stages
  f32x4 Oc[8];
  run_pass(Qm, Km, Vm, kvLenM, Oc);

  // store bf16: main + cross (register add)
  u16* obb = Ob + (size_t)(q0 + 16 * w) * 1536 + h * 128;
#pragma unroll
  for (int rr = 0; rr < 4; ++rr) {
    u16* brow = obb + (size_t)(4 * quad + rr) * 1536 + r;
#pragma unroll
    for (int dt = 0; dt < 8; ++dt)
      brow[16 * dt] = f2b(Oc[dt][rr] + Ocr[dt][rr]);
  }
}

// =====================================================================
// Host orchestration (5 dispatches)
// =====================================================================
extern "C" void kernel_launch(void* const* d_in, const int* in_sizes, int n_in,
                              void* d_out, int out_size, void* d_ws, size_t ws_size,
                              hipStream_t stream) {
  (void)in_sizes; (void)n_in; (void)out_size; (void)ws_size;
  constexpr int T = 4096, TR = 1024, DIM = 1536, NH = 12;

  const float* hs  = (const float*)d_in[0];
  const float* rhs = (const float*)d_in[1];
  const float* rc  = (const float*)d_in[2];
  const float* rs  = (const float*)d_in[3];
  const float* Wq  = (const float*)d_in[4];
  const float* bq  = (const float*)d_in[5];
  const float* Wk  = (const float*)d_in[6];
  const float* bk  = (const float*)d_in[7];
  const float* Wv  = (const float*)d_in[8];
  const float* bv  = (const float*)d_in[9];
  const float* Wkr = (const float*)d_in[10];
  const float* bkr = (const float*)d_in[11];
  const float* Wvr = (const float*)d_in[12];
  const float* bvr = (const float*)d_in[13];
  const float* Wo  = (const float*)d_in[14];
  const float* bo  = (const float*)d_in[15];
  const float* gq  = (const float*)d_in[16];
  const float* gk  = (const float*)d_in[17];
  float* out = (float*)d_out;

  char* ws = (char*)d_ws;
  size_t off = 0;
  auto alloc = [&](size_t bytes) -> void* {
    void* p = ws + off;
    off += (bytes + 255) & ~(size_t)255;
    return p;
  };
  u16* bQ    = (u16*)alloc((size_t)T * DIM * 2);
  u16* bQr   = (u16*)alloc((size_t)T * DIM * 2);
  u16* bK    = (u16*)alloc((size_t)T * DIM * 2);
  u16* bV    = (u16*)alloc((size_t)T * DIM * 2);
  u16* bKr   = (u16*)alloc((size_t)TR * DIM * 2);
  u16* bVr   = (u16*)alloc((size_t)TR * DIM * 2);
  u16* bHs   = (u16*)alloc((size_t)T * DIM * 2);       // bf16 hs; ALIAS-> VtG
  u16* bRhs  = (u16*)alloc((size_t)TR * DIM * 2);      // bf16 rhs; ALIAS-> VtR
  u16* bWqkv = (u16*)alloc((size_t)3 * DIM * DIM * 2); // WqT|WkT|WvT; ALIAS-> bOb
  u16* bWr   = (u16*)alloc((size_t)2 * DIM * DIM * 2); // WkrT|WvrT
  u16* bWoT  = (u16*)alloc((size_t)DIM * DIM * 2);     // WoT (own slab)
  u16* VtG = bHs;
  u16* VtR = bRhs;
  u16* bOb = bWqkv;

  const dim3 blk(256);

  // 1. fused prep: f32->bf16 converts (z=0) + 6 weight transposes (z=1)
  prep_kernel<<<dim3(3840, 1, 2), blk, 0, stream>>>(
      hs, bHs, T * DIM / 8, rhs, bRhs, TR * DIM / 8,
      Wq, Wk, Wv, Wkr, Wvr, Wo,
      bWqkv + 0 * (size_t)DIM * DIM, bWqkv + 1 * (size_t)DIM * DIM,
      bWqkv + 2 * (size_t)DIM * DIM, bWr + 0 * (size_t)DIM * DIM,
      bWr + 1 * (size_t)DIM * DIM, bWoT);

  // 2. merged projections: QKV (1152 blocks) + KrVr (192 blocks)
  gemm_qkvr_kernel<<<dim3(1344), blk, 0, stream>>>(
      bHs, bWqkv, bQ, bK, bV, bq, bk, bv,
      bRhs, bWr, bKr, bVr, bkr, bvr);

  // 3. fused rmsnorm/rope + per-head V transposes
  normtrans_kernel<<<dim3(12288 + 1536), blk, 0, stream>>>(
      bQ, bK, bKr, gq, gk, rc, rs, bQ, bQr, bK, bKr,
      bV, VtG, bVr, VtR);

  // 4. merged flash attention: cross (kv=1024) + main (kv=4096), adds in regs
  flash_kernel<<<dim3(T / 64, NH), blk, 0, stream>>>(
      bQ, bKr, VtR, TR, bQr, bK, VtG, T, bOb);

  // 5. output projection (64-row tiles for occupancy)
  gemm128_kernel<2, float><<<dim3(12, 64), blk, 0, stream>>>(
      bOb, DIM, bWoT, DIM, out, (float*)nullptr, (float*)nullptr, DIM, bo, nullptr, nullptr, DIM);
}